// Round 13
// baseline (855.066 us; speedup 1.0000x reference)
//
#include <hip/hip_runtime.h>
#include <hip/hip_bf16.h>
#include <math.h>

constexpr int CB  = 4;     // batch
constexpr int CN  = 2048;  // tokens
constexpr int CD  = 1024;  // model dim
constexpr int CE  = 4;     // experts
constexpr int CS  = 512;   // slots per expert
constexpr int CH  = 4096;  // expert hidden
constexpr int CES = 2048;  // E*S

typedef unsigned short u16;
typedef unsigned int   u32;
typedef __bf16 bf16x8 __attribute__((ext_vector_type(8)));
typedef float  f32x4  __attribute__((ext_vector_type(4)));

__device__ __forceinline__ u16 f2bf(float x) {
  u32 u = __float_as_uint(x);
  u = (u + 0x7FFF + ((u >> 16) & 1)) >> 16;   // round-to-nearest-even
  return (u16)u;
}

__device__ __forceinline__ void gl2lds16(const void* g, void* l) {
  __builtin_amdgcn_global_load_lds(
      (const __attribute__((address_space(1))) void*)g,
      (__attribute__((address_space(3))) void*)l, 16, 0, 0);
}

// bijective XCD-aware block swizzle (all grids have nwg % 8 == 0)
__device__ __forceinline__ void xcd_swz(int& bx, int& by, int& bz) {
  u32 gx = gridDim.x, gy = gridDim.y;
  u32 w = blockIdx.x + gx * (blockIdx.y + gy * blockIdx.z);
  u32 nwg = gx * gy * gridDim.z;
  u32 q = nwg >> 3;
  u32 wg = (w & 7) * q + (w >> 3);
  bx = wg % gx;
  u32 r = wg / gx;
  by = r % gy;
  bz = r / gy;
}

// ---------------- spectral-norm scale kernels ----------------
// scale = sigma * ||W u|| / ||W^T (W u)||

__global__ __launch_bounds__(256) void gemv_rows_k(const float* __restrict__ W,
    const float* __restrict__ u, float* __restrict__ t1, int M, int K, int ustride) {
  int bi = blockIdx.y;
  int row = blockIdx.x * 4 + (threadIdx.x >> 6);
  int lane = threadIdx.x & 63;
  const float* Wr = W + ((long)bi * M + row) * K;
  const float* ub = u + (long)bi * ustride;
  float s = 0.f;
  for (int k = lane; k < K; k += 64) s += Wr[k] * ub[k];
#pragma unroll
  for (int off = 32; off; off >>= 1) s += __shfl_down(s, off, 64);
  if (lane == 0) t1[bi * M + row] = s;
}

// also emits bf16 conversion of W (and optional lo-plane split)
__global__ __launch_bounds__(256) void gemv_cols_k(const float* __restrict__ W,
    const float* __restrict__ t1, float* __restrict__ t2,
    u16* __restrict__ bh, u16* __restrict__ bl, int M, int K) {
  int bi = blockIdx.z;
  int k = blockIdx.x * 256 + threadIdx.x;
  int m0 = blockIdx.y * 256;
  const float* Wb = W + (long)bi * M * K;
  const float* tb = t1 + bi * M;
  u16* bhb = bh + (long)bi * M * K;
  u16* blb = bl ? bl + (long)bi * M * K : nullptr;
  float s = 0.f;
#pragma unroll 4
  for (int m = 0; m < 256; m++) {
    long idx = (long)(m0 + m) * K + k;
    float w = Wb[idx];
    s += w * tb[m0 + m];
    u16 h = f2bf(w);
    bhb[idx] = h;
    if (blb) blb[idx] = f2bf(w - __uint_as_float((u32)h << 16));
  }
  atomicAdd(&t2[bi * K + k], s);
}

// all 9 spectral scales in one launch: block 0 = W_slot, 1..4 = W1[e], 5..8 = W2[e]
__global__ __launch_bounds__(256) void scale_all_k(
    const float* __restrict__ t1s, const float* __restrict__ t2s,
    const float* __restrict__ t1a, const float* __restrict__ t2a,
    const float* __restrict__ t1b, const float* __restrict__ t2b,
    const float* __restrict__ sigs, const float* __restrict__ sig1,
    const float* __restrict__ sig2, float* __restrict__ scales) {
  int bi = blockIdx.x;
  const float *t1, *t2; float sg; float* o; int M, K;
  if (bi == 0)      { t1 = t1s;                 t2 = t2s;                 sg = sigs[0];     o = scales + 0;      M = 4096; K = 1024; }
  else if (bi < 5)  { int e = bi - 1; t1 = t1a + e * 4096; t2 = t2a + e * 1024; sg = sig1[e]; o = scales + 1 + e; M = 4096; K = 1024; }
  else              { int e = bi - 5; t1 = t1b + e * 1024; t2 = t2b + e * 4096; sg = sig2[e]; o = scales + 5 + e; M = 1024; K = 4096; }
  int tid = threadIdx.x;
  __shared__ float red[256];
  float s1 = 0.f;
  for (int i = tid; i < M; i += 256) { float v = t1[i]; s1 += v * v; }
  red[tid] = s1; __syncthreads();
  for (int w = 128; w; w >>= 1) { if (tid < w) red[tid] += red[tid + w]; __syncthreads(); }
  float n1 = red[0]; __syncthreads();
  float s2 = 0.f;
  for (int i = tid; i < K; i += 256) { float v = t2[i]; s2 += v * v; }
  red[tid] = s2; __syncthreads();
  for (int w = 128; w; w >>= 1) { if (tid < w) red[tid] += red[tid + w]; __syncthreads(); }
  if (tid == 0) o[0] = sg * sqrtf(n1 / red[0]);
}

// ---------------- fused x hi/lo split + token-group-mean hi/lo split ----------------
__global__ __launch_bounds__(256) void xsplit_fused_k(const float* __restrict__ x,
    u16* __restrict__ xh, u16* __restrict__ xl,
    u16* __restrict__ xmh, u16* __restrict__ xml) {
  int idx = blockIdx.x * 256 + threadIdx.x;      // b*S*(D/8) total
  int d8 = idx & (CD / 8 - 1);
  int si = (idx >> 7) & (CS - 1);
  int b  = idx >> 16;
  long rbase = ((long)(b * CN + si * 4)) * CD + d8 * 8;
  float vr[4][8];
#pragma unroll
  for (int r = 0; r < 4; r++) {
    float4 a = *(const float4*)(x + rbase + (long)r * CD);
    float4 c = *(const float4*)(x + rbase + (long)r * CD + 4);
    vr[r][0]=a.x; vr[r][1]=a.y; vr[r][2]=a.z; vr[r][3]=a.w;
    vr[r][4]=c.x; vr[r][5]=c.y; vr[r][6]=c.z; vr[r][7]=c.w;
  }
#pragma unroll
  for (int r = 0; r < 4; r++) {
    u16 oh[8], ol[8];
#pragma unroll
    for (int c = 0; c < 8; c++) {
      u16 h = f2bf(vr[r][c]);
      oh[c] = h;
      ol[c] = f2bf(vr[r][c] - __uint_as_float((u32)h << 16));
    }
    *(uint4*)(xh + rbase + (long)r * CD) = *(const uint4*)oh;
    *(uint4*)(xl + rbase + (long)r * CD) = *(const uint4*)ol;
  }
  long mbase = ((long)(b * CS + si)) * CD + d8 * 8;
  u16 oh[8], ol[8];
#pragma unroll
  for (int c = 0; c < 8; c++) {
    float v = 0.25f * (vr[0][c] + vr[1][c] + vr[2][c] + vr[3][c]);
    u16 h = f2bf(v);
    oh[c] = h;
    ol[c] = f2bf(v - __uint_as_float((u32)h << 16));
  }
  *(uint4*)(xmh + mbase) = *(const uint4*)oh;
  *(uint4*)(xml + mbase) = *(const uint4*)ol;
}

// ---------------- dispatch softmax stat combine (16 slabs of 128 rows) ----------------
__global__ __launch_bounds__(256) void colstat_comb_k(const float* __restrict__ pmax,
    const float* __restrict__ psum, float* __restrict__ cmax, float* __restrict__ csum) {
  int idx = blockIdx.x * 256 + threadIdx.x;   // b*CES
  int b = idx >> 11;
  int es = idx & (CES - 1);
  float m = -1e30f;
#pragma unroll
  for (int sl = 0; sl < 16; sl++) m = fmaxf(m, pmax[(b * 16 + sl) * CES + es]);
  float s = 0.f;
#pragma unroll
  for (int sl = 0; sl < 16; sl++)
    s += psum[(b * 16 + sl) * CES + es] * __expf(pmax[(b * 16 + sl) * CES + es] - m);
  cmax[idx] = m; csum[idx] = s;
}

// ---------------- fused combine softmax (over es) -> bf16 ----------------
__global__ __launch_bounds__(256) void rowcomb_k(const float* __restrict__ lg,
                                                 u16* __restrict__ outB) {
  __shared__ float red[8];
  long row = blockIdx.x;                       // b*CN + n
  const float* p = lg + row * CES + threadIdx.x * 8;
  float4 a = *(const float4*)p;
  float4 b = *(const float4*)(p + 4);
  float v[8] = {a.x, a.y, a.z, a.w, b.x, b.y, b.z, b.w};
  float m = v[0];
#pragma unroll
  for (int c = 1; c < 8; c++) m = fmaxf(m, v[c]);
#pragma unroll
  for (int off = 32; off; off >>= 1) m = fmaxf(m, __shfl_xor(m, off, 64));
  int wv = threadIdx.x >> 6;
  if ((threadIdx.x & 63) == 0) red[wv] = m;
  __syncthreads();
  m = fmaxf(fmaxf(red[0], red[1]), fmaxf(red[2], red[3]));
  float s = 0.f;
#pragma unroll
  for (int c = 0; c < 8; c++) { v[c] = __expf(v[c] - m); s += v[c]; }
#pragma unroll
  for (int off = 32; off; off >>= 1) s += __shfl_xor(s, off, 64);
  if ((threadIdx.x & 63) == 0) red[4 + wv] = s;
  __syncthreads();
  float inv = 1.f / (red[4] + red[5] + red[6] + red[7]);
  u16 o[8];
#pragma unroll
  for (int c = 0; c < 8; c++) o[c] = f2bf(v[c] * inv);
  *(uint4*)(outB + row * CES + threadIdx.x * 8) = *(const uint4*)o;
}

// in [z][R][C] f32 -> out [z][C][R] bf16; expmode: v = exp(v - sub[z*C + col])
__global__ __launch_bounds__(256) void tr_f2b_k(const float* __restrict__ in,
    u16* __restrict__ out, const float* __restrict__ sub, int R, int C, int expmode) {
  __shared__ u16 t[32][33];
  int z = blockIdx.z;
  long ibase = (long)z * R * C;
  int r0 = blockIdx.y * 32, c0 = blockIdx.x * 32;
  int tx = threadIdx.x & 31, ty = threadIdx.x >> 5;
  float cm = expmode ? sub[(long)z * C + c0 + tx] : 0.f;
  for (int rr = ty; rr < 32; rr += 8) {
    float v = in[ibase + (long)(r0 + rr) * C + c0 + tx];
    if (expmode) v = __expf(v - cm);
    t[tx][rr] = f2bf(v);
  }
  __syncthreads();
  for (int cc = ty; cc < 32; cc += 8)
    out[ibase + (long)(c0 + cc) * R + r0 + tx] = t[cc][tx];
}

// ---------------- epilogues ----------------
struct MEpSESplit {  // SE hi/lo planes [b][es][d], es = ei*512+si; m=(b,si), n=(ei,di)
  u16* hi; u16* lo; const float* scale;
  __device__ void store(int z, int m, int n, float v) const {
    v *= scale[0];
    int b = m >> 9, si = m & 511, ei = n >> 10, di = n & 1023;
    long o = ((long)(b * CES + ei * 512 + si)) * CD + di;
    u16 h = f2bf(v);
    hi[o] = h;
    lo[o] = f2bf(v - __uint_as_float((u32)h << 16));
  }
};
struct MEpLogits {   // logits[b][n][es] = v ; z=b, m=token, n=es
  float* lg;
  __device__ void store(int b, int m, int n, float v) const {
    lg[((long)(b * CN + m)) * CES + n] = v;
  }
};
struct MEpSlots {  // slotsB[e][b*512+si][d] = bf16(v / csum[b][es]); z=b, m=es
  u16* sb; const float* __restrict__ csum;
  __device__ void store(int b, int m, int n, float v) const {
    float inv = 1.f / csum[b * CES + m];
    int e = m >> 9, si = m & 511;
    sb[((long)(e * 2048 + b * 512 + si)) * CD + n] = f2bf(v * inv);
  }
};
struct MEpGelu {   // h[e][m][H] = bf16(gelu(v*sc1[e] + b1[e][n])); z=e, m=(b,si)
  // tanh-form GELU: |err vs exact| below bf16 rounding of h (verified r8/r9).
  u16* h; const float* __restrict__ scales; const float* __restrict__ b1;
  __device__ void store(int e, int m, int n, float v) const {
    float xg = v * scales[1 + e] + b1[e * CH + n];
    float t = xg * (0.7978845608f + 0.0356774081f * xg * xg);
    float ex = __expf(2.f * t);
    float th = 1.f - 2.f / (ex + 1.f);          // tanh(t), saturates correctly
    float g = 0.5f * xg * (1.f + th);
    h[((long)(e * 2048 + m)) * CH + n] = f2bf(g);
  }
};
struct MEpYT {     // outbufT[b][d][es] = bf16(v*sc2[e] + b2[e][m]); z=e, m=d, n=(b,si)
  u16* ot; const float* __restrict__ scales; const float* __restrict__ b2;
  __device__ void store(int e, int m, int n, float v) const {
    int b = n >> 9, si = n & 511;
    ot[((long)(b * CD + m)) * CES + e * 512 + si] = f2bf(v * scales[5 + e] + b2[e * CD + m]);
  }
};
struct MEpOut {    // out[b][n][d] = v (combine already has 1/rsum); z=b
  float* o;
  __device__ void store(int b, int m, int n, float v) const {
    o[((long)(b * CN + m)) * CD + n] = v;
  }
};

// ---------------- bf16 MFMA GEMM, 128xBN tile, 4 waves (proven r4-r9) ----------------
template <int BN, int BK, class EP>
__global__ __launch_bounds__(256) void mgemm_k(const u16* __restrict__ A, long Azs, int ldA,
                                               const u16* __restrict__ B, long Bzs, int ldB,
                                               EP ep, int K) {
  constexpr int BM = 128;
  constexpr int FI = 4;
  constexpr int FJ = BN / 32;
  constexpr int RPL = 512 / BK;            // rows per 1KB load-group
  constexpr int NGRP = (BM + BN) / RPL;    // 1KB groups per K-step
  constexpr int GPW = NGRP / 4;            // groups per wave
  __shared__ __align__(16) u16 S[(BM + BN) * BK];
  int bx, by, bz;
  xcd_swz(bx, by, bz);
  const int tid = threadIdx.x;
  const int wid = tid >> 6, lane = tid & 63;
  const int m0 = by * BM, n0 = bx * BN;
  const u16* Az = A + (long)bz * Azs;
  const u16* Bz = B + (long)bz * Bzs;
  const int wr = wid >> 1, wc = wid & 1;
  const int lrow = lane / (BK / 8);        // row within load-group
  const int lk   = (lane % (BK / 8)) * 8;  // k offset within row

  f32x4 acc[FI][FJ];
  f32x4 zero = {0.f, 0.f, 0.f, 0.f};
#pragma unroll
  for (int i = 0; i < FI; i++)
#pragma unroll
    for (int j = 0; j < FJ; j++) acc[i][j] = zero;

  for (int k0 = 0; k0 < K; k0 += BK) {
#pragma unroll
    for (int g = 0; g < GPW; g++) {
      int grp = g * 4 + wid;
      int row = grp * RPL + lrow;          // A rows [0,BM), then B rows
      const u16* src = (row < BM)
          ? Az + (long)(m0 + row) * ldA + k0 + lk
          : Bz + (long)(n0 + row - BM) * ldB + k0 + lk;
      gl2lds16(src, (char*)S + grp * 1024);
    }
    __syncthreads();
#pragma unroll
    for (int kk2 = 0; kk2 < BK / 32; kk2++) {
      bf16x8 af[FI], bfr[FJ];
#pragma unroll
      for (int i = 0; i < FI; i++) {
        int arow = wr * 64 + i * 16 + (lane & 15);
        af[i] = *(const bf16x8*)&S[arow * BK + kk2 * 32 + (lane >> 4) * 8];
      }
#pragma unroll
      for (int j = 0; j < FJ; j++) {
        int brow = BM + wc * (BN / 2) + j * 16 + (lane & 15);
        bfr[j] = *(const bf16x8*)&S[brow * BK + kk2 * 32 + (lane >> 4) * 8];
      }
#pragma unroll
      for (int i = 0; i < FI; i++)
#pragma unroll
        for (int j = 0; j < FJ; j++)
          acc[i][j] = __builtin_amdgcn_mfma_f32_16x16x32_bf16(af[i], bfr[j], acc[i][j], 0, 0, 0);
    }
    __syncthreads();
  }
#pragma unroll
  for (int i = 0; i < FI; i++) {
    int grow = m0 + wr * 64 + i * 16 + (lane >> 4) * 4;
#pragma unroll
    for (int j = 0; j < FJ; j++) {
      int gcol = n0 + wc * (BN / 2) + j * 16 + (lane & 15);
#pragma unroll
      for (int r = 0; r < 4; r++)
        ep.store(bz, grow + r, gcol, acc[i][j][r]);
    }
  }
}

// ---------------- bf16 MFMA GEMM, 256x128 tile, 8 waves (proven r10/r11, FFN1) -------
template <class EP>
__global__ __launch_bounds__(512) void mgemm_big_k(const u16* __restrict__ A, long Azs, int ldA,
                                                   const u16* __restrict__ B, long Bzs, int ldB,
                                                   EP ep, int K) {
  constexpr int BM = 256, BN = 128, BK = 32;
  __shared__ __align__(16) u16 S[(BM + BN) * BK];   // 24 KiB
  int bx, by, bz;
  xcd_swz(bx, by, bz);
  const int tid = threadIdx.x;
  const int wid = tid >> 6, lane = tid & 63;
  const int m0 = by * BM, n0 = bx * BN;
  const u16* Az = A + (long)bz * Azs;
  const u16* Bz = B + (long)bz * Bzs;
  const int wr = wid >> 1, wc = wid & 1;
  const int lrow = lane >> 2;              // 16 rows per 1KB group
  const int lk   = (lane & 3) * 8;

  f32x4 acc[4][4];
  f32x4 zero = {0.f, 0.f, 0.f, 0.f};
#pragma unroll
  for (int i = 0; i < 4; i++)
#pragma unroll
    for (int j = 0; j < 4; j++) acc[i][j] = zero;

  for (int k0 = 0; k0 < K; k0 += BK) {
#pragma unroll
    for (int g = 0; g < 3; g++) {          // 24 groups / 8 waves
      int grp = g * 8 + wid;
      int row = grp * 16 + lrow;           // A rows [0,256), then B rows
      const u16* src = (row < BM)
          ? Az + (long)(m0 + row) * ldA + k0 + lk
          : Bz + (long)(n0 + row - BM) * ldB + k0 + lk;
      gl2lds16(src, (char*)S + grp * 1024);
    }
    __syncthreads();
    bf16x8 af[4], bfr[4];
#pragma unroll
    for (int i = 0; i < 4; i++) {
      int arow = wr * 64 + i * 16 + (lane & 15);
      af[i] = *(const bf16x8*)&S[arow * BK + (lane >> 4) * 8];
      int brow = BM + wc * 64 + i * 16 + (lane & 15);
      bfr[i] = *(const bf16x8*)&S[brow * BK + (lane >> 4) * 8];
    }
#pragma unroll
    for (int i = 0; i < 4; i++)
#pragma unroll
      for (int j = 0; j < 4; j++)
        acc[i][j] = __builtin_amdgcn_mfma_f32_16x16x32_bf16(af[i], bfr[j], acc[i][j], 0, 0, 0);
    __syncthreads();
  }
#pragma unroll
  for (int i = 0; i < 4; i++) {
    int grow = m0 + wr * 64 + i * 16 + (lane >> 4) * 4;
#pragma unroll
    for (int j = 0; j < 4; j++) {
      int gcol = n0 + wc * 64 + j * 16 + (lane & 15);
#pragma unroll
      for (int r = 0; r < 4; r++)
        ep.store(bz, grow + r, gcol, acc[i][j][r]);
    }
  }
}

// ---------------- split-bf16 3-term GEMM, 128^2 tile, 4 waves (proven r9) ----------
// CSTAT: emit per-block (128-row slab) column max/expsum into
// pmax/psum[(bz*16+by)*CES + n0 + c]  (dispatch-softmax partial stats).
template <bool CSTAT, class EP>
__global__ __launch_bounds__(256) void mgemm3_k(const u16* __restrict__ Ah,
                                                const u16* __restrict__ Al, long Azs, int ldA,
                                                const u16* __restrict__ Bh,
                                                const u16* __restrict__ Bl, long Bzs, int ldB,
                                                EP ep, int K,
                                                float* __restrict__ pmax,
                                                float* __restrict__ psum) {
  constexpr int BK = 32;
  __shared__ __align__(16) u16 Ahs[128 * BK];
  __shared__ __align__(16) u16 Als[128 * BK];
  __shared__ __align__(16) u16 Bhs[128 * BK];
  __shared__ __align__(16) u16 Bls[128 * BK];
  int bx, by, bz;
  xcd_swz(bx, by, bz);
  const int tid = threadIdx.x;
  const int wid = tid >> 6, lane = tid & 63;
  const int m0 = by * 128, n0 = bx * 128;
  const u16* Ahz = Ah + (long)bz * Azs;
  const u16* Alz = Al + (long)bz * Azs;
  const u16* Bhz = Bh + (long)bz * Bzs;
  const u16* Blz = Bl + (long)bz * Bzs;
  const int wr = wid >> 1, wc = wid & 1;
  const int srow = lane >> 2;
  const int sk8  = (lane & 3) * 8;

  f32x4 acc[4][4];
  f32x4 zero = {0.f, 0.f, 0.f, 0.f};
#pragma unroll
  for (int i = 0; i < 4; i++)
#pragma unroll
    for (int j = 0; j < 4; j++) acc[i][j] = zero;

  for (int k0 = 0; k0 < K; k0 += BK) {
#pragma unroll
    for (int i = 0; i < 2; i++) {
      int chunk = i * 4 + wid;
      int r = chunk * 16 + srow;
      long ao = (long)(m0 + r) * ldA + k0 + sk8;
      long bo = (long)(n0 + r) * ldB + k0 + sk8;
      gl2lds16(Ahz + ao, (char*)Ahs + chunk * 1024);
      gl2lds16(Alz + ao, (char*)Als + chunk * 1024);
      gl2lds16(Bhz + bo, (char*)Bhs + chunk * 1024);
      gl2lds16(Blz + bo, (char*)Bls + chunk * 1024);
    }
    __syncthreads();
    bf16x8 ah[4], al[4], bh[4], bl[4];
#pragma unroll
    for (int i = 0; i < 4; i++) {
      int arow = wr * 64 + i * 16 + (lane & 15);
      int aoff = arow * BK + (lane >> 4) * 8;
      ah[i] = *(const bf16x8*)&Ahs[aoff];
      al[i] = *(const bf16x8*)&Als[aoff];
      int brow = wc * 64 + i * 16 + (lane & 15);
      int boff = brow * BK + (lane >> 4) * 8;
      bh[i] = *(const bf16x8*)&Bhs[boff];
      bl[i] = *(const bf16x8*)&Bls[boff];
    }
#pragma unroll
    for (int i = 0; i < 4; i++)
#pragma unroll
      for (int j = 0; j < 4; j++) {
        acc[i][j] = __builtin_amdgcn_mfma_f32_16x16x32_bf16(ah[i], bh[j], acc[i][j], 0, 0, 0);
        acc[i][j] = __builtin_amdgcn_mfma_f32_16x16x32_bf16(al[i], bh[j], acc[i][j], 0, 0, 0);
        acc[i][j] = __builtin_amdgcn_mfma_f32_16x16x32_bf16(ah[i], bl[j], acc[i][j], 0, 0, 0);
      }
    __syncthreads();
  }
#pragma unroll
  for (int i = 0; i < 4; i++) {
    int grow = m0 + wr * 64 + i * 16 + (lane >> 4) * 4;
#pragma unroll
    for (int j = 0; j < 4; j++) {
      int gcol = n0 + wc * 64 + j * 16 + (lane & 15);
#pragma unroll
      for (int r = 0; r < 4; r++)
        ep.store(bz, grow + r, gcol, acc[i][j][r]);
    }
  }

  if constexpr (CSTAT) {
    // col c = wc*64 + j*16 + (lane&15); lanes {l, l^16, l^32, l^48} share a col.
    __shared__ float cred[2][128];
    __shared__ float sred[2][128];
    float cmv[4], lsum[4];
#pragma unroll
    for (int j = 0; j < 4; j++) {
      float m = acc[0][j][0];
#pragma unroll
      for (int i = 0; i < 4; i++)
#pragma unroll
        for (int r = 0; r < 4; r++) m = fmaxf(m, acc[i][j][r]);
      m = fmaxf(m, __shfl_xor(m, 16, 64));
      m = fmaxf(m, __shfl_xor(m, 32, 64));
      cmv[j] = m;                          // col max over this wave's 64 rows
    }
    if (lane < 16) {
#pragma unroll
      for (int j = 0; j < 4; j++) cred[wr][wc * 64 + j * 16 + lane] = cmv[j];
    }
    __syncthreads();
#pragma unroll
    for (int j = 0; j < 4; j++) {
      int c = wc * 64 + j * 16 + (lane & 15);
      float cm = fmaxf(cred[0][c], cred[1][c]);   // block col max (128 rows)
      float s = 0.f;
#pragma unroll
      for (int i = 0; i < 4; i++)
#pragma unroll
        for (int r = 0; r < 4; r++) s += __expf(acc[i][j][r] - cm);
      s += __shfl_xor(s, 16, 64);
      s += __shfl_xor(s, 32, 64);
      cmv[j] = cm; lsum[j] = s;
    }
    if (lane < 16) {
#pragma unroll
      for (int j = 0; j < 4; j++) sred[wr][wc * 64 + j * 16 + lane] = lsum[j];
    }
    __syncthreads();
    if (wr == 0 && lane < 16) {
      long sb = ((long)bz * 16 + by) * CES + n0;
#pragma unroll
      for (int j = 0; j < 4; j++) {
        int c = wc * 64 + j * 16 + lane;
        pmax[sb + c] = cmv[j];
        psum[sb + c] = sred[0][c] + sred[1][c];
      }
    }
  }
}

// ---------------- launch ----------------
extern "C" void kernel_launch(void* const* d_in, const int* in_sizes, int n_in,
                              void* d_out, int out_size, void* d_ws, size_t ws_size,
                              hipStream_t stream) {
  const float* x          = (const float*)d_in[0];
  const float* W_slot     = (const float*)d_in[1];
  const float* u_slot     = (const float*)d_in[2];
  const float* sigma_slot = (const float*)d_in[3];
  const float* W1         = (const float*)d_in[4];
  const float* b1         = (const float*)d_in[5];
  const float* u1         = (const float*)d_in[6];
  const float* sig1       = (const float*)d_in[7];
  const float* W2         = (const float*)d_in[8];
  const float* b2         = (const float*)d_in[9];
  const float* u2         = (const float*)d_in[10];
  const float* sig2       = (const float*)d_in[11];
  float* out = (float*)d_out;

  // ---- workspace overlays (peak ~202 MiB, proven footprint) ----
  char* ws = (char*)d_ws;
  size_t off = 0;
  auto alloc = [&](size_t bytes) -> char* {
    char* p = ws + off;
    off += (bytes + 255) & ~(size_t)255;
    return p;
  };
  float* t1s = (float*)alloc(4096 * 4);
  float* t1a = (float*)alloc(4 * 4096 * 4);
  float* t1b = (float*)alloc(4 * 1024 * 4);
  float* t2s = (float*)alloc(1024 * 4);
  float* t2a = (float*)alloc(4 * 1024 * 4);
  float* t2b = (float*)alloc(4 * 4096 * 4);
  float* scales = (float*)alloc(16 * 4);
  float* pmax   = (float*)alloc((size_t)CB * 16 * CES * 4);
  float* psum   = (float*)alloc((size_t)CB * 16 * CES * 4);
  float* cmax   = (float*)alloc((size_t)CB * CES * 4);
  float* csum   = (float*)alloc((size_t)CB * CES * 4);
  char* regAB   = alloc((size_t)CB * CN * CD * 2 * 2);                // 32 MiB
  char* regBB   = alloc((size_t)CB * CES * CD * 2 * 2);               // 32 MiB
  char* regL    = alloc((size_t)CB * CN * CES * 4);                   // 64 MiB
  char* regS    = alloc((size_t)CE * CB * CS * CD * 2);               // 16 MiB
  u16* W1b      = (u16*)alloc((size_t)CE * CH * CD * 2);              // 32 MiB
  u16* W2b      = (u16*)alloc((size_t)CE * CD * CH * 2);              // 32 MiB

  u16*   xh      = (u16*)regAB;                        // [b][n][d]
  u16*   xl      = (u16*)(regAB + (size_t)CB * CN * CD * 2);
  u16*   dispT   = (u16*)regAB;                        // [b][es][n]
  u16*   combineB= (u16*)regAB;                        // [b][n][es]
  u16*   seh     = (u16*)regBB;                        // [b][es][d]
  u16*   sel     = (u16*)(regBB + (size_t)CB * CES * CD * 2);
  u16*   xT      = (u16*)regBB;                        // [b][d][n]
  float* logits  = (float*)regL;                       // [b][n][es]
  u16*   hbuf    = (u16*)regL;                         // [e][2048][H]
  u16*   xmh     = (u16*)regL;                         // [(b,s)][d] 4 MiB
  u16*   xml     = (u16*)(regL + (size_t)CB * CS * CD * 2);
  u16*   wslh    = (u16*)(regL + (size_t)2 * CB * CS * CD * 2);  // [4096][1024] 8 MiB
  u16*   wsll    = (u16*)(regL + (size_t)2 * CB * CS * CD * 2 + (size_t)CE * CD * CD * 2);
  u16*   slotsB  = (u16*)regS;                         // [e][(b,si)][d]
  u16*   outbufT = (u16*)regS;                         // [b][d][es]

  // zero t2s..t2b in one span (consecutive 256-aligned allocs)
  hipMemsetAsync(t2s, 0, (size_t)((char*)t2b - (char*)t2s) + 4 * 4096 * 4, stream);

  // spectral scales (gemv_cols also emits bf16 weight planes)
  gemv_rows_k<<<dim3(4096 / 4, 1), 256, 0, stream>>>(W_slot, u_slot, t1s, 4096, 1024, 0);
  gemv_rows_k<<<dim3(4096 / 4, 4), 256, 0, stream>>>(W1, u1, t1a, CH, CD, CD);
  gemv_rows_k<<<dim3(1024 / 4, 4), 256, 0, stream>>>(W2, u2, t1b, CD, CH, CH);
  gemv_cols_k<<<dim3(1024 / 256, 4096 / 256, 1), 256, 0, stream>>>(W_slot, t1s, t2s, wslh, wsll, 4096, 1024);
  gemv_cols_k<<<dim3(1024 / 256, 4096 / 256, 4), 256, 0, stream>>>(W1, t1a, t2a, W1b, nullptr, CH, CD);
  gemv_cols_k<<<dim3(4096 / 256, 1024 / 256, 4), 256, 0, stream>>>(W2, t1b, t2b, W2b, nullptr, CD, CH);
  scale_all_k<<<9, 256, 0, stream>>>(t1s, t2s, t1a, t2a, t1b, t2b,
                                     sigma_slot, sig1, sig2, scales);

  // x hi/lo split + token-group-mean hi/lo split (single pass over x)
  xsplit_fused_k<<<(CB * CS * (CD / 8)) / 256, 256, 0, stream>>>(x, xh, xl, xmh, xml);

  // SE = (xm @ W_slot^T) * scale_slot, split-bf16 3-term -> SE hi/lo planes
  // (128^2 tile, 512 blocks — proven r9/r11)
  mgemm3_k<false><<<dim3(4096 / 128, 2048 / 128, 1), 256, 0, stream>>>(
      xmh, xml, 0L, CD, wslh, wsll, 0L, CD, MEpSESplit{seh, sel, scales}, CD,
      nullptr, nullptr);

  // logits[b] = x_b @ SE_b^T, split-bf16 3-term -> f32, + fused col stats
  // (128^2 tile, 1024 blocks — proven r9/r12: ~128 µs @ MfmaUtil 35%)
  mgemm3_k<true><<<dim3(CES / 128, CN / 128, CB), 256, 0, stream>>>(
      xh, xl, (long)CN * CD, CD, seh, sel, (long)CES * CD, CD,
      MEpLogits{logits}, CD, pmax, psum);

  // dispatch softmax stat combine (16 slabs of 128 rows)
  colstat_comb_k<<<(CB * CES) / 256, 256, 0, stream>>>(pmax, psum, cmax, csum);

  // dispT[b][es][n] = bf16(exp(lg - cmax))   (overwrites xh/xl; dead after logits)
  tr_f2b_k<<<dim3(CES / 32, CN / 32, CB), 256, 0, stream>>>(logits, dispT, cmax, CN, CES, 1);
  // xT[b][d][n] = bf16(x^T)                  (overwrites seh; dead after logits)
  tr_f2b_k<<<dim3(CD / 32, CN / 32, CB), 256, 0, stream>>>(x, xT, nullptr, CN, CD, 0);

  // slots: [b] dispT(2048 x K2048) @ xT(1024 x K2048)^T -> slotsB (bf16, /csum)
  // <128,32>: 512 blocks = 2/CU, 256 B/MFMA (vs <64,64> 384 B/MFMA)
  mgemm_k<128, 32><<<dim3(CD / 128, CES / 128, CB), 256, 0, stream>>>(
      dispT, (long)CES * CN, CN, xT, (long)CD * CN, CN, MEpSlots{slotsB, csum}, CN);

  // combineB[b][n][es] = bf16(softmax over es)   (overwrites dispT; dead)
  rowcomb_k<<<CB * CN, 256, 0, stream>>>(logits, combineB);

  // FFN1: [e] slotsB(2048 x K1024) @ W1b(4096 x K1024)^T -> hbuf (gelu, bf16)
  // (256x128 tile, 1024 blocks — proven r10/r11, best staging intensity 192 B/MFMA)
  mgemm_big_k<<<dim3(CH / 128, 2048 / 256, CE), 512, 0, stream>>>(
      slotsB, (long)2048 * CD, CD, W1b, (long)CH * CD, CD, MEpGelu{hbuf, scales, b1}, CD);

  // FFN2 (swapped, writes y^T directly): [e] W2b(1024 x K4096) @ hbuf(2048 x K4096)^T
  // -> outbufT[b][d][es] bf16   <128,32>: 512 blocks = 2/CU
  mgemm_k<128, 32><<<dim3(2048 / 128, CD / 128, CE), 256, 0, stream>>>(
      W2b, (long)CD * CH, CH, hbuf, (long)2048 * CH, CH, MEpYT{outbufT, scales, b2}, CH);

  // final: [b] combineB(2048 x K2048) @ outbufT(1024 x K2048)^T -> out f32
  // <128,32>: 512 blocks = 2/CU
  mgemm_k<128, 32><<<dim3(CD / 128, CN / 128, CB), 256, 0, stream>>>(
      combineB, (long)CN * CES, CES, outbufT, (long)CD * CES, CES, MEpOut{out}, CES);

  (void)in_sizes; (void)n_in; (void)out_size; (void)ws_size;
}

// Round 14
// 830.130 us; speedup vs baseline: 1.0300x; 1.0300x over previous
//
#include <hip/hip_runtime.h>
#include <hip/hip_bf16.h>
#include <math.h>

constexpr int CB  = 4;     // batch
constexpr int CN  = 2048;  // tokens
constexpr int CD  = 1024;  // model dim
constexpr int CE  = 4;     // experts
constexpr int CS  = 512;   // slots per expert
constexpr int CH  = 4096;  // expert hidden
constexpr int CES = 2048;  // E*S

typedef unsigned short u16;
typedef unsigned int   u32;
typedef __bf16 bf16x8 __attribute__((ext_vector_type(8)));
typedef float  f32x4  __attribute__((ext_vector_type(4)));

__device__ __forceinline__ u16 f2bf(float x) {
  u32 u = __float_as_uint(x);
  u = (u + 0x7FFF + ((u >> 16) & 1)) >> 16;   // round-to-nearest-even
  return (u16)u;
}

__device__ __forceinline__ void gl2lds16(const void* g, void* l) {
  __builtin_amdgcn_global_load_lds(
      (const __attribute__((address_space(1))) void*)g,
      (__attribute__((address_space(3))) void*)l, 16, 0, 0);
}

// bijective XCD-aware block swizzle (all grids have nwg % 8 == 0)
__device__ __forceinline__ void xcd_swz(int& bx, int& by, int& bz) {
  u32 gx = gridDim.x, gy = gridDim.y;
  u32 w = blockIdx.x + gx * (blockIdx.y + gy * blockIdx.z);
  u32 nwg = gx * gy * gridDim.z;
  u32 q = nwg >> 3;
  u32 wg = (w & 7) * q + (w >> 3);
  bx = wg % gx;
  u32 r = wg / gx;
  by = r % gy;
  bz = r / gy;
}

// ---------------- spectral-norm scale kernels ----------------
// scale = sigma * ||W u|| / ||W^T (W u)||

__global__ __launch_bounds__(256) void gemv_rows_k(const float* __restrict__ W,
    const float* __restrict__ u, float* __restrict__ t1, int M, int K, int ustride) {
  int bi = blockIdx.y;
  int row = blockIdx.x * 4 + (threadIdx.x >> 6);
  int lane = threadIdx.x & 63;
  const float* Wr = W + ((long)bi * M + row) * K;
  const float* ub = u + (long)bi * ustride;
  float s = 0.f;
  for (int k = lane; k < K; k += 64) s += Wr[k] * ub[k];
#pragma unroll
  for (int off = 32; off; off >>= 1) s += __shfl_down(s, off, 64);
  if (lane == 0) t1[bi * M + row] = s;
}

// also emits bf16 conversion of W (and optional lo-plane split)
__global__ __launch_bounds__(256) void gemv_cols_k(const float* __restrict__ W,
    const float* __restrict__ t1, float* __restrict__ t2,
    u16* __restrict__ bh, u16* __restrict__ bl, int M, int K) {
  int bi = blockIdx.z;
  int k = blockIdx.x * 256 + threadIdx.x;
  int m0 = blockIdx.y * 256;
  const float* Wb = W + (long)bi * M * K;
  const float* tb = t1 + bi * M;
  u16* bhb = bh + (long)bi * M * K;
  u16* blb = bl ? bl + (long)bi * M * K : nullptr;
  float s = 0.f;
#pragma unroll 4
  for (int m = 0; m < 256; m++) {
    long idx = (long)(m0 + m) * K + k;
    float w = Wb[idx];
    s += w * tb[m0 + m];
    u16 h = f2bf(w);
    bhb[idx] = h;
    if (blb) blb[idx] = f2bf(w - __uint_as_float((u32)h << 16));
  }
  atomicAdd(&t2[bi * K + k], s);
}

// all 9 spectral scales in one launch: block 0 = W_slot, 1..4 = W1[e], 5..8 = W2[e]
__global__ __launch_bounds__(256) void scale_all_k(
    const float* __restrict__ t1s, const float* __restrict__ t2s,
    const float* __restrict__ t1a, const float* __restrict__ t2a,
    const float* __restrict__ t1b, const float* __restrict__ t2b,
    const float* __restrict__ sigs, const float* __restrict__ sig1,
    const float* __restrict__ sig2, float* __restrict__ scales) {
  int bi = blockIdx.x;
  const float *t1, *t2; float sg; float* o; int M, K;
  if (bi == 0)      { t1 = t1s;                 t2 = t2s;                 sg = sigs[0];     o = scales + 0;      M = 4096; K = 1024; }
  else if (bi < 5)  { int e = bi - 1; t1 = t1a + e * 4096; t2 = t2a + e * 1024; sg = sig1[e]; o = scales + 1 + e; M = 4096; K = 1024; }
  else              { int e = bi - 5; t1 = t1b + e * 1024; t2 = t2b + e * 4096; sg = sig2[e]; o = scales + 5 + e; M = 1024; K = 4096; }
  int tid = threadIdx.x;
  __shared__ float red[256];
  float s1 = 0.f;
  for (int i = tid; i < M; i += 256) { float v = t1[i]; s1 += v * v; }
  red[tid] = s1; __syncthreads();
  for (int w = 128; w; w >>= 1) { if (tid < w) red[tid] += red[tid + w]; __syncthreads(); }
  float n1 = red[0]; __syncthreads();
  float s2 = 0.f;
  for (int i = tid; i < K; i += 256) { float v = t2[i]; s2 += v * v; }
  red[tid] = s2; __syncthreads();
  for (int w = 128; w; w >>= 1) { if (tid < w) red[tid] += red[tid + w]; __syncthreads(); }
  if (tid == 0) o[0] = sg * sqrtf(n1 / red[0]);
}

// ---------------- fused x hi/lo split + token-group-mean hi/lo split ----------------
__global__ __launch_bounds__(256) void xsplit_fused_k(const float* __restrict__ x,
    u16* __restrict__ xh, u16* __restrict__ xl,
    u16* __restrict__ xmh, u16* __restrict__ xml) {
  int idx = blockIdx.x * 256 + threadIdx.x;      // b*S*(D/8) total
  int d8 = idx & (CD / 8 - 1);
  int si = (idx >> 7) & (CS - 1);
  int b  = idx >> 16;
  long rbase = ((long)(b * CN + si * 4)) * CD + d8 * 8;
  float vr[4][8];
#pragma unroll
  for (int r = 0; r < 4; r++) {
    float4 a = *(const float4*)(x + rbase + (long)r * CD);
    float4 c = *(const float4*)(x + rbase + (long)r * CD + 4);
    vr[r][0]=a.x; vr[r][1]=a.y; vr[r][2]=a.z; vr[r][3]=a.w;
    vr[r][4]=c.x; vr[r][5]=c.y; vr[r][6]=c.z; vr[r][7]=c.w;
  }
#pragma unroll
  for (int r = 0; r < 4; r++) {
    u16 oh[8], ol[8];
#pragma unroll
    for (int c = 0; c < 8; c++) {
      u16 h = f2bf(vr[r][c]);
      oh[c] = h;
      ol[c] = f2bf(vr[r][c] - __uint_as_float((u32)h << 16));
    }
    *(uint4*)(xh + rbase + (long)r * CD) = *(const uint4*)oh;
    *(uint4*)(xl + rbase + (long)r * CD) = *(const uint4*)ol;
  }
  long mbase = ((long)(b * CS + si)) * CD + d8 * 8;
  u16 oh[8], ol[8];
#pragma unroll
  for (int c = 0; c < 8; c++) {
    float v = 0.25f * (vr[0][c] + vr[1][c] + vr[2][c] + vr[3][c]);
    u16 h = f2bf(v);
    oh[c] = h;
    ol[c] = f2bf(v - __uint_as_float((u32)h << 16));
  }
  *(uint4*)(xmh + mbase) = *(const uint4*)oh;
  *(uint4*)(xml + mbase) = *(const uint4*)ol;
}

// ---------------- dispatch softmax stat combine (16 slabs of 128 rows) ----------------
__global__ __launch_bounds__(256) void colstat_comb_k(const float* __restrict__ pmax,
    const float* __restrict__ psum, float* __restrict__ cmax, float* __restrict__ csum) {
  int idx = blockIdx.x * 256 + threadIdx.x;   // b*CES
  int b = idx >> 11;
  int es = idx & (CES - 1);
  float m = -1e30f;
#pragma unroll
  for (int sl = 0; sl < 16; sl++) m = fmaxf(m, pmax[(b * 16 + sl) * CES + es]);
  float s = 0.f;
#pragma unroll
  for (int sl = 0; sl < 16; sl++)
    s += psum[(b * 16 + sl) * CES + es] * __expf(pmax[(b * 16 + sl) * CES + es] - m);
  cmax[idx] = m; csum[idx] = s;
}

// ---------------- fused combine softmax (over es) -> bf16 ----------------
__global__ __launch_bounds__(256) void rowcomb_k(const float* __restrict__ lg,
                                                 u16* __restrict__ outB) {
  __shared__ float red[8];
  long row = blockIdx.x;                       // b*CN + n
  const float* p = lg + row * CES + threadIdx.x * 8;
  float4 a = *(const float4*)p;
  float4 b = *(const float4*)(p + 4);
  float v[8] = {a.x, a.y, a.z, a.w, b.x, b.y, b.z, b.w};
  float m = v[0];
#pragma unroll
  for (int c = 1; c < 8; c++) m = fmaxf(m, v[c]);
#pragma unroll
  for (int off = 32; off; off >>= 1) m = fmaxf(m, __shfl_xor(m, off, 64));
  int wv = threadIdx.x >> 6;
  if ((threadIdx.x & 63) == 0) red[wv] = m;
  __syncthreads();
  m = fmaxf(fmaxf(red[0], red[1]), fmaxf(red[2], red[3]));
  float s = 0.f;
#pragma unroll
  for (int c = 0; c < 8; c++) { v[c] = __expf(v[c] - m); s += v[c]; }
#pragma unroll
  for (int off = 32; off; off >>= 1) s += __shfl_xor(s, off, 64);
  if ((threadIdx.x & 63) == 0) red[4 + wv] = s;
  __syncthreads();
  float inv = 1.f / (red[4] + red[5] + red[6] + red[7]);
  u16 o[8];
#pragma unroll
  for (int c = 0; c < 8; c++) o[c] = f2bf(v[c] * inv);
  *(uint4*)(outB + row * CES + threadIdx.x * 8) = *(const uint4*)o;
}

// in [z][R][C] f32 -> out [z][C][R] bf16; expmode: v = exp(v - sub[z*C + col])
__global__ __launch_bounds__(256) void tr_f2b_k(const float* __restrict__ in,
    u16* __restrict__ out, const float* __restrict__ sub, int R, int C, int expmode) {
  __shared__ u16 t[32][33];
  int z = blockIdx.z;
  long ibase = (long)z * R * C;
  int r0 = blockIdx.y * 32, c0 = blockIdx.x * 32;
  int tx = threadIdx.x & 31, ty = threadIdx.x >> 5;
  float cm = expmode ? sub[(long)z * C + c0 + tx] : 0.f;
  for (int rr = ty; rr < 32; rr += 8) {
    float v = in[ibase + (long)(r0 + rr) * C + c0 + tx];
    if (expmode) v = __expf(v - cm);
    t[tx][rr] = f2bf(v);
  }
  __syncthreads();
  for (int cc = ty; cc < 32; cc += 8)
    out[ibase + (long)(c0 + cc) * R + r0 + tx] = t[cc][tx];
}

// ---------------- epilogues ----------------
struct MEpSESplit {  // SE hi/lo planes [b][es][d], es = ei*512+si; m=(b,si), n=(ei,di)
  u16* hi; u16* lo; const float* scale;
  __device__ void store(int z, int m, int n, float v) const {
    v *= scale[0];
    int b = m >> 9, si = m & 511, ei = n >> 10, di = n & 1023;
    long o = ((long)(b * CES + ei * 512 + si)) * CD + di;
    u16 h = f2bf(v);
    hi[o] = h;
    lo[o] = f2bf(v - __uint_as_float((u32)h << 16));
  }
};
struct MEpLogits {   // logits[b][n][es] = v ; z=b, m=token, n=es
  float* lg;
  __device__ void store(int b, int m, int n, float v) const {
    lg[((long)(b * CN + m)) * CES + n] = v;
  }
};
struct MEpSlots {  // slotsB[e][b*512+si][d] = bf16(v / csum[b][es]); z=b, m=es
  u16* sb; const float* __restrict__ csum;
  __device__ void store(int b, int m, int n, float v) const {
    float inv = 1.f / csum[b * CES + m];
    int e = m >> 9, si = m & 511;
    sb[((long)(e * 2048 + b * 512 + si)) * CD + n] = f2bf(v * inv);
  }
};
struct MEpGelu {   // h[e][m][H] = bf16(gelu(v*sc1[e] + b1[e][n])); z=e, m=(b,si)
  // tanh-form GELU: |err vs exact| below bf16 rounding of h (verified r8/r9).
  u16* h; const float* __restrict__ scales; const float* __restrict__ b1;
  __device__ void store(int e, int m, int n, float v) const {
    float xg = v * scales[1 + e] + b1[e * CH + n];
    float t = xg * (0.7978845608f + 0.0356774081f * xg * xg);
    float ex = __expf(2.f * t);
    float th = 1.f - 2.f / (ex + 1.f);          // tanh(t), saturates correctly
    float g = 0.5f * xg * (1.f + th);
    h[((long)(e * 2048 + m)) * CH + n] = f2bf(g);
  }
};
struct MEpYT {     // outbufT[b][d][es] = bf16(v*sc2[e] + b2[e][m]); z=e, m=d, n=(b,si)
  u16* ot; const float* __restrict__ scales; const float* __restrict__ b2;
  __device__ void store(int e, int m, int n, float v) const {
    int b = n >> 9, si = n & 511;
    ot[((long)(b * CD + m)) * CES + e * 512 + si] = f2bf(v * scales[5 + e] + b2[e * CD + m]);
  }
};
struct MEpOut {    // out[b][n][d] = v (combine already has 1/rsum); z=b
  float* o;
  __device__ void store(int b, int m, int n, float v) const {
    o[((long)(b * CN + m)) * CD + n] = v;
  }
};

// ---------------- bf16 MFMA GEMM, 128xBN, 4 waves, DOUBLE-BUFFERED prefetch ---------
// Minimum 2-phase pipeline (guide T3 recipe): issue next-tile STAGE before
// computing current tile; ONE __syncthreads per K-step (drains own vmcnt).
// S[cur^1] written while S[cur] read — disjoint; buffer reuse protected by the
// previous iteration's barrier.
template <int BN, int BK, class EP>
__global__ __launch_bounds__(256) void mgemm_db_k(const u16* __restrict__ A, long Azs, int ldA,
                                                  const u16* __restrict__ B, long Bzs, int ldB,
                                                  EP ep, int K) {
  constexpr int BM = 128;
  constexpr int FI = 4;
  constexpr int FJ = BN / 32;
  constexpr int RPL = 512 / BK;            // rows per 1KB load-group
  constexpr int NGRP = (BM + BN) / RPL;    // 1KB groups per K-step
  constexpr int GPW = NGRP / 4;            // groups per wave
  __shared__ __align__(16) u16 S[2][(BM + BN) * BK];
  int bx, by, bz;
  xcd_swz(bx, by, bz);
  const int tid = threadIdx.x;
  const int wid = tid >> 6, lane = tid & 63;
  const int m0 = by * BM, n0 = bx * BN;
  const u16* Az = A + (long)bz * Azs;
  const u16* Bz = B + (long)bz * Bzs;
  const int wr = wid >> 1, wc = wid & 1;
  const int lrow = lane / (BK / 8);        // row within load-group
  const int lk   = (lane % (BK / 8)) * 8;  // k offset within row

  auto stage = [&](int buf, int k0) {
#pragma unroll
    for (int g = 0; g < GPW; g++) {
      int grp = g * 4 + wid;
      int row = grp * RPL + lrow;          // A rows [0,BM), then B rows
      const u16* src = (row < BM)
          ? Az + (long)(m0 + row) * ldA + k0 + lk
          : Bz + (long)(n0 + row - BM) * ldB + k0 + lk;
      gl2lds16(src, (char*)S[buf] + grp * 1024);
    }
  };

  f32x4 acc[FI][FJ];
  f32x4 zero = {0.f, 0.f, 0.f, 0.f};
#pragma unroll
  for (int i = 0; i < FI; i++)
#pragma unroll
    for (int j = 0; j < FJ; j++) acc[i][j] = zero;

  stage(0, 0);
  __syncthreads();
  int cur = 0;
  for (int k0 = 0; k0 < K; k0 += BK) {
    if (k0 + BK < K) stage(cur ^ 1, k0 + BK);   // prefetch next tile (uniform branch)
    const u16* Sc = S[cur];
#pragma unroll
    for (int kk2 = 0; kk2 < BK / 32; kk2++) {
      bf16x8 af[FI], bfr[FJ];
#pragma unroll
      for (int i = 0; i < FI; i++) {
        int arow = wr * 64 + i * 16 + (lane & 15);
        af[i] = *(const bf16x8*)&Sc[arow * BK + kk2 * 32 + (lane >> 4) * 8];
      }
#pragma unroll
      for (int j = 0; j < FJ; j++) {
        int brow = BM + wc * (BN / 2) + j * 16 + (lane & 15);
        bfr[j] = *(const bf16x8*)&Sc[brow * BK + kk2 * 32 + (lane >> 4) * 8];
      }
#pragma unroll
      for (int i = 0; i < FI; i++)
#pragma unroll
        for (int j = 0; j < FJ; j++)
          acc[i][j] = __builtin_amdgcn_mfma_f32_16x16x32_bf16(af[i], bfr[j], acc[i][j], 0, 0, 0);
    }
    __syncthreads();                       // drains own stage-loads + LDS handoff
    cur ^= 1;
  }
#pragma unroll
  for (int i = 0; i < FI; i++) {
    int grow = m0 + wr * 64 + i * 16 + (lane >> 4) * 4;
#pragma unroll
    for (int j = 0; j < FJ; j++) {
      int gcol = n0 + wc * (BN / 2) + j * 16 + (lane & 15);
#pragma unroll
      for (int r = 0; r < 4; r++)
        ep.store(bz, grow + r, gcol, acc[i][j][r]);
    }
  }
}

// ---------------- bf16 MFMA GEMM, 256x128 tile, 8 waves (proven r10/r11, FFN1) -------
template <class EP>
__global__ __launch_bounds__(512) void mgemm_big_k(const u16* __restrict__ A, long Azs, int ldA,
                                                   const u16* __restrict__ B, long Bzs, int ldB,
                                                   EP ep, int K) {
  constexpr int BM = 256, BN = 128, BK = 32;
  __shared__ __align__(16) u16 S[(BM + BN) * BK];   // 24 KiB
  int bx, by, bz;
  xcd_swz(bx, by, bz);
  const int tid = threadIdx.x;
  const int wid = tid >> 6, lane = tid & 63;
  const int m0 = by * BM, n0 = bx * BN;
  const u16* Az = A + (long)bz * Azs;
  const u16* Bz = B + (long)bz * Bzs;
  const int wr = wid >> 1, wc = wid & 1;
  const int lrow = lane >> 2;              // 16 rows per 1KB group
  const int lk   = (lane & 3) * 8;

  f32x4 acc[4][4];
  f32x4 zero = {0.f, 0.f, 0.f, 0.f};
#pragma unroll
  for (int i = 0; i < 4; i++)
#pragma unroll
    for (int j = 0; j < 4; j++) acc[i][j] = zero;

  for (int k0 = 0; k0 < K; k0 += BK) {
#pragma unroll
    for (int g = 0; g < 3; g++) {          // 24 groups / 8 waves
      int grp = g * 8 + wid;
      int row = grp * 16 + lrow;           // A rows [0,256), then B rows
      const u16* src = (row < BM)
          ? Az + (long)(m0 + row) * ldA + k0 + lk
          : Bz + (long)(n0 + row - BM) * ldB + k0 + lk;
      gl2lds16(src, (char*)S + grp * 1024);
    }
    __syncthreads();
    bf16x8 af[4], bfr[4];
#pragma unroll
    for (int i = 0; i < 4; i++) {
      int arow = wr * 64 + i * 16 + (lane & 15);
      af[i] = *(const bf16x8*)&S[arow * BK + (lane >> 4) * 8];
      int brow = BM + wc * 64 + i * 16 + (lane & 15);
      bfr[i] = *(const bf16x8*)&S[brow * BK + (lane >> 4) * 8];
    }
#pragma unroll
    for (int i = 0; i < 4; i++)
#pragma unroll
      for (int j = 0; j < 4; j++)
        acc[i][j] = __builtin_amdgcn_mfma_f32_16x16x32_bf16(af[i], bfr[j], acc[i][j], 0, 0, 0);
    __syncthreads();
  }
#pragma unroll
  for (int i = 0; i < 4; i++) {
    int grow = m0 + wr * 64 + i * 16 + (lane >> 4) * 4;
#pragma unroll
    for (int j = 0; j < 4; j++) {
      int gcol = n0 + wc * 64 + j * 16 + (lane & 15);
#pragma unroll
      for (int r = 0; r < 4; r++)
        ep.store(bz, grow + r, gcol, acc[i][j][r]);
    }
  }
}

// ---------------- split-bf16 3-term GEMM, 128^2 tile, 4 waves (proven r9) ----------
// CSTAT: emit per-block (128-row slab) column max/expsum into
// pmax/psum[(bz*16+by)*CES + n0 + c]  (dispatch-softmax partial stats).
template <bool CSTAT, class EP>
__global__ __launch_bounds__(256) void mgemm3_k(const u16* __restrict__ Ah,
                                                const u16* __restrict__ Al, long Azs, int ldA,
                                                const u16* __restrict__ Bh,
                                                const u16* __restrict__ Bl, long Bzs, int ldB,
                                                EP ep, int K,
                                                float* __restrict__ pmax,
                                                float* __restrict__ psum) {
  constexpr int BK = 32;
  __shared__ __align__(16) u16 Ahs[128 * BK];
  __shared__ __align__(16) u16 Als[128 * BK];
  __shared__ __align__(16) u16 Bhs[128 * BK];
  __shared__ __align__(16) u16 Bls[128 * BK];
  int bx, by, bz;
  xcd_swz(bx, by, bz);
  const int tid = threadIdx.x;
  const int wid = tid >> 6, lane = tid & 63;
  const int m0 = by * 128, n0 = bx * 128;
  const u16* Ahz = Ah + (long)bz * Azs;
  const u16* Alz = Al + (long)bz * Azs;
  const u16* Bhz = Bh + (long)bz * Bzs;
  const u16* Blz = Bl + (long)bz * Bzs;
  const int wr = wid >> 1, wc = wid & 1;
  const int srow = lane >> 2;
  const int sk8  = (lane & 3) * 8;

  f32x4 acc[4][4];
  f32x4 zero = {0.f, 0.f, 0.f, 0.f};
#pragma unroll
  for (int i = 0; i < 4; i++)
#pragma unroll
    for (int j = 0; j < 4; j++) acc[i][j] = zero;

  for (int k0 = 0; k0 < K; k0 += BK) {
#pragma unroll
    for (int i = 0; i < 2; i++) {
      int chunk = i * 4 + wid;
      int r = chunk * 16 + srow;
      long ao = (long)(m0 + r) * ldA + k0 + sk8;
      long bo = (long)(n0 + r) * ldB + k0 + sk8;
      gl2lds16(Ahz + ao, (char*)Ahs + chunk * 1024);
      gl2lds16(Alz + ao, (char*)Als + chunk * 1024);
      gl2lds16(Bhz + bo, (char*)Bhs + chunk * 1024);
      gl2lds16(Blz + bo, (char*)Bls + chunk * 1024);
    }
    __syncthreads();
    bf16x8 ah[4], al[4], bh[4], bl[4];
#pragma unroll
    for (int i = 0; i < 4; i++) {
      int arow = wr * 64 + i * 16 + (lane & 15);
      int aoff = arow * BK + (lane >> 4) * 8;
      ah[i] = *(const bf16x8*)&Ahs[aoff];
      al[i] = *(const bf16x8*)&Als[aoff];
      int brow = wc * 64 + i * 16 + (lane & 15);
      int boff = brow * BK + (lane >> 4) * 8;
      bh[i] = *(const bf16x8*)&Bhs[boff];
      bl[i] = *(const bf16x8*)&Bls[boff];
    }
#pragma unroll
    for (int i = 0; i < 4; i++)
#pragma unroll
      for (int j = 0; j < 4; j++) {
        acc[i][j] = __builtin_amdgcn_mfma_f32_16x16x32_bf16(ah[i], bh[j], acc[i][j], 0, 0, 0);
        acc[i][j] = __builtin_amdgcn_mfma_f32_16x16x32_bf16(al[i], bh[j], acc[i][j], 0, 0, 0);
        acc[i][j] = __builtin_amdgcn_mfma_f32_16x16x32_bf16(ah[i], bl[j], acc[i][j], 0, 0, 0);
      }
    __syncthreads();
  }
#pragma unroll
  for (int i = 0; i < 4; i++) {
    int grow = m0 + wr * 64 + i * 16 + (lane >> 4) * 4;
#pragma unroll
    for (int j = 0; j < 4; j++) {
      int gcol = n0 + wc * 64 + j * 16 + (lane & 15);
#pragma unroll
      for (int r = 0; r < 4; r++)
        ep.store(bz, grow + r, gcol, acc[i][j][r]);
    }
  }

  if constexpr (CSTAT) {
    // col c = wc*64 + j*16 + (lane&15); lanes {l, l^16, l^32, l^48} share a col.
    __shared__ float cred[2][128];
    __shared__ float sred[2][128];
    float cmv[4], lsum[4];
#pragma unroll
    for (int j = 0; j < 4; j++) {
      float m = acc[0][j][0];
#pragma unroll
      for (int i = 0; i < 4; i++)
#pragma unroll
        for (int r = 0; r < 4; r++) m = fmaxf(m, acc[i][j][r]);
      m = fmaxf(m, __shfl_xor(m, 16, 64));
      m = fmaxf(m, __shfl_xor(m, 32, 64));
      cmv[j] = m;                          // col max over this wave's 64 rows
    }
    if (lane < 16) {
#pragma unroll
      for (int j = 0; j < 4; j++) cred[wr][wc * 64 + j * 16 + lane] = cmv[j];
    }
    __syncthreads();
#pragma unroll
    for (int j = 0; j < 4; j++) {
      int c = wc * 64 + j * 16 + (lane & 15);
      float cm = fmaxf(cred[0][c], cred[1][c]);   // block col max (128 rows)
      float s = 0.f;
#pragma unroll
      for (int i = 0; i < 4; i++)
#pragma unroll
        for (int r = 0; r < 4; r++) s += __expf(acc[i][j][r] - cm);
      s += __shfl_xor(s, 16, 64);
      s += __shfl_xor(s, 32, 64);
      cmv[j] = cm; lsum[j] = s;
    }
    if (lane < 16) {
#pragma unroll
      for (int j = 0; j < 4; j++) sred[wr][wc * 64 + j * 16 + lane] = lsum[j];
    }
    __syncthreads();
    if (wr == 0 && lane < 16) {
      long sb = ((long)bz * 16 + by) * CES + n0;
#pragma unroll
      for (int j = 0; j < 4; j++) {
        int c = wc * 64 + j * 16 + lane;
        pmax[sb + c] = cmv[j];
        psum[sb + c] = sred[0][c] + sred[1][c];
      }
    }
  }
}

// ---------------- launch ----------------
extern "C" void kernel_launch(void* const* d_in, const int* in_sizes, int n_in,
                              void* d_out, int out_size, void* d_ws, size_t ws_size,
                              hipStream_t stream) {
  const float* x          = (const float*)d_in[0];
  const float* W_slot     = (const float*)d_in[1];
  const float* u_slot     = (const float*)d_in[2];
  const float* sigma_slot = (const float*)d_in[3];
  const float* W1         = (const float*)d_in[4];
  const float* b1         = (const float*)d_in[5];
  const float* u1         = (const float*)d_in[6];
  const float* sig1       = (const float*)d_in[7];
  const float* W2         = (const float*)d_in[8];
  const float* b2         = (const float*)d_in[9];
  const float* u2         = (const float*)d_in[10];
  const float* sig2       = (const float*)d_in[11];
  float* out = (float*)d_out;

  // ---- workspace overlays (peak ~202 MiB, proven footprint) ----
  char* ws = (char*)d_ws;
  size_t off = 0;
  auto alloc = [&](size_t bytes) -> char* {
    char* p = ws + off;
    off += (bytes + 255) & ~(size_t)255;
    return p;
  };
  float* t1s = (float*)alloc(4096 * 4);
  float* t1a = (float*)alloc(4 * 4096 * 4);
  float* t1b = (float*)alloc(4 * 1024 * 4);
  float* t2s = (float*)alloc(1024 * 4);
  float* t2a = (float*)alloc(4 * 1024 * 4);
  float* t2b = (float*)alloc(4 * 4096 * 4);
  float* scales = (float*)alloc(16 * 4);
  float* pmax   = (float*)alloc((size_t)CB * 16 * CES * 4);
  float* psum   = (float*)alloc((size_t)CB * 16 * CES * 4);
  float* cmax   = (float*)alloc((size_t)CB * CES * 4);
  float* csum   = (float*)alloc((size_t)CB * CES * 4);
  char* regAB   = alloc((size_t)CB * CN * CD * 2 * 2);                // 32 MiB
  char* regBB   = alloc((size_t)CB * CES * CD * 2 * 2);               // 32 MiB
  char* regL    = alloc((size_t)CB * CN * CES * 4);                   // 64 MiB
  char* regS    = alloc((size_t)CE * CB * CS * CD * 2);               // 16 MiB
  u16* W1b      = (u16*)alloc((size_t)CE * CH * CD * 2);              // 32 MiB
  u16* W2b      = (u16*)alloc((size_t)CE * CD * CH * 2);              // 32 MiB

  u16*   xh      = (u16*)regAB;                        // [b][n][d]
  u16*   xl      = (u16*)(regAB + (size_t)CB * CN * CD * 2);
  u16*   dispT   = (u16*)regAB;                        // [b][es][n]
  u16*   combineB= (u16*)regAB;                        // [b][n][es]
  u16*   seh     = (u16*)regBB;                        // [b][es][d]
  u16*   sel     = (u16*)(regBB + (size_t)CB * CES * CD * 2);
  u16*   xT      = (u16*)regBB;                        // [b][d][n]
  float* logits  = (float*)regL;                       // [b][n][es]
  u16*   hbuf    = (u16*)regL;                         // [e][2048][H]
  u16*   xmh     = (u16*)regL;                         // [(b,s)][d] 4 MiB
  u16*   xml     = (u16*)(regL + (size_t)CB * CS * CD * 2);
  u16*   wslh    = (u16*)(regL + (size_t)2 * CB * CS * CD * 2);  // [4096][1024] 8 MiB
  u16*   wsll    = (u16*)(regL + (size_t)2 * CB * CS * CD * 2 + (size_t)CE * CD * CD * 2);
  u16*   slotsB  = (u16*)regS;                         // [e][(b,si)][d]
  u16*   outbufT = (u16*)regS;                         // [b][d][es]

  // zero t2s..t2b in one span (consecutive 256-aligned allocs)
  hipMemsetAsync(t2s, 0, (size_t)((char*)t2b - (char*)t2s) + 4 * 4096 * 4, stream);

  // spectral scales (gemv_cols also emits bf16 weight planes)
  gemv_rows_k<<<dim3(4096 / 4, 1), 256, 0, stream>>>(W_slot, u_slot, t1s, 4096, 1024, 0);
  gemv_rows_k<<<dim3(4096 / 4, 4), 256, 0, stream>>>(W1, u1, t1a, CH, CD, CD);
  gemv_rows_k<<<dim3(1024 / 4, 4), 256, 0, stream>>>(W2, u2, t1b, CD, CH, CH);
  gemv_cols_k<<<dim3(1024 / 256, 4096 / 256, 1), 256, 0, stream>>>(W_slot, t1s, t2s, wslh, wsll, 4096, 1024);
  gemv_cols_k<<<dim3(1024 / 256, 4096 / 256, 4), 256, 0, stream>>>(W1, t1a, t2a, W1b, nullptr, CH, CD);
  gemv_cols_k<<<dim3(4096 / 256, 1024 / 256, 4), 256, 0, stream>>>(W2, t1b, t2b, W2b, nullptr, CD, CH);
  scale_all_k<<<9, 256, 0, stream>>>(t1s, t2s, t1a, t2a, t1b, t2b,
                                     sigma_slot, sig1, sig2, scales);

  // x hi/lo split + token-group-mean hi/lo split (single pass over x)
  xsplit_fused_k<<<(CB * CS * (CD / 8)) / 256, 256, 0, stream>>>(x, xh, xl, xmh, xml);

  // SE = (xm @ W_slot^T) * scale_slot, split-bf16 3-term -> SE hi/lo planes
  mgemm3_k<false><<<dim3(4096 / 128, 2048 / 128, 1), 256, 0, stream>>>(
      xmh, xml, 0L, CD, wslh, wsll, 0L, CD, MEpSESplit{seh, sel, scales}, CD,
      nullptr, nullptr);

  // logits[b] = x_b @ SE_b^T, split-bf16 3-term -> f32, + fused col stats
  mgemm3_k<true><<<dim3(CES / 128, CN / 128, CB), 256, 0, stream>>>(
      xh, xl, (long)CN * CD, CD, seh, sel, (long)CES * CD, CD,
      MEpLogits{logits}, CD, pmax, psum);

  // dispatch softmax stat combine (16 slabs of 128 rows)
  colstat_comb_k<<<(CB * CES) / 256, 256, 0, stream>>>(pmax, psum, cmax, csum);

  // dispT[b][es][n] = bf16(exp(lg - cmax))   (overwrites xh/xl; dead after logits)
  tr_f2b_k<<<dim3(CES / 32, CN / 32, CB), 256, 0, stream>>>(logits, dispT, cmax, CN, CES, 1);
  // xT[b][d][n] = bf16(x^T)                  (overwrites seh; dead after logits)
  tr_f2b_k<<<dim3(CD / 32, CN / 32, CB), 256, 0, stream>>>(x, xT, nullptr, CN, CD, 0);

  // slots: [b] dispT(2048 x K2048) @ xT(1024 x K2048)^T -> slotsB (bf16, /csum)
  // double-buffered prefetch <128,32>
  mgemm_db_k<128, 32><<<dim3(CD / 128, CES / 128, CB), 256, 0, stream>>>(
      dispT, (long)CES * CN, CN, xT, (long)CD * CN, CN, MEpSlots{slotsB, csum}, CN);

  // combineB[b][n][es] = bf16(softmax over es)   (overwrites dispT; dead)
  rowcomb_k<<<CB * CN, 256, 0, stream>>>(logits, combineB);

  // FFN1: [e] slotsB(2048 x K1024) @ W1b(4096 x K1024)^T -> hbuf (gelu, bf16)
  // (256x128 tile, 1024 blocks — proven r10/r11)
  mgemm_big_k<<<dim3(CH / 128, 2048 / 256, CE), 512, 0, stream>>>(
      slotsB, (long)2048 * CD, CD, W1b, (long)CH * CD, CD, MEpGelu{hbuf, scales, b1}, CD);

  // FFN2 (swapped, writes y^T directly): [e] W2b(1024 x K4096) @ hbuf(2048 x K4096)^T
  // -> outbufT[b][d][es] bf16 — double-buffered prefetch <128,32>
  mgemm_db_k<128, 32><<<dim3(2048 / 128, CD / 128, CE), 256, 0, stream>>>(
      W2b, (long)CD * CH, CH, hbuf, (long)2048 * CH, CH, MEpYT{outbufT, scales, b2}, CH);

  // final: [b] combineB(2048 x K2048) @ outbufT(1024 x K2048)^T -> out f32
  // double-buffered prefetch <128,32>
  mgemm_db_k<128, 32><<<dim3(CD / 128, CN / 128, CB), 256, 0, stream>>>(
      combineB, (long)CN * CES, CES, outbufT, (long)CD * CES, CES, MEpOut{out}, CES);

  (void)in_sizes; (void)n_in; (void)out_size; (void)ws_size;
}

// Round 15
// 810.713 us; speedup vs baseline: 1.0547x; 1.0240x over previous
//
#include <hip/hip_runtime.h>
#include <hip/hip_bf16.h>
#include <math.h>

constexpr int CB  = 4;     // batch
constexpr int CN  = 2048;  // tokens
constexpr int CD  = 1024;  // model dim
constexpr int CE  = 4;     // experts
constexpr int CS  = 512;   // slots per expert
constexpr int CH  = 4096;  // expert hidden
constexpr int CES = 2048;  // E*S

typedef unsigned short u16;
typedef unsigned int   u32;
typedef __bf16 bf16x8 __attribute__((ext_vector_type(8)));
typedef float  f32x4  __attribute__((ext_vector_type(4)));

__device__ __forceinline__ u16 f2bf(float x) {
  u32 u = __float_as_uint(x);
  u = (u + 0x7FFF + ((u >> 16) & 1)) >> 16;   // round-to-nearest-even
  return (u16)u;
}

__device__ __forceinline__ void gl2lds16(const void* g, void* l) {
  __builtin_amdgcn_global_load_lds(
      (const __attribute__((address_space(1))) void*)g,
      (__attribute__((address_space(3))) void*)l, 16, 0, 0);
}

// bijective XCD-aware block swizzle (all grids have nwg % 8 == 0)
__device__ __forceinline__ void xcd_swz(int& bx, int& by, int& bz) {
  u32 gx = gridDim.x, gy = gridDim.y;
  u32 w = blockIdx.x + gx * (blockIdx.y + gy * blockIdx.z);
  u32 nwg = gx * gy * gridDim.z;
  u32 q = nwg >> 3;
  u32 wg = (w & 7) * q + (w >> 3);
  bx = wg % gx;
  u32 r = wg / gx;
  by = r % gy;
  bz = r / gy;
}

// ---------------- spectral-norm scale kernels ----------------
// scale = sigma * ||W u|| / ||W^T (W u)||

__global__ __launch_bounds__(256) void gemv_rows_k(const float* __restrict__ W,
    const float* __restrict__ u, float* __restrict__ t1, int M, int K, int ustride) {
  int bi = blockIdx.y;
  int row = blockIdx.x * 4 + (threadIdx.x >> 6);
  int lane = threadIdx.x & 63;
  const float* Wr = W + ((long)bi * M + row) * K;
  const float* ub = u + (long)bi * ustride;
  float s = 0.f;
  for (int k = lane; k < K; k += 64) s += Wr[k] * ub[k];
#pragma unroll
  for (int off = 32; off; off >>= 1) s += __shfl_down(s, off, 64);
  if (lane == 0) t1[bi * M + row] = s;
}

// also emits bf16 conversion of W (and optional lo-plane split)
__global__ __launch_bounds__(256) void gemv_cols_k(const float* __restrict__ W,
    const float* __restrict__ t1, float* __restrict__ t2,
    u16* __restrict__ bh, u16* __restrict__ bl, int M, int K) {
  int bi = blockIdx.z;
  int k = blockIdx.x * 256 + threadIdx.x;
  int m0 = blockIdx.y * 256;
  const float* Wb = W + (long)bi * M * K;
  const float* tb = t1 + bi * M;
  u16* bhb = bh + (long)bi * M * K;
  u16* blb = bl ? bl + (long)bi * M * K : nullptr;
  float s = 0.f;
#pragma unroll 4
  for (int m = 0; m < 256; m++) {
    long idx = (long)(m0 + m) * K + k;
    float w = Wb[idx];
    s += w * tb[m0 + m];
    u16 h = f2bf(w);
    bhb[idx] = h;
    if (blb) blb[idx] = f2bf(w - __uint_as_float((u32)h << 16));
  }
  atomicAdd(&t2[bi * K + k], s);
}

// all 9 spectral scales in one launch: block 0 = W_slot, 1..4 = W1[e], 5..8 = W2[e]
__global__ __launch_bounds__(256) void scale_all_k(
    const float* __restrict__ t1s, const float* __restrict__ t2s,
    const float* __restrict__ t1a, const float* __restrict__ t2a,
    const float* __restrict__ t1b, const float* __restrict__ t2b,
    const float* __restrict__ sigs, const float* __restrict__ sig1,
    const float* __restrict__ sig2, float* __restrict__ scales) {
  int bi = blockIdx.x;
  const float *t1, *t2; float sg; float* o; int M, K;
  if (bi == 0)      { t1 = t1s;                 t2 = t2s;                 sg = sigs[0];     o = scales + 0;      M = 4096; K = 1024; }
  else if (bi < 5)  { int e = bi - 1; t1 = t1a + e * 4096; t2 = t2a + e * 1024; sg = sig1[e]; o = scales + 1 + e; M = 4096; K = 1024; }
  else              { int e = bi - 5; t1 = t1b + e * 1024; t2 = t2b + e * 4096; sg = sig2[e]; o = scales + 5 + e; M = 1024; K = 4096; }
  int tid = threadIdx.x;
  __shared__ float red[256];
  float s1 = 0.f;
  for (int i = tid; i < M; i += 256) { float v = t1[i]; s1 += v * v; }
  red[tid] = s1; __syncthreads();
  for (int w = 128; w; w >>= 1) { if (tid < w) red[tid] += red[tid + w]; __syncthreads(); }
  float n1 = red[0]; __syncthreads();
  float s2 = 0.f;
  for (int i = tid; i < K; i += 256) { float v = t2[i]; s2 += v * v; }
  red[tid] = s2; __syncthreads();
  for (int w = 128; w; w >>= 1) { if (tid < w) red[tid] += red[tid + w]; __syncthreads(); }
  if (tid == 0) o[0] = sg * sqrtf(n1 / red[0]);
}

// ---------------- fused x hi/lo split + token-group-mean hi/lo split ----------------
__global__ __launch_bounds__(256) void xsplit_fused_k(const float* __restrict__ x,
    u16* __restrict__ xh, u16* __restrict__ xl,
    u16* __restrict__ xmh, u16* __restrict__ xml) {
  int idx = blockIdx.x * 256 + threadIdx.x;      // b*S*(D/8) total
  int d8 = idx & (CD / 8 - 1);
  int si = (idx >> 7) & (CS - 1);
  int b  = idx >> 16;
  long rbase = ((long)(b * CN + si * 4)) * CD + d8 * 8;
  float vr[4][8];
#pragma unroll
  for (int r = 0; r < 4; r++) {
    float4 a = *(const float4*)(x + rbase + (long)r * CD);
    float4 c = *(const float4*)(x + rbase + (long)r * CD + 4);
    vr[r][0]=a.x; vr[r][1]=a.y; vr[r][2]=a.z; vr[r][3]=a.w;
    vr[r][4]=c.x; vr[r][5]=c.y; vr[r][6]=c.z; vr[r][7]=c.w;
  }
#pragma unroll
  for (int r = 0; r < 4; r++) {
    u16 oh[8], ol[8];
#pragma unroll
    for (int c = 0; c < 8; c++) {
      u16 h = f2bf(vr[r][c]);
      oh[c] = h;
      ol[c] = f2bf(vr[r][c] - __uint_as_float((u32)h << 16));
    }
    *(uint4*)(xh + rbase + (long)r * CD) = *(const uint4*)oh;
    *(uint4*)(xl + rbase + (long)r * CD) = *(const uint4*)ol;
  }
  long mbase = ((long)(b * CS + si)) * CD + d8 * 8;
  u16 oh[8], ol[8];
#pragma unroll
  for (int c = 0; c < 8; c++) {
    float v = 0.25f * (vr[0][c] + vr[1][c] + vr[2][c] + vr[3][c]);
    u16 h = f2bf(v);
    oh[c] = h;
    ol[c] = f2bf(v - __uint_as_float((u32)h << 16));
  }
  *(uint4*)(xmh + mbase) = *(const uint4*)oh;
  *(uint4*)(xml + mbase) = *(const uint4*)ol;
}

// ---------------- dispatch softmax stat combine (16 slabs of 128 rows) ----------------
__global__ __launch_bounds__(256) void colstat_comb_k(const float* __restrict__ pmax,
    const float* __restrict__ psum, float* __restrict__ cmax, float* __restrict__ csum) {
  int idx = blockIdx.x * 256 + threadIdx.x;   // b*CES
  int b = idx >> 11;
  int es = idx & (CES - 1);
  float m = -1e30f;
#pragma unroll
  for (int sl = 0; sl < 16; sl++) m = fmaxf(m, pmax[(b * 16 + sl) * CES + es]);
  float s = 0.f;
#pragma unroll
  for (int sl = 0; sl < 16; sl++)
    s += psum[(b * 16 + sl) * CES + es] * __expf(pmax[(b * 16 + sl) * CES + es] - m);
  cmax[idx] = m; csum[idx] = s;
}

// ---------------- fused combine softmax (over es) -> bf16 ----------------
__global__ __launch_bounds__(256) void rowcomb_k(const float* __restrict__ lg,
                                                 u16* __restrict__ outB) {
  __shared__ float red[8];
  long row = blockIdx.x;                       // b*CN + n
  const float* p = lg + row * CES + threadIdx.x * 8;
  float4 a = *(const float4*)p;
  float4 b = *(const float4*)(p + 4);
  float v[8] = {a.x, a.y, a.z, a.w, b.x, b.y, b.z, b.w};
  float m = v[0];
#pragma unroll
  for (int c = 1; c < 8; c++) m = fmaxf(m, v[c]);
#pragma unroll
  for (int off = 32; off; off >>= 1) m = fmaxf(m, __shfl_xor(m, off, 64));
  int wv = threadIdx.x >> 6;
  if ((threadIdx.x & 63) == 0) red[wv] = m;
  __syncthreads();
  m = fmaxf(fmaxf(red[0], red[1]), fmaxf(red[2], red[3]));
  float s = 0.f;
#pragma unroll
  for (int c = 0; c < 8; c++) { v[c] = __expf(v[c] - m); s += v[c]; }
#pragma unroll
  for (int off = 32; off; off >>= 1) s += __shfl_xor(s, off, 64);
  if ((threadIdx.x & 63) == 0) red[4 + wv] = s;
  __syncthreads();
  float inv = 1.f / (red[4] + red[5] + red[6] + red[7]);
  u16 o[8];
#pragma unroll
  for (int c = 0; c < 8; c++) o[c] = f2bf(v[c] * inv);
  *(uint4*)(outB + row * CES + threadIdx.x * 8) = *(const uint4*)o;
}

// in [z][R][C] f32 -> out [z][C][R] bf16; expmode: v = exp(v - sub[z*C + col])
__global__ __launch_bounds__(256) void tr_f2b_k(const float* __restrict__ in,
    u16* __restrict__ out, const float* __restrict__ sub, int R, int C, int expmode) {
  __shared__ u16 t[32][33];
  int z = blockIdx.z;
  long ibase = (long)z * R * C;
  int r0 = blockIdx.y * 32, c0 = blockIdx.x * 32;
  int tx = threadIdx.x & 31, ty = threadIdx.x >> 5;
  float cm = expmode ? sub[(long)z * C + c0 + tx] : 0.f;
  for (int rr = ty; rr < 32; rr += 8) {
    float v = in[ibase + (long)(r0 + rr) * C + c0 + tx];
    if (expmode) v = __expf(v - cm);
    t[tx][rr] = f2bf(v);
  }
  __syncthreads();
  for (int cc = ty; cc < 32; cc += 8)
    out[ibase + (long)(c0 + cc) * R + r0 + tx] = t[cc][tx];
}

// ---------------- epilogues ----------------
struct MEpSESplit {  // SE hi/lo planes [b][es][d], es = ei*512+si; m=(b,si), n=(ei,di)
  u16* hi; u16* lo; const float* scale;
  __device__ void store(int z, int m, int n, float v) const {
    v *= scale[0];
    int b = m >> 9, si = m & 511, ei = n >> 10, di = n & 1023;
    long o = ((long)(b * CES + ei * 512 + si)) * CD + di;
    u16 h = f2bf(v);
    hi[o] = h;
    lo[o] = f2bf(v - __uint_as_float((u32)h << 16));
  }
};
struct MEpLogits {   // logits[b][n][es] = v ; z=b, m=token, n=es
  float* lg;
  __device__ void store(int b, int m, int n, float v) const {
    lg[((long)(b * CN + m)) * CES + n] = v;
  }
};
struct MEpSlots {  // slotsB[e][b*512+si][d] = bf16(v / csum[b][es]); z=b, m=es
  u16* sb; const float* __restrict__ csum;
  __device__ void store(int b, int m, int n, float v) const {
    float inv = 1.f / csum[b * CES + m];
    int e = m >> 9, si = m & 511;
    sb[((long)(e * 2048 + b * 512 + si)) * CD + n] = f2bf(v * inv);
  }
};
struct MEpGelu {   // h[e][m][H] = bf16(gelu(v*sc1[e] + b1[e][n])); z=e, m=(b,si)
  // tanh-form GELU: |err vs exact| below bf16 rounding of h (verified r8/r9).
  u16* h; const float* __restrict__ scales; const float* __restrict__ b1;
  __device__ void store(int e, int m, int n, float v) const {
    float xg = v * scales[1 + e] + b1[e * CH + n];
    float t = xg * (0.7978845608f + 0.0356774081f * xg * xg);
    float ex = __expf(2.f * t);
    float th = 1.f - 2.f / (ex + 1.f);          // tanh(t), saturates correctly
    float g = 0.5f * xg * (1.f + th);
    h[((long)(e * 2048 + m)) * CH + n] = f2bf(g);
  }
};
struct MEpYT {     // outbufT[b][d][es] = bf16(v*sc2[e] + b2[e][m]); z=e, m=d, n=(b,si)
  u16* ot; const float* __restrict__ scales; const float* __restrict__ b2;
  __device__ void store(int e, int m, int n, float v) const {
    int b = n >> 9, si = n & 511;
    ot[((long)(b * CD + m)) * CES + e * 512 + si] = f2bf(v * scales[5 + e] + b2[e * CD + m]);
  }
};
struct MEpOut {    // out[b][n][d] = v (combine already has 1/rsum); z=b
  float* o;
  __device__ void store(int b, int m, int n, float v) const {
    o[((long)(b * CN + m)) * CD + n] = v;
  }
};

// ------ bf16 MFMA GEMM, 128xBN, 4 waves, db + COUNTED vmcnt (T4) ------
// Next-tile loads stay in flight across the barrier (never drain to 0 in the
// main loop). Raw s_barrier + sched_barrier(0) pins ordering (rule #18).
// Buffer reuse: S[cur] re-staged only at iter t+1, after barrier#2 of iter t.
template <int BN, int BK, class EP>
__global__ __launch_bounds__(256) void mgemm_db_k(const u16* __restrict__ A, long Azs, int ldA,
                                                  const u16* __restrict__ B, long Bzs, int ldB,
                                                  EP ep, int K) {
  constexpr int BM = 128;
  constexpr int FI = 4;
  constexpr int FJ = BN / 32;
  constexpr int RPL = 512 / BK;            // rows per 1KB load-group
  constexpr int NGRP = (BM + BN) / RPL;    // 1KB groups per K-step
  constexpr int GPW = NGRP / 4;            // gl2lds instructions per wave per stage
  static_assert(GPW == 4, "vmcnt literal below assumes 4 loads per stage");
  __shared__ __align__(16) u16 S[2][(BM + BN) * BK];
  int bx, by, bz;
  xcd_swz(bx, by, bz);
  const int tid = threadIdx.x;
  const int wid = tid >> 6, lane = tid & 63;
  const int m0 = by * BM, n0 = bx * BN;
  const u16* Az = A + (long)bz * Azs;
  const u16* Bz = B + (long)bz * Bzs;
  const int wr = wid >> 1, wc = wid & 1;
  const int lrow = lane / (BK / 8);        // row within load-group
  const int lk   = (lane % (BK / 8)) * 8;  // k offset within row

  auto stage = [&](int buf, int k0) {
#pragma unroll
    for (int g = 0; g < GPW; g++) {
      int grp = g * 4 + wid;
      int row = grp * RPL + lrow;          // A rows [0,BM), then B rows
      const u16* src = (row < BM)
          ? Az + (long)(m0 + row) * ldA + k0 + lk
          : Bz + (long)(n0 + row - BM) * ldB + k0 + lk;
      gl2lds16(src, (char*)S[buf] + grp * 1024);
    }
  };

  f32x4 acc[FI][FJ];
  f32x4 zero = {0.f, 0.f, 0.f, 0.f};
#pragma unroll
  for (int i = 0; i < FI; i++)
#pragma unroll
    for (int j = 0; j < FJ; j++) acc[i][j] = zero;

  stage(0, 0);
  int cur = 0;
  for (int k0 = 0; k0 < K; k0 += BK) {
    if (k0 + BK < K) {
      stage(cur ^ 1, k0 + BK);             // prefetch next tile
      asm volatile("s_waitcnt vmcnt(4)" ::: "memory");   // cur-tile done; next stays in flight
    } else {
      asm volatile("s_waitcnt vmcnt(0)" ::: "memory");   // final tile: full drain
    }
    __builtin_amdgcn_s_barrier();          // buffer cur complete for all waves
    __builtin_amdgcn_sched_barrier(0);
    const u16* Sc = S[cur];
#pragma unroll
    for (int kk2 = 0; kk2 < BK / 32; kk2++) {
      bf16x8 af[FI], bfr[FJ];
#pragma unroll
      for (int i = 0; i < FI; i++) {
        int arow = wr * 64 + i * 16 + (lane & 15);
        af[i] = *(const bf16x8*)&Sc[arow * BK + kk2 * 32 + (lane >> 4) * 8];
      }
#pragma unroll
      for (int j = 0; j < FJ; j++) {
        int brow = BM + wc * (BN / 2) + j * 16 + (lane & 15);
        bfr[j] = *(const bf16x8*)&Sc[brow * BK + kk2 * 32 + (lane >> 4) * 8];
      }
#pragma unroll
      for (int i = 0; i < FI; i++)
#pragma unroll
        for (int j = 0; j < FJ; j++)
          acc[i][j] = __builtin_amdgcn_mfma_f32_16x16x32_bf16(af[i], bfr[j], acc[i][j], 0, 0, 0);
    }
    __builtin_amdgcn_s_barrier();          // all waves done reading buffer cur
    __builtin_amdgcn_sched_barrier(0);     // keep next iter's stage below this point
    cur ^= 1;
  }
#pragma unroll
  for (int i = 0; i < FI; i++) {
    int grow = m0 + wr * 64 + i * 16 + (lane >> 4) * 4;
#pragma unroll
    for (int j = 0; j < FJ; j++) {
      int gcol = n0 + wc * (BN / 2) + j * 16 + (lane & 15);
#pragma unroll
      for (int r = 0; r < 4; r++)
        ep.store(bz, grow + r, gcol, acc[i][j][r]);
    }
  }
}

// ---------------- bf16 MFMA GEMM, 256x128 tile, 8 waves (proven r10/r11, FFN1) -------
template <class EP>
__global__ __launch_bounds__(512) void mgemm_big_k(const u16* __restrict__ A, long Azs, int ldA,
                                                   const u16* __restrict__ B, long Bzs, int ldB,
                                                   EP ep, int K) {
  constexpr int BM = 256, BN = 128, BK = 32;
  __shared__ __align__(16) u16 S[(BM + BN) * BK];   // 24 KiB
  int bx, by, bz;
  xcd_swz(bx, by, bz);
  const int tid = threadIdx.x;
  const int wid = tid >> 6, lane = tid & 63;
  const int m0 = by * BM, n0 = bx * BN;
  const u16* Az = A + (long)bz * Azs;
  const u16* Bz = B + (long)bz * Bzs;
  const int wr = wid >> 1, wc = wid & 1;
  const int lrow = lane >> 2;              // 16 rows per 1KB group
  const int lk   = (lane & 3) * 8;

  f32x4 acc[4][4];
  f32x4 zero = {0.f, 0.f, 0.f, 0.f};
#pragma unroll
  for (int i = 0; i < 4; i++)
#pragma unroll
    for (int j = 0; j < 4; j++) acc[i][j] = zero;

  for (int k0 = 0; k0 < K; k0 += BK) {
#pragma unroll
    for (int g = 0; g < 3; g++) {          // 24 groups / 8 waves
      int grp = g * 8 + wid;
      int row = grp * 16 + lrow;           // A rows [0,256), then B rows
      const u16* src = (row < BM)
          ? Az + (long)(m0 + row) * ldA + k0 + lk
          : Bz + (long)(n0 + row - BM) * ldB + k0 + lk;
      gl2lds16(src, (char*)S + grp * 1024);
    }
    __syncthreads();
    bf16x8 af[4], bfr[4];
#pragma unroll
    for (int i = 0; i < 4; i++) {
      int arow = wr * 64 + i * 16 + (lane & 15);
      af[i] = *(const bf16x8*)&S[arow * BK + (lane >> 4) * 8];
      int brow = BM + wc * 64 + i * 16 + (lane & 15);
      bfr[i] = *(const bf16x8*)&S[brow * BK + (lane >> 4) * 8];
    }
#pragma unroll
    for (int i = 0; i < 4; i++)
#pragma unroll
      for (int j = 0; j < 4; j++)
        acc[i][j] = __builtin_amdgcn_mfma_f32_16x16x32_bf16(af[i], bfr[j], acc[i][j], 0, 0, 0);
    __syncthreads();
  }
#pragma unroll
  for (int i = 0; i < 4; i++) {
    int grow = m0 + wr * 64 + i * 16 + (lane >> 4) * 4;
#pragma unroll
    for (int j = 0; j < 4; j++) {
      int gcol = n0 + wc * 64 + j * 16 + (lane & 15);
#pragma unroll
      for (int r = 0; r < 4; r++)
        ep.store(bz, grow + r, gcol, acc[i][j][r]);
    }
  }
}

// ---------------- split-bf16 3-term GEMM, 128^2 tile, 4 waves (proven r9) ----------
// CSTAT: emit per-block (128-row slab) column max/expsum into
// pmax/psum[(bz*16+by)*CES + n0 + c]  (dispatch-softmax partial stats).
template <bool CSTAT, class EP>
__global__ __launch_bounds__(256) void mgemm3_k(const u16* __restrict__ Ah,
                                                const u16* __restrict__ Al, long Azs, int ldA,
                                                const u16* __restrict__ Bh,
                                                const u16* __restrict__ Bl, long Bzs, int ldB,
                                                EP ep, int K,
                                                float* __restrict__ pmax,
                                                float* __restrict__ psum) {
  constexpr int BK = 32;
  __shared__ __align__(16) u16 Ahs[128 * BK];
  __shared__ __align__(16) u16 Als[128 * BK];
  __shared__ __align__(16) u16 Bhs[128 * BK];
  __shared__ __align__(16) u16 Bls[128 * BK];
  int bx, by, bz;
  xcd_swz(bx, by, bz);
  const int tid = threadIdx.x;
  const int wid = tid >> 6, lane = tid & 63;
  const int m0 = by * 128, n0 = bx * 128;
  const u16* Ahz = Ah + (long)bz * Azs;
  const u16* Alz = Al + (long)bz * Azs;
  const u16* Bhz = Bh + (long)bz * Bzs;
  const u16* Blz = Bl + (long)bz * Bzs;
  const int wr = wid >> 1, wc = wid & 1;
  const int srow = lane >> 2;
  const int sk8  = (lane & 3) * 8;

  f32x4 acc[4][4];
  f32x4 zero = {0.f, 0.f, 0.f, 0.f};
#pragma unroll
  for (int i = 0; i < 4; i++)
#pragma unroll
    for (int j = 0; j < 4; j++) acc[i][j] = zero;

  for (int k0 = 0; k0 < K; k0 += BK) {
#pragma unroll
    for (int i = 0; i < 2; i++) {
      int chunk = i * 4 + wid;
      int r = chunk * 16 + srow;
      long ao = (long)(m0 + r) * ldA + k0 + sk8;
      long bo = (long)(n0 + r) * ldB + k0 + sk8;
      gl2lds16(Ahz + ao, (char*)Ahs + chunk * 1024);
      gl2lds16(Alz + ao, (char*)Als + chunk * 1024);
      gl2lds16(Bhz + bo, (char*)Bhs + chunk * 1024);
      gl2lds16(Blz + bo, (char*)Bls + chunk * 1024);
    }
    __syncthreads();
    bf16x8 ah[4], al[4], bh[4], bl[4];
#pragma unroll
    for (int i = 0; i < 4; i++) {
      int arow = wr * 64 + i * 16 + (lane & 15);
      int aoff = arow * BK + (lane >> 4) * 8;
      ah[i] = *(const bf16x8*)&Ahs[aoff];
      al[i] = *(const bf16x8*)&Als[aoff];
      int brow = wc * 64 + i * 16 + (lane & 15);
      int boff = brow * BK + (lane >> 4) * 8;
      bh[i] = *(const bf16x8*)&Bhs[boff];
      bl[i] = *(const bf16x8*)&Bls[boff];
    }
#pragma unroll
    for (int i = 0; i < 4; i++)
#pragma unroll
      for (int j = 0; j < 4; j++) {
        acc[i][j] = __builtin_amdgcn_mfma_f32_16x16x32_bf16(ah[i], bh[j], acc[i][j], 0, 0, 0);
        acc[i][j] = __builtin_amdgcn_mfma_f32_16x16x32_bf16(al[i], bh[j], acc[i][j], 0, 0, 0);
        acc[i][j] = __builtin_amdgcn_mfma_f32_16x16x32_bf16(ah[i], bl[j], acc[i][j], 0, 0, 0);
      }
    __syncthreads();
  }
#pragma unroll
  for (int i = 0; i < 4; i++) {
    int grow = m0 + wr * 64 + i * 16 + (lane >> 4) * 4;
#pragma unroll
    for (int j = 0; j < 4; j++) {
      int gcol = n0 + wc * 64 + j * 16 + (lane & 15);
#pragma unroll
      for (int r = 0; r < 4; r++)
        ep.store(bz, grow + r, gcol, acc[i][j][r]);
    }
  }

  if constexpr (CSTAT) {
    // col c = wc*64 + j*16 + (lane&15); lanes {l, l^16, l^32, l^48} share a col.
    __shared__ float cred[2][128];
    __shared__ float sred[2][128];
    float cmv[4], lsum[4];
#pragma unroll
    for (int j = 0; j < 4; j++) {
      float m = acc[0][j][0];
#pragma unroll
      for (int i = 0; i < 4; i++)
#pragma unroll
        for (int r = 0; r < 4; r++) m = fmaxf(m, acc[i][j][r]);
      m = fmaxf(m, __shfl_xor(m, 16, 64));
      m = fmaxf(m, __shfl_xor(m, 32, 64));
      cmv[j] = m;                          // col max over this wave's 64 rows
    }
    if (lane < 16) {
#pragma unroll
      for (int j = 0; j < 4; j++) cred[wr][wc * 64 + j * 16 + lane] = cmv[j];
    }
    __syncthreads();
#pragma unroll
    for (int j = 0; j < 4; j++) {
      int c = wc * 64 + j * 16 + (lane & 15);
      float cm = fmaxf(cred[0][c], cred[1][c]);   // block col max (128 rows)
      float s = 0.f;
#pragma unroll
      for (int i = 0; i < 4; i++)
#pragma unroll
        for (int r = 0; r < 4; r++) s += __expf(acc[i][j][r] - cm);
      s += __shfl_xor(s, 16, 64);
      s += __shfl_xor(s, 32, 64);
      cmv[j] = cm; lsum[j] = s;
    }
    if (lane < 16) {
#pragma unroll
      for (int j = 0; j < 4; j++) sred[wr][wc * 64 + j * 16 + lane] = lsum[j];
    }
    __syncthreads();
    if (wr == 0 && lane < 16) {
      long sb = ((long)bz * 16 + by) * CES + n0;
#pragma unroll
      for (int j = 0; j < 4; j++) {
        int c = wc * 64 + j * 16 + lane;
        pmax[sb + c] = cmv[j];
        psum[sb + c] = sred[0][c] + sred[1][c];
      }
    }
  }
}

// ---------------- launch ----------------
extern "C" void kernel_launch(void* const* d_in, const int* in_sizes, int n_in,
                              void* d_out, int out_size, void* d_ws, size_t ws_size,
                              hipStream_t stream) {
  const float* x          = (const float*)d_in[0];
  const float* W_slot     = (const float*)d_in[1];
  const float* u_slot     = (const float*)d_in[2];
  const float* sigma_slot = (const float*)d_in[3];
  const float* W1         = (const float*)d_in[4];
  const float* b1         = (const float*)d_in[5];
  const float* u1         = (const float*)d_in[6];
  const float* sig1       = (const float*)d_in[7];
  const float* W2         = (const float*)d_in[8];
  const float* b2         = (const float*)d_in[9];
  const float* u2         = (const float*)d_in[10];
  const float* sig2       = (const float*)d_in[11];
  float* out = (float*)d_out;

  // ---- workspace overlays (peak ~202 MiB, proven footprint) ----
  char* ws = (char*)d_ws;
  size_t off = 0;
  auto alloc = [&](size_t bytes) -> char* {
    char* p = ws + off;
    off += (bytes + 255) & ~(size_t)255;
    return p;
  };
  float* t1s = (float*)alloc(4096 * 4);
  float* t1a = (float*)alloc(4 * 4096 * 4);
  float* t1b = (float*)alloc(4 * 1024 * 4);
  float* t2s = (float*)alloc(1024 * 4);
  float* t2a = (float*)alloc(4 * 1024 * 4);
  float* t2b = (float*)alloc(4 * 4096 * 4);
  float* scales = (float*)alloc(16 * 4);
  float* pmax   = (float*)alloc((size_t)CB * 16 * CES * 4);
  float* psum   = (float*)alloc((size_t)CB * 16 * CES * 4);
  float* cmax   = (float*)alloc((size_t)CB * CES * 4);
  float* csum   = (float*)alloc((size_t)CB * CES * 4);
  char* regAB   = alloc((size_t)CB * CN * CD * 2 * 2);                // 32 MiB
  char* regBB   = alloc((size_t)CB * CES * CD * 2 * 2);               // 32 MiB
  char* regL    = alloc((size_t)CB * CN * CES * 4);                   // 64 MiB
  char* regS    = alloc((size_t)CE * CB * CS * CD * 2);               // 16 MiB
  u16* W1b      = (u16*)alloc((size_t)CE * CH * CD * 2);              // 32 MiB
  u16* W2b      = (u16*)alloc((size_t)CE * CD * CH * 2);              // 32 MiB

  u16*   xh      = (u16*)regAB;                        // [b][n][d]
  u16*   xl      = (u16*)(regAB + (size_t)CB * CN * CD * 2);
  u16*   dispT   = (u16*)regAB;                        // [b][es][n]
  u16*   combineB= (u16*)regAB;                        // [b][n][es]
  u16*   seh     = (u16*)regBB;                        // [b][es][d]
  u16*   sel     = (u16*)(regBB + (size_t)CB * CES * CD * 2);
  u16*   xT      = (u16*)regBB;                        // [b][d][n]
  float* logits  = (float*)regL;                       // [b][n][es]
  u16*   hbuf    = (u16*)regL;                         // [e][2048][H]
  u16*   xmh     = (u16*)regL;                         // [(b,s)][d] 4 MiB
  u16*   xml     = (u16*)(regL + (size_t)CB * CS * CD * 2);
  u16*   wslh    = (u16*)(regL + (size_t)2 * CB * CS * CD * 2);  // [4096][1024] 8 MiB
  u16*   wsll    = (u16*)(regL + (size_t)2 * CB * CS * CD * 2 + (size_t)CE * CD * CD * 2);
  u16*   slotsB  = (u16*)regS;                         // [e][(b,si)][d]
  u16*   outbufT = (u16*)regS;                         // [b][d][es]

  // zero t2s..t2b in one span (consecutive 256-aligned allocs)
  hipMemsetAsync(t2s, 0, (size_t)((char*)t2b - (char*)t2s) + 4 * 4096 * 4, stream);

  // spectral scales (gemv_cols also emits bf16 weight planes)
  gemv_rows_k<<<dim3(4096 / 4, 1), 256, 0, stream>>>(W_slot, u_slot, t1s, 4096, 1024, 0);
  gemv_rows_k<<<dim3(4096 / 4, 4), 256, 0, stream>>>(W1, u1, t1a, CH, CD, CD);
  gemv_rows_k<<<dim3(1024 / 4, 4), 256, 0, stream>>>(W2, u2, t1b, CD, CH, CH);
  gemv_cols_k<<<dim3(1024 / 256, 4096 / 256, 1), 256, 0, stream>>>(W_slot, t1s, t2s, wslh, wsll, 4096, 1024);
  gemv_cols_k<<<dim3(1024 / 256, 4096 / 256, 4), 256, 0, stream>>>(W1, t1a, t2a, W1b, nullptr, CH, CD);
  gemv_cols_k<<<dim3(4096 / 256, 1024 / 256, 4), 256, 0, stream>>>(W2, t1b, t2b, W2b, nullptr, CD, CH);
  scale_all_k<<<9, 256, 0, stream>>>(t1s, t2s, t1a, t2a, t1b, t2b,
                                     sigma_slot, sig1, sig2, scales);

  // x hi/lo split + token-group-mean hi/lo split (single pass over x)
  xsplit_fused_k<<<(CB * CS * (CD / 8)) / 256, 256, 0, stream>>>(x, xh, xl, xmh, xml);

  // SE = (xm @ W_slot^T) * scale_slot, split-bf16 3-term -> SE hi/lo planes
  mgemm3_k<false><<<dim3(4096 / 128, 2048 / 128, 1), 256, 0, stream>>>(
      xmh, xml, 0L, CD, wslh, wsll, 0L, CD, MEpSESplit{seh, sel, scales}, CD,
      nullptr, nullptr);

  // logits[b] = x_b @ SE_b^T, split-bf16 3-term -> f32, + fused col stats
  mgemm3_k<true><<<dim3(CES / 128, CN / 128, CB), 256, 0, stream>>>(
      xh, xl, (long)CN * CD, CD, seh, sel, (long)CES * CD, CD,
      MEpLogits{logits}, CD, pmax, psum);

  // dispatch softmax stat combine (16 slabs of 128 rows)
  colstat_comb_k<<<(CB * CES) / 256, 256, 0, stream>>>(pmax, psum, cmax, csum);

  // dispT[b][es][n] = bf16(exp(lg - cmax))   (overwrites xh/xl; dead after logits)
  tr_f2b_k<<<dim3(CES / 32, CN / 32, CB), 256, 0, stream>>>(logits, dispT, cmax, CN, CES, 1);
  // xT[b][d][n] = bf16(x^T)                  (overwrites seh; dead after logits)
  tr_f2b_k<<<dim3(CD / 32, CN / 32, CB), 256, 0, stream>>>(x, xT, nullptr, CN, CD, 0);

  // slots: [b] dispT(2048 x K2048) @ xT(1024 x K2048)^T -> slotsB (bf16, /csum)
  mgemm_db_k<128, 32><<<dim3(CD / 128, CES / 128, CB), 256, 0, stream>>>(
      dispT, (long)CES * CN, CN, xT, (long)CD * CN, CN, MEpSlots{slotsB, csum}, CN);

  // combineB[b][n][es] = bf16(softmax over es)   (overwrites dispT; dead)
  rowcomb_k<<<CB * CN, 256, 0, stream>>>(logits, combineB);

  // FFN1: [e] slotsB(2048 x K1024) @ W1b(4096 x K1024)^T -> hbuf (gelu, bf16)
  mgemm_big_k<<<dim3(CH / 128, 2048 / 256, CE), 512, 0, stream>>>(
      slotsB, (long)2048 * CD, CD, W1b, (long)CH * CD, CD, MEpGelu{hbuf, scales, b1}, CD);

  // FFN2 (swapped, writes y^T directly): [e] W2b(1024 x K4096) @ hbuf(2048 x K4096)^T
  mgemm_db_k<128, 32><<<dim3(2048 / 128, CD / 128, CE), 256, 0, stream>>>(
      W2b, (long)CD * CH, CH, hbuf, (long)2048 * CH, CH, MEpYT{outbufT, scales, b2}, CH);

  // final: [b] combineB(2048 x K2048) @ outbufT(1024 x K2048)^T -> out f32
  mgemm_db_k<128, 32><<<dim3(CD / 128, CN / 128, CB), 256, 0, stream>>>(
      combineB, (long)CN * CES, CES, outbufT, (long)CD * CES, CES, MEpOut{out}, CES);

  (void)in_sizes; (void)n_in; (void)out_size; (void)ws_size;
}

// Round 16
// 810.299 us; speedup vs baseline: 1.0552x; 1.0005x over previous
//
#include <hip/hip_runtime.h>
#include <hip/hip_bf16.h>
#include <math.h>

constexpr int CB  = 4;     // batch
constexpr int CN  = 2048;  // tokens
constexpr int CD  = 1024;  // model dim
constexpr int CE  = 4;     // experts
constexpr int CS  = 512;   // slots per expert
constexpr int CH  = 4096;  // expert hidden
constexpr int CES = 2048;  // E*S

typedef unsigned short u16;
typedef unsigned int   u32;
typedef __bf16 bf16x8 __attribute__((ext_vector_type(8)));
typedef float  f32x4  __attribute__((ext_vector_type(4)));

__device__ __forceinline__ u16 f2bf(float x) {
  u32 u = __float_as_uint(x);
  u = (u + 0x7FFF + ((u >> 16) & 1)) >> 16;   // round-to-nearest-even
  return (u16)u;
}

__device__ __forceinline__ void gl2lds16(const void* g, void* l) {
  __builtin_amdgcn_global_load_lds(
      (const __attribute__((address_space(1))) void*)g,
      (__attribute__((address_space(3))) void*)l, 16, 0, 0);
}

// bijective XCD-aware block swizzle (all grids have nwg % 8 == 0)
__device__ __forceinline__ void xcd_swz(int& bx, int& by, int& bz) {
  u32 gx = gridDim.x, gy = gridDim.y;
  u32 w = blockIdx.x + gx * (blockIdx.y + gy * blockIdx.z);
  u32 nwg = gx * gy * gridDim.z;
  u32 q = nwg >> 3;
  u32 wg = (w & 7) * q + (w >> 3);
  bx = wg % gx;
  u32 r = wg / gx;
  by = r % gy;
  bz = r / gy;
}

// ---------------- spectral-norm scale kernels ----------------
// scale = sigma * ||W u|| / ||W^T (W u)||

__global__ __launch_bounds__(256) void gemv_rows_k(const float* __restrict__ W,
    const float* __restrict__ u, float* __restrict__ t1, int M, int K, int ustride) {
  int bi = blockIdx.y;
  int row = blockIdx.x * 4 + (threadIdx.x >> 6);
  int lane = threadIdx.x & 63;
  const float* Wr = W + ((long)bi * M + row) * K;
  const float* ub = u + (long)bi * ustride;
  float s = 0.f;
  for (int k = lane; k < K; k += 64) s += Wr[k] * ub[k];
#pragma unroll
  for (int off = 32; off; off >>= 1) s += __shfl_down(s, off, 64);
  if (lane == 0) t1[bi * M + row] = s;
}

// also emits bf16 conversion of W (and optional lo-plane split)
__global__ __launch_bounds__(256) void gemv_cols_k(const float* __restrict__ W,
    const float* __restrict__ t1, float* __restrict__ t2,
    u16* __restrict__ bh, u16* __restrict__ bl, int M, int K) {
  int bi = blockIdx.z;
  int k = blockIdx.x * 256 + threadIdx.x;
  int m0 = blockIdx.y * 256;
  const float* Wb = W + (long)bi * M * K;
  const float* tb = t1 + bi * M;
  u16* bhb = bh + (long)bi * M * K;
  u16* blb = bl ? bl + (long)bi * M * K : nullptr;
  float s = 0.f;
#pragma unroll 4
  for (int m = 0; m < 256; m++) {
    long idx = (long)(m0 + m) * K + k;
    float w = Wb[idx];
    s += w * tb[m0 + m];
    u16 h = f2bf(w);
    bhb[idx] = h;
    if (blb) blb[idx] = f2bf(w - __uint_as_float((u32)h << 16));
  }
  atomicAdd(&t2[bi * K + k], s);
}

// all 9 spectral scales in one launch: block 0 = W_slot, 1..4 = W1[e], 5..8 = W2[e]
__global__ __launch_bounds__(256) void scale_all_k(
    const float* __restrict__ t1s, const float* __restrict__ t2s,
    const float* __restrict__ t1a, const float* __restrict__ t2a,
    const float* __restrict__ t1b, const float* __restrict__ t2b,
    const float* __restrict__ sigs, const float* __restrict__ sig1,
    const float* __restrict__ sig2, float* __restrict__ scales) {
  int bi = blockIdx.x;
  const float *t1, *t2; float sg; float* o; int M, K;
  if (bi == 0)      { t1 = t1s;                 t2 = t2s;                 sg = sigs[0];     o = scales + 0;      M = 4096; K = 1024; }
  else if (bi < 5)  { int e = bi - 1; t1 = t1a + e * 4096; t2 = t2a + e * 1024; sg = sig1[e]; o = scales + 1 + e; M = 4096; K = 1024; }
  else              { int e = bi - 5; t1 = t1b + e * 1024; t2 = t2b + e * 4096; sg = sig2[e]; o = scales + 5 + e; M = 1024; K = 4096; }
  int tid = threadIdx.x;
  __shared__ float red[256];
  float s1 = 0.f;
  for (int i = tid; i < M; i += 256) { float v = t1[i]; s1 += v * v; }
  red[tid] = s1; __syncthreads();
  for (int w = 128; w; w >>= 1) { if (tid < w) red[tid] += red[tid + w]; __syncthreads(); }
  float n1 = red[0]; __syncthreads();
  float s2 = 0.f;
  for (int i = tid; i < K; i += 256) { float v = t2[i]; s2 += v * v; }
  red[tid] = s2; __syncthreads();
  for (int w = 128; w; w >>= 1) { if (tid < w) red[tid] += red[tid + w]; __syncthreads(); }
  if (tid == 0) o[0] = sg * sqrtf(n1 / red[0]);
}

// ---------------- fused x hi/lo split + token-group-mean hi/lo split ----------------
__global__ __launch_bounds__(256) void xsplit_fused_k(const float* __restrict__ x,
    u16* __restrict__ xh, u16* __restrict__ xl,
    u16* __restrict__ xmh, u16* __restrict__ xml) {
  int idx = blockIdx.x * 256 + threadIdx.x;      // b*S*(D/8) total
  int d8 = idx & (CD / 8 - 1);
  int si = (idx >> 7) & (CS - 1);
  int b  = idx >> 16;
  long rbase = ((long)(b * CN + si * 4)) * CD + d8 * 8;
  float vr[4][8];
#pragma unroll
  for (int r = 0; r < 4; r++) {
    float4 a = *(const float4*)(x + rbase + (long)r * CD);
    float4 c = *(const float4*)(x + rbase + (long)r * CD + 4);
    vr[r][0]=a.x; vr[r][1]=a.y; vr[r][2]=a.z; vr[r][3]=a.w;
    vr[r][4]=c.x; vr[r][5]=c.y; vr[r][6]=c.z; vr[r][7]=c.w;
  }
#pragma unroll
  for (int r = 0; r < 4; r++) {
    u16 oh[8], ol[8];
#pragma unroll
    for (int c = 0; c < 8; c++) {
      u16 h = f2bf(vr[r][c]);
      oh[c] = h;
      ol[c] = f2bf(vr[r][c] - __uint_as_float((u32)h << 16));
    }
    *(uint4*)(xh + rbase + (long)r * CD) = *(const uint4*)oh;
    *(uint4*)(xl + rbase + (long)r * CD) = *(const uint4*)ol;
  }
  long mbase = ((long)(b * CS + si)) * CD + d8 * 8;
  u16 oh[8], ol[8];
#pragma unroll
  for (int c = 0; c < 8; c++) {
    float v = 0.25f * (vr[0][c] + vr[1][c] + vr[2][c] + vr[3][c]);
    u16 h = f2bf(v);
    oh[c] = h;
    ol[c] = f2bf(v - __uint_as_float((u32)h << 16));
  }
  *(uint4*)(xmh + mbase) = *(const uint4*)oh;
  *(uint4*)(xml + mbase) = *(const uint4*)ol;
}

// ---------------- dispatch softmax stat combine (16 slabs of 128 rows) ----------------
__global__ __launch_bounds__(256) void colstat_comb_k(const float* __restrict__ pmax,
    const float* __restrict__ psum, float* __restrict__ cmax, float* __restrict__ csum) {
  int idx = blockIdx.x * 256 + threadIdx.x;   // b*CES
  int b = idx >> 11;
  int es = idx & (CES - 1);
  float m = -1e30f;
#pragma unroll
  for (int sl = 0; sl < 16; sl++) m = fmaxf(m, pmax[(b * 16 + sl) * CES + es]);
  float s = 0.f;
#pragma unroll
  for (int sl = 0; sl < 16; sl++)
    s += psum[(b * 16 + sl) * CES + es] * __expf(pmax[(b * 16 + sl) * CES + es] - m);
  cmax[idx] = m; csum[idx] = s;
}

// ---------------- fused combine softmax (over es) -> bf16 ----------------
__global__ __launch_bounds__(256) void rowcomb_k(const float* __restrict__ lg,
                                                 u16* __restrict__ outB) {
  __shared__ float red[8];
  long row = blockIdx.x;                       // b*CN + n
  const float* p = lg + row * CES + threadIdx.x * 8;
  float4 a = *(const float4*)p;
  float4 b = *(const float4*)(p + 4);
  float v[8] = {a.x, a.y, a.z, a.w, b.x, b.y, b.z, b.w};
  float m = v[0];
#pragma unroll
  for (int c = 1; c < 8; c++) m = fmaxf(m, v[c]);
#pragma unroll
  for (int off = 32; off; off >>= 1) m = fmaxf(m, __shfl_xor(m, off, 64));
  int wv = threadIdx.x >> 6;
  if ((threadIdx.x & 63) == 0) red[wv] = m;
  __syncthreads();
  m = fmaxf(fmaxf(red[0], red[1]), fmaxf(red[2], red[3]));
  float s = 0.f;
#pragma unroll
  for (int c = 0; c < 8; c++) { v[c] = __expf(v[c] - m); s += v[c]; }
#pragma unroll
  for (int off = 32; off; off >>= 1) s += __shfl_xor(s, off, 64);
  if ((threadIdx.x & 63) == 0) red[4 + wv] = s;
  __syncthreads();
  float inv = 1.f / (red[4] + red[5] + red[6] + red[7]);
  u16 o[8];
#pragma unroll
  for (int c = 0; c < 8; c++) o[c] = f2bf(v[c] * inv);
  *(uint4*)(outB + row * CES + threadIdx.x * 8) = *(const uint4*)o;
}

// in [z][R][C] f32 -> out [z][C][R] bf16; expmode: v = exp(v - sub[z*C + col])
__global__ __launch_bounds__(256) void tr_f2b_k(const float* __restrict__ in,
    u16* __restrict__ out, const float* __restrict__ sub, int R, int C, int expmode) {
  __shared__ u16 t[32][33];
  int z = blockIdx.z;
  long ibase = (long)z * R * C;
  int r0 = blockIdx.y * 32, c0 = blockIdx.x * 32;
  int tx = threadIdx.x & 31, ty = threadIdx.x >> 5;
  float cm = expmode ? sub[(long)z * C + c0 + tx] : 0.f;
  for (int rr = ty; rr < 32; rr += 8) {
    float v = in[ibase + (long)(r0 + rr) * C + c0 + tx];
    if (expmode) v = __expf(v - cm);
    t[tx][rr] = f2bf(v);
  }
  __syncthreads();
  for (int cc = ty; cc < 32; cc += 8)
    out[ibase + (long)(c0 + cc) * R + r0 + tx] = t[cc][tx];
}

// ---------------- epilogues ----------------
struct MEpSESplit {  // SE hi/lo planes [b][es][d], es = ei*512+si; m=(b,si), n=(ei,di)
  u16* hi; u16* lo; const float* scale;
  __device__ void store(int z, int m, int n, float v) const {
    v *= scale[0];
    int b = m >> 9, si = m & 511, ei = n >> 10, di = n & 1023;
    long o = ((long)(b * CES + ei * 512 + si)) * CD + di;
    u16 h = f2bf(v);
    hi[o] = h;
    lo[o] = f2bf(v - __uint_as_float((u32)h << 16));
  }
};
struct MEpLogits {   // logits[b][n][es] = v ; z=b, m=token, n=es
  float* lg;
  __device__ void store(int b, int m, int n, float v) const {
    lg[((long)(b * CN + m)) * CES + n] = v;
  }
};
struct MEpSlots {  // slotsB[e][b*512+si][d] = bf16(v / csum[b][es]); z=b, m=es
  u16* sb; const float* __restrict__ csum;
  __device__ void store(int b, int m, int n, float v) const {
    float inv = 1.f / csum[b * CES + m];
    int e = m >> 9, si = m & 511;
    sb[((long)(e * 2048 + b * 512 + si)) * CD + n] = f2bf(v * inv);
  }
};
struct MEpGelu {   // h[e][m][H] = bf16(gelu(v*sc1[e] + b1[e][n])); z=e, m=(b,si)
  // tanh-form GELU: |err vs exact| below bf16 rounding of h (verified r8/r9).
  u16* h; const float* __restrict__ scales; const float* __restrict__ b1;
  __device__ void store(int e, int m, int n, float v) const {
    float xg = v * scales[1 + e] + b1[e * CH + n];
    float t = xg * (0.7978845608f + 0.0356774081f * xg * xg);
    float ex = __expf(2.f * t);
    float th = 1.f - 2.f / (ex + 1.f);          // tanh(t), saturates correctly
    float g = 0.5f * xg * (1.f + th);
    h[((long)(e * 2048 + m)) * CH + n] = f2bf(g);
  }
};
struct MEpYT {     // outbufT[b][d][es] = bf16(v*sc2[e] + b2[e][m]); z=e, m=d, n=(b,si)
  u16* ot; const float* __restrict__ scales; const float* __restrict__ b2;
  __device__ void store(int e, int m, int n, float v) const {
    int b = n >> 9, si = n & 511;
    ot[((long)(b * CD + m)) * CES + e * 512 + si] = f2bf(v * scales[5 + e] + b2[e * CD + m]);
  }
};
struct MEpOut {    // out[b][n][d] = v (combine already has 1/rsum); z=b
  float* o;
  __device__ void store(int b, int m, int n, float v) const {
    o[((long)(b * CN + m)) * CD + n] = v;
  }
};

// ------ bf16 MFMA GEMM, 128xBN, 4 waves, 3-DEEP pipeline + counted vmcnt (T3/T4) ------
// Two stages stay in flight across the wait: vmcnt(8) = 2 stages x 4 loads.
// FIFO completion (m135) => oldest stage (cur) complete. Buffer cur_t re-staged
// only at t+1, after barrier#2 of t. Grid-limited at 2 blocks/CU, so 48 KB LDS
// does not reduce occupancy.
template <int BN, int BK, class EP>
__global__ __launch_bounds__(256) void mgemm_db_k(const u16* __restrict__ A, long Azs, int ldA,
                                                  const u16* __restrict__ B, long Bzs, int ldB,
                                                  EP ep, int K) {
  constexpr int BM = 128;
  constexpr int FI = 4;
  constexpr int FJ = BN / 32;
  constexpr int RPL = 512 / BK;            // rows per 1KB load-group
  constexpr int NGRP = (BM + BN) / RPL;    // 1KB groups per K-step
  constexpr int GPW = NGRP / 4;            // gl2lds instructions per wave per stage
  static_assert(GPW == 4, "vmcnt literals below assume 4 loads per stage");
  __shared__ __align__(16) u16 S[3][(BM + BN) * BK];
  int bx, by, bz;
  xcd_swz(bx, by, bz);
  const int tid = threadIdx.x;
  const int wid = tid >> 6, lane = tid & 63;
  const int m0 = by * BM, n0 = bx * BN;
  const u16* Az = A + (long)bz * Azs;
  const u16* Bz = B + (long)bz * Bzs;
  const int wr = wid >> 1, wc = wid & 1;
  const int lrow = lane / (BK / 8);        // row within load-group
  const int lk   = (lane % (BK / 8)) * 8;  // k offset within row

  auto stage = [&](int buf, int k0) {
#pragma unroll
    for (int g = 0; g < GPW; g++) {
      int grp = g * 4 + wid;
      int row = grp * RPL + lrow;          // A rows [0,BM), then B rows
      const u16* src = (row < BM)
          ? Az + (long)(m0 + row) * ldA + k0 + lk
          : Bz + (long)(n0 + row - BM) * ldB + k0 + lk;
      gl2lds16(src, (char*)S[buf] + grp * 1024);
    }
  };

  f32x4 acc[FI][FJ];
  f32x4 zero = {0.f, 0.f, 0.f, 0.f};
#pragma unroll
  for (int i = 0; i < FI; i++)
#pragma unroll
    for (int j = 0; j < FJ; j++) acc[i][j] = zero;

  stage(0, 0);
  if (BK < K) stage(1, BK);
  int cur = 0;
  for (int k0 = 0; k0 < K; k0 += BK) {
    if (k0 + 2 * BK < K) {
      int nb = cur + 2; if (nb >= 3) nb -= 3;
      stage(nb, k0 + 2 * BK);              // prefetch tile t+2
      asm volatile("s_waitcnt vmcnt(8)" ::: "memory");   // stage t done; t+1,t+2 in flight
    } else if (k0 + BK < K) {
      asm volatile("s_waitcnt vmcnt(4)" ::: "memory");   // stage t done; t+1 in flight
    } else {
      asm volatile("s_waitcnt vmcnt(0)" ::: "memory");   // final tile: full drain
    }
    __builtin_amdgcn_s_barrier();          // buffer cur complete for all waves
    __builtin_amdgcn_sched_barrier(0);
    const u16* Sc = S[cur];
#pragma unroll
    for (int kk2 = 0; kk2 < BK / 32; kk2++) {
      bf16x8 af[FI], bfr[FJ];
#pragma unroll
      for (int i = 0; i < FI; i++) {
        int arow = wr * 64 + i * 16 + (lane & 15);
        af[i] = *(const bf16x8*)&Sc[arow * BK + kk2 * 32 + (lane >> 4) * 8];
      }
#pragma unroll
      for (int j = 0; j < FJ; j++) {
        int brow = BM + wc * (BN / 2) + j * 16 + (lane & 15);
        bfr[j] = *(const bf16x8*)&Sc[brow * BK + kk2 * 32 + (lane >> 4) * 8];
      }
#pragma unroll
      for (int i = 0; i < FI; i++)
#pragma unroll
        for (int j = 0; j < FJ; j++)
          acc[i][j] = __builtin_amdgcn_mfma_f32_16x16x32_bf16(af[i], bfr[j], acc[i][j], 0, 0, 0);
    }
    __builtin_amdgcn_s_barrier();          // all waves done reading buffer cur
    __builtin_amdgcn_sched_barrier(0);     // keep next iter's stage below this point
    cur += 1; if (cur == 3) cur = 0;
  }
#pragma unroll
  for (int i = 0; i < FI; i++) {
    int grow = m0 + wr * 64 + i * 16 + (lane >> 4) * 4;
#pragma unroll
    for (int j = 0; j < FJ; j++) {
      int gcol = n0 + wc * (BN / 2) + j * 16 + (lane & 15);
#pragma unroll
      for (int r = 0; r < 4; r++)
        ep.store(bz, grow + r, gcol, acc[i][j][r]);
    }
  }
}

// ---------------- bf16 MFMA GEMM, 256x128 tile, 8 waves (proven r10/r11, FFN1) -------
template <class EP>
__global__ __launch_bounds__(512) void mgemm_big_k(const u16* __restrict__ A, long Azs, int ldA,
                                                   const u16* __restrict__ B, long Bzs, int ldB,
                                                   EP ep, int K) {
  constexpr int BM = 256, BN = 128, BK = 32;
  __shared__ __align__(16) u16 S[(BM + BN) * BK];   // 24 KiB
  int bx, by, bz;
  xcd_swz(bx, by, bz);
  const int tid = threadIdx.x;
  const int wid = tid >> 6, lane = tid & 63;
  const int m0 = by * BM, n0 = bx * BN;
  const u16* Az = A + (long)bz * Azs;
  const u16* Bz = B + (long)bz * Bzs;
  const int wr = wid >> 1, wc = wid & 1;
  const int lrow = lane >> 2;              // 16 rows per 1KB group
  const int lk   = (lane & 3) * 8;

  f32x4 acc[4][4];
  f32x4 zero = {0.f, 0.f, 0.f, 0.f};
#pragma unroll
  for (int i = 0; i < 4; i++)
#pragma unroll
    for (int j = 0; j < 4; j++) acc[i][j] = zero;

  for (int k0 = 0; k0 < K; k0 += BK) {
#pragma unroll
    for (int g = 0; g < 3; g++) {          // 24 groups / 8 waves
      int grp = g * 8 + wid;
      int row = grp * 16 + lrow;           // A rows [0,256), then B rows
      const u16* src = (row < BM)
          ? Az + (long)(m0 + row) * ldA + k0 + lk
          : Bz + (long)(n0 + row - BM) * ldB + k0 + lk;
      gl2lds16(src, (char*)S + grp * 1024);
    }
    __syncthreads();
    bf16x8 af[4], bfr[4];
#pragma unroll
    for (int i = 0; i < 4; i++) {
      int arow = wr * 64 + i * 16 + (lane & 15);
      af[i] = *(const bf16x8*)&S[arow * BK + (lane >> 4) * 8];
      int brow = BM + wc * 64 + i * 16 + (lane & 15);
      bfr[i] = *(const bf16x8*)&S[brow * BK + (lane >> 4) * 8];
    }
#pragma unroll
    for (int i = 0; i < 4; i++)
#pragma unroll
      for (int j = 0; j < 4; j++)
        acc[i][j] = __builtin_amdgcn_mfma_f32_16x16x32_bf16(af[i], bfr[j], acc[i][j], 0, 0, 0);
    __syncthreads();
  }
#pragma unroll
  for (int i = 0; i < 4; i++) {
    int grow = m0 + wr * 64 + i * 16 + (lane >> 4) * 4;
#pragma unroll
    for (int j = 0; j < 4; j++) {
      int gcol = n0 + wc * 64 + j * 16 + (lane & 15);
#pragma unroll
      for (int r = 0; r < 4; r++)
        ep.store(bz, grow + r, gcol, acc[i][j][r]);
    }
  }
}

// ---------------- split-bf16 3-term GEMM, 128^2 tile, 4 waves (proven r9) ----------
// CSTAT: emit per-block (128-row slab) column max/expsum into
// pmax/psum[(bz*16+by)*CES + n0 + c]  (dispatch-softmax partial stats).
template <bool CSTAT, class EP>
__global__ __launch_bounds__(256) void mgemm3_k(const u16* __restrict__ Ah,
                                                const u16* __restrict__ Al, long Azs, int ldA,
                                                const u16* __restrict__ Bh,
                                                const u16* __restrict__ Bl, long Bzs, int ldB,
                                                EP ep, int K,
                                                float* __restrict__ pmax,
                                                float* __restrict__ psum) {
  constexpr int BK = 32;
  __shared__ __align__(16) u16 Ahs[128 * BK];
  __shared__ __align__(16) u16 Als[128 * BK];
  __shared__ __align__(16) u16 Bhs[128 * BK];
  __shared__ __align__(16) u16 Bls[128 * BK];
  int bx, by, bz;
  xcd_swz(bx, by, bz);
  const int tid = threadIdx.x;
  const int wid = tid >> 6, lane = tid & 63;
  const int m0 = by * 128, n0 = bx * 128;
  const u16* Ahz = Ah + (long)bz * Azs;
  const u16* Alz = Al + (long)bz * Azs;
  const u16* Bhz = Bh + (long)bz * Bzs;
  const u16* Blz = Bl + (long)bz * Bzs;
  const int wr = wid >> 1, wc = wid & 1;
  const int srow = lane >> 2;
  const int sk8  = (lane & 3) * 8;

  f32x4 acc[4][4];
  f32x4 zero = {0.f, 0.f, 0.f, 0.f};
#pragma unroll
  for (int i = 0; i < 4; i++)
#pragma unroll
    for (int j = 0; j < 4; j++) acc[i][j] = zero;

  for (int k0 = 0; k0 < K; k0 += BK) {
#pragma unroll
    for (int i = 0; i < 2; i++) {
      int chunk = i * 4 + wid;
      int r = chunk * 16 + srow;
      long ao = (long)(m0 + r) * ldA + k0 + sk8;
      long bo = (long)(n0 + r) * ldB + k0 + sk8;
      gl2lds16(Ahz + ao, (char*)Ahs + chunk * 1024);
      gl2lds16(Alz + ao, (char*)Als + chunk * 1024);
      gl2lds16(Bhz + bo, (char*)Bhs + chunk * 1024);
      gl2lds16(Blz + bo, (char*)Bls + chunk * 1024);
    }
    __syncthreads();
    bf16x8 ah[4], al[4], bh[4], bl[4];
#pragma unroll
    for (int i = 0; i < 4; i++) {
      int arow = wr * 64 + i * 16 + (lane & 15);
      int aoff = arow * BK + (lane >> 4) * 8;
      ah[i] = *(const bf16x8*)&Ahs[aoff];
      al[i] = *(const bf16x8*)&Als[aoff];
      int brow = wc * 64 + i * 16 + (lane & 15);
      int boff = brow * BK + (lane >> 4) * 8;
      bh[i] = *(const bf16x8*)&Bhs[boff];
      bl[i] = *(const bf16x8*)&Bls[boff];
    }
#pragma unroll
    for (int i = 0; i < 4; i++)
#pragma unroll
      for (int j = 0; j < 4; j++) {
        acc[i][j] = __builtin_amdgcn_mfma_f32_16x16x32_bf16(ah[i], bh[j], acc[i][j], 0, 0, 0);
        acc[i][j] = __builtin_amdgcn_mfma_f32_16x16x32_bf16(al[i], bh[j], acc[i][j], 0, 0, 0);
        acc[i][j] = __builtin_amdgcn_mfma_f32_16x16x32_bf16(ah[i], bl[j], acc[i][j], 0, 0, 0);
      }
    __syncthreads();
  }
#pragma unroll
  for (int i = 0; i < 4; i++) {
    int grow = m0 + wr * 64 + i * 16 + (lane >> 4) * 4;
#pragma unroll
    for (int j = 0; j < 4; j++) {
      int gcol = n0 + wc * 64 + j * 16 + (lane & 15);
#pragma unroll
      for (int r = 0; r < 4; r++)
        ep.store(bz, grow + r, gcol, acc[i][j][r]);
    }
  }

  if constexpr (CSTAT) {
    // col c = wc*64 + j*16 + (lane&15); lanes {l, l^16, l^32, l^48} share a col.
    __shared__ float cred[2][128];
    __shared__ float sred[2][128];
    float cmv[4], lsum[4];
#pragma unroll
    for (int j = 0; j < 4; j++) {
      float m = acc[0][j][0];
#pragma unroll
      for (int i = 0; i < 4; i++)
#pragma unroll
        for (int r = 0; r < 4; r++) m = fmaxf(m, acc[i][j][r]);
      m = fmaxf(m, __shfl_xor(m, 16, 64));
      m = fmaxf(m, __shfl_xor(m, 32, 64));
      cmv[j] = m;                          // col max over this wave's 64 rows
    }
    if (lane < 16) {
#pragma unroll
      for (int j = 0; j < 4; j++) cred[wr][wc * 64 + j * 16 + lane] = cmv[j];
    }
    __syncthreads();
#pragma unroll
    for (int j = 0; j < 4; j++) {
      int c = wc * 64 + j * 16 + (lane & 15);
      float cm = fmaxf(cred[0][c], cred[1][c]);   // block col max (128 rows)
      float s = 0.f;
#pragma unroll
      for (int i = 0; i < 4; i++)
#pragma unroll
        for (int r = 0; r < 4; r++) s += __expf(acc[i][j][r] - cm);
      s += __shfl_xor(s, 16, 64);
      s += __shfl_xor(s, 32, 64);
      cmv[j] = cm; lsum[j] = s;
    }
    if (lane < 16) {
#pragma unroll
      for (int j = 0; j < 4; j++) sred[wr][wc * 64 + j * 16 + lane] = lsum[j];
    }
    __syncthreads();
    if (wr == 0 && lane < 16) {
      long sb = ((long)bz * 16 + by) * CES + n0;
#pragma unroll
      for (int j = 0; j < 4; j++) {
        int c = wc * 64 + j * 16 + lane;
        pmax[sb + c] = cmv[j];
        psum[sb + c] = sred[0][c] + sred[1][c];
      }
    }
  }
}

// ---------------- launch ----------------
extern "C" void kernel_launch(void* const* d_in, const int* in_sizes, int n_in,
                              void* d_out, int out_size, void* d_ws, size_t ws_size,
                              hipStream_t stream) {
  const float* x          = (const float*)d_in[0];
  const float* W_slot     = (const float*)d_in[1];
  const float* u_slot     = (const float*)d_in[2];
  const float* sigma_slot = (const float*)d_in[3];
  const float* W1         = (const float*)d_in[4];
  const float* b1         = (const float*)d_in[5];
  const float* u1         = (const float*)d_in[6];
  const float* sig1       = (const float*)d_in[7];
  const float* W2         = (const float*)d_in[8];
  const float* b2         = (const float*)d_in[9];
  const float* u2         = (const float*)d_in[10];
  const float* sig2       = (const float*)d_in[11];
  float* out = (float*)d_out;

  // ---- workspace overlays (peak ~202 MiB, proven footprint) ----
  char* ws = (char*)d_ws;
  size_t off = 0;
  auto alloc = [&](size_t bytes) -> char* {
    char* p = ws + off;
    off += (bytes + 255) & ~(size_t)255;
    return p;
  };
  float* t1s = (float*)alloc(4096 * 4);
  float* t1a = (float*)alloc(4 * 4096 * 4);
  float* t1b = (float*)alloc(4 * 1024 * 4);
  float* t2s = (float*)alloc(1024 * 4);
  float* t2a = (float*)alloc(4 * 1024 * 4);
  float* t2b = (float*)alloc(4 * 4096 * 4);
  float* scales = (float*)alloc(16 * 4);
  float* pmax   = (float*)alloc((size_t)CB * 16 * CES * 4);
  float* psum   = (float*)alloc((size_t)CB * 16 * CES * 4);
  float* cmax   = (float*)alloc((size_t)CB * CES * 4);
  float* csum   = (float*)alloc((size_t)CB * CES * 4);
  char* regAB   = alloc((size_t)CB * CN * CD * 2 * 2);                // 32 MiB
  char* regBB   = alloc((size_t)CB * CES * CD * 2 * 2);               // 32 MiB
  char* regL    = alloc((size_t)CB * CN * CES * 4);                   // 64 MiB
  char* regS    = alloc((size_t)CE * CB * CS * CD * 2);               // 16 MiB
  u16* W1b      = (u16*)alloc((size_t)CE * CH * CD * 2);              // 32 MiB
  u16* W2b      = (u16*)alloc((size_t)CE * CD * CH * 2);              // 32 MiB

  u16*   xh      = (u16*)regAB;                        // [b][n][d]
  u16*   xl      = (u16*)(regAB + (size_t)CB * CN * CD * 2);
  u16*   dispT   = (u16*)regAB;                        // [b][es][n]
  u16*   combineB= (u16*)regAB;                        // [b][n][es]
  u16*   seh     = (u16*)regBB;                        // [b][es][d]
  u16*   sel     = (u16*)(regBB + (size_t)CB * CES * CD * 2);
  u16*   xT      = (u16*)regBB;                        // [b][d][n]
  float* logits  = (float*)regL;                       // [b][n][es]
  u16*   hbuf    = (u16*)regL;                         // [e][2048][H]
  u16*   xmh     = (u16*)regL;                         // [(b,s)][d] 4 MiB
  u16*   xml     = (u16*)(regL + (size_t)CB * CS * CD * 2);
  u16*   wslh    = (u16*)(regL + (size_t)2 * CB * CS * CD * 2);  // [4096][1024] 8 MiB
  u16*   wsll    = (u16*)(regL + (size_t)2 * CB * CS * CD * 2 + (size_t)CE * CD * CD * 2);
  u16*   slotsB  = (u16*)regS;                         // [e][(b,si)][d]
  u16*   outbufT = (u16*)regS;                         // [b][d][es]

  // zero t2s..t2b in one span (consecutive 256-aligned allocs)
  hipMemsetAsync(t2s, 0, (size_t)((char*)t2b - (char*)t2s) + 4 * 4096 * 4, stream);

  // spectral scales (gemv_cols also emits bf16 weight planes)
  gemv_rows_k<<<dim3(4096 / 4, 1), 256, 0, stream>>>(W_slot, u_slot, t1s, 4096, 1024, 0);
  gemv_rows_k<<<dim3(4096 / 4, 4), 256, 0, stream>>>(W1, u1, t1a, CH, CD, CD);
  gemv_rows_k<<<dim3(1024 / 4, 4), 256, 0, stream>>>(W2, u2, t1b, CD, CH, CH);
  gemv_cols_k<<<dim3(1024 / 256, 4096 / 256, 1), 256, 0, stream>>>(W_slot, t1s, t2s, wslh, wsll, 4096, 1024);
  gemv_cols_k<<<dim3(1024 / 256, 4096 / 256, 4), 256, 0, stream>>>(W1, t1a, t2a, W1b, nullptr, CH, CD);
  gemv_cols_k<<<dim3(4096 / 256, 1024 / 256, 4), 256, 0, stream>>>(W2, t1b, t2b, W2b, nullptr, CD, CH);
  scale_all_k<<<9, 256, 0, stream>>>(t1s, t2s, t1a, t2a, t1b, t2b,
                                     sigma_slot, sig1, sig2, scales);

  // x hi/lo split + token-group-mean hi/lo split (single pass over x)
  xsplit_fused_k<<<(CB * CS * (CD / 8)) / 256, 256, 0, stream>>>(x, xh, xl, xmh, xml);

  // SE = (xm @ W_slot^T) * scale_slot, split-bf16 3-term -> SE hi/lo planes
  mgemm3_k<false><<<dim3(4096 / 128, 2048 / 128, 1), 256, 0, stream>>>(
      xmh, xml, 0L, CD, wslh, wsll, 0L, CD, MEpSESplit{seh, sel, scales}, CD,
      nullptr, nullptr);

  // logits[b] = x_b @ SE_b^T, split-bf16 3-term -> f32, + fused col stats
  mgemm3_k<true><<<dim3(CES / 128, CN / 128, CB), 256, 0, stream>>>(
      xh, xl, (long)CN * CD, CD, seh, sel, (long)CES * CD, CD,
      MEpLogits{logits}, CD, pmax, psum);

  // dispatch softmax stat combine (16 slabs of 128 rows)
  colstat_comb_k<<<(CB * CES) / 256, 256, 0, stream>>>(pmax, psum, cmax, csum);

  // dispT[b][es][n] = bf16(exp(lg - cmax))   (overwrites xh/xl; dead after logits)
  tr_f2b_k<<<dim3(CES / 32, CN / 32, CB), 256, 0, stream>>>(logits, dispT, cmax, CN, CES, 1);
  // xT[b][d][n] = bf16(x^T)                  (overwrites seh; dead after logits)
  tr_f2b_k<<<dim3(CD / 32, CN / 32, CB), 256, 0, stream>>>(x, xT, nullptr, CN, CD, 0);

  // slots: [b] dispT(2048 x K2048) @ xT(1024 x K2048)^T -> slotsB (bf16, /csum)
  mgemm_db_k<128, 32><<<dim3(CD / 128, CES / 128, CB), 256, 0, stream>>>(
      dispT, (long)CES * CN, CN, xT, (long)CD * CN, CN, MEpSlots{slotsB, csum}, CN);

  // combineB[b][n][es] = bf16(softmax over es)   (overwrites dispT; dead)
  rowcomb_k<<<CB * CN, 256, 0, stream>>>(logits, combineB);

  // FFN1: [e] slotsB(2048 x K1024) @ W1b(4096 x K1024)^T -> hbuf (gelu, bf16)
  mgemm_big_k<<<dim3(CH / 128, 2048 / 256, CE), 512, 0, stream>>>(
      slotsB, (long)2048 * CD, CD, W1b, (long)CH * CD, CD, MEpGelu{hbuf, scales, b1}, CD);

  // FFN2 (swapped, writes y^T directly): [e] W2b(1024 x K4096) @ hbuf(2048 x K4096)^T
  mgemm_db_k<128, 32><<<dim3(2048 / 128, CD / 128, CE), 256, 0, stream>>>(
      W2b, (long)CD * CH, CH, hbuf, (long)2048 * CH, CH, MEpYT{outbufT, scales, b2}, CH);

  // final: [b] combineB(2048 x K2048) @ outbufT(1024 x K2048)^T -> out f32
  mgemm_db_k<128, 32><<<dim3(CD / 128, CN / 128, CB), 256, 0, stream>>>(
      combineB, (long)CN * CES, CES, outbufT, (long)CD * CES, CES, MEpOut{out}, CES);

  (void)in_sizes; (void)n_in; (void)out_size; (void)ws_size;
}

// Round 17
// 796.799 us; speedup vs baseline: 1.0731x; 1.0169x over previous
//
#include <hip/hip_runtime.h>
#include <hip/hip_bf16.h>
#include <math.h>

constexpr int CB  = 4;     // batch
constexpr int CN  = 2048;  // tokens
constexpr int CD  = 1024;  // model dim
constexpr int CE  = 4;     // experts
constexpr int CS  = 512;   // slots per expert
constexpr int CH  = 4096;  // expert hidden
constexpr int CES = 2048;  // E*S

typedef unsigned short u16;
typedef unsigned int   u32;
typedef __bf16 bf16x8 __attribute__((ext_vector_type(8)));
typedef float  f32x4  __attribute__((ext_vector_type(4)));

__device__ __forceinline__ u16 f2bf(float x) {
  u32 u = __float_as_uint(x);
  u = (u + 0x7FFF + ((u >> 16) & 1)) >> 16;   // round-to-nearest-even
  return (u16)u;
}

__device__ __forceinline__ void gl2lds16(const void* g, void* l) {
  __builtin_amdgcn_global_load_lds(
      (const __attribute__((address_space(1))) void*)g,
      (__attribute__((address_space(3))) void*)l, 16, 0, 0);
}

// bijective XCD-aware block swizzle (all grids have nwg % 8 == 0)
__device__ __forceinline__ void xcd_swz(int& bx, int& by, int& bz) {
  u32 gx = gridDim.x, gy = gridDim.y;
  u32 w = blockIdx.x + gx * (blockIdx.y + gy * blockIdx.z);
  u32 nwg = gx * gy * gridDim.z;
  u32 q = nwg >> 3;
  u32 wg = (w & 7) * q + (w >> 3);
  bx = wg % gx;
  u32 r = wg / gx;
  by = r % gy;
  bz = r / gy;
}

// ---------------- spectral-norm scale kernels ----------------
// scale = sigma * ||W u|| / ||W^T (W u)||

__global__ __launch_bounds__(256) void gemv_rows_k(const float* __restrict__ W,
    const float* __restrict__ u, float* __restrict__ t1, int M, int K, int ustride) {
  int bi = blockIdx.y;
  int row = blockIdx.x * 4 + (threadIdx.x >> 6);
  int lane = threadIdx.x & 63;
  const float* Wr = W + ((long)bi * M + row) * K;
  const float* ub = u + (long)bi * ustride;
  float s = 0.f;
  for (int k = lane; k < K; k += 64) s += Wr[k] * ub[k];
#pragma unroll
  for (int off = 32; off; off >>= 1) s += __shfl_down(s, off, 64);
  if (lane == 0) t1[bi * M + row] = s;
}

// also emits bf16 conversion of W (and optional lo-plane split)
__global__ __launch_bounds__(256) void gemv_cols_k(const float* __restrict__ W,
    const float* __restrict__ t1, float* __restrict__ t2,
    u16* __restrict__ bh, u16* __restrict__ bl, int M, int K) {
  int bi = blockIdx.z;
  int k = blockIdx.x * 256 + threadIdx.x;
  int m0 = blockIdx.y * 256;
  const float* Wb = W + (long)bi * M * K;
  const float* tb = t1 + bi * M;
  u16* bhb = bh + (long)bi * M * K;
  u16* blb = bl ? bl + (long)bi * M * K : nullptr;
  float s = 0.f;
#pragma unroll 4
  for (int m = 0; m < 256; m++) {
    long idx = (long)(m0 + m) * K + k;
    float w = Wb[idx];
    s += w * tb[m0 + m];
    u16 h = f2bf(w);
    bhb[idx] = h;
    if (blb) blb[idx] = f2bf(w - __uint_as_float((u32)h << 16));
  }
  atomicAdd(&t2[bi * K + k], s);
}

// all 9 spectral scales in one launch: block 0 = W_slot, 1..4 = W1[e], 5..8 = W2[e]
__global__ __launch_bounds__(256) void scale_all_k(
    const float* __restrict__ t1s, const float* __restrict__ t2s,
    const float* __restrict__ t1a, const float* __restrict__ t2a,
    const float* __restrict__ t1b, const float* __restrict__ t2b,
    const float* __restrict__ sigs, const float* __restrict__ sig1,
    const float* __restrict__ sig2, float* __restrict__ scales) {
  int bi = blockIdx.x;
  const float *t1, *t2; float sg; float* o; int M, K;
  if (bi == 0)      { t1 = t1s;                 t2 = t2s;                 sg = sigs[0];     o = scales + 0;      M = 4096; K = 1024; }
  else if (bi < 5)  { int e = bi - 1; t1 = t1a + e * 4096; t2 = t2a + e * 1024; sg = sig1[e]; o = scales + 1 + e; M = 4096; K = 1024; }
  else              { int e = bi - 5; t1 = t1b + e * 1024; t2 = t2b + e * 4096; sg = sig2[e]; o = scales + 5 + e; M = 1024; K = 4096; }
  int tid = threadIdx.x;
  __shared__ float red[256];
  float s1 = 0.f;
  for (int i = tid; i < M; i += 256) { float v = t1[i]; s1 += v * v; }
  red[tid] = s1; __syncthreads();
  for (int w = 128; w; w >>= 1) { if (tid < w) red[tid] += red[tid + w]; __syncthreads(); }
  float n1 = red[0]; __syncthreads();
  float s2 = 0.f;
  for (int i = tid; i < K; i += 256) { float v = t2[i]; s2 += v * v; }
  red[tid] = s2; __syncthreads();
  for (int w = 128; w; w >>= 1) { if (tid < w) red[tid] += red[tid + w]; __syncthreads(); }
  if (tid == 0) o[0] = sg * sqrtf(n1 / red[0]);
}

// ---------------- fused x hi/lo split + token-group-mean hi/lo split ----------------
__global__ __launch_bounds__(256) void xsplit_fused_k(const float* __restrict__ x,
    u16* __restrict__ xh, u16* __restrict__ xl,
    u16* __restrict__ xmh, u16* __restrict__ xml) {
  int idx = blockIdx.x * 256 + threadIdx.x;      // b*S*(D/8) total
  int d8 = idx & (CD / 8 - 1);
  int si = (idx >> 7) & (CS - 1);
  int b  = idx >> 16;
  long rbase = ((long)(b * CN + si * 4)) * CD + d8 * 8;
  float vr[4][8];
#pragma unroll
  for (int r = 0; r < 4; r++) {
    float4 a = *(const float4*)(x + rbase + (long)r * CD);
    float4 c = *(const float4*)(x + rbase + (long)r * CD + 4);
    vr[r][0]=a.x; vr[r][1]=a.y; vr[r][2]=a.z; vr[r][3]=a.w;
    vr[r][4]=c.x; vr[r][5]=c.y; vr[r][6]=c.z; vr[r][7]=c.w;
  }
#pragma unroll
  for (int r = 0; r < 4; r++) {
    u16 oh[8], ol[8];
#pragma unroll
    for (int c = 0; c < 8; c++) {
      u16 h = f2bf(vr[r][c]);
      oh[c] = h;
      ol[c] = f2bf(vr[r][c] - __uint_as_float((u32)h << 16));
    }
    *(uint4*)(xh + rbase + (long)r * CD) = *(const uint4*)oh;
    *(uint4*)(xl + rbase + (long)r * CD) = *(const uint4*)ol;
  }
  long mbase = ((long)(b * CS + si)) * CD + d8 * 8;
  u16 oh[8], ol[8];
#pragma unroll
  for (int c = 0; c < 8; c++) {
    float v = 0.25f * (vr[0][c] + vr[1][c] + vr[2][c] + vr[3][c]);
    u16 h = f2bf(v);
    oh[c] = h;
    ol[c] = f2bf(v - __uint_as_float((u32)h << 16));
  }
  *(uint4*)(xmh + mbase) = *(const uint4*)oh;
  *(uint4*)(xml + mbase) = *(const uint4*)ol;
}

// ---------------- dispatch softmax stat combine (16 slabs of 128 rows) ----------------
__global__ __launch_bounds__(256) void colstat_comb_k(const float* __restrict__ pmax,
    const float* __restrict__ psum, float* __restrict__ cmax, float* __restrict__ csum) {
  int idx = blockIdx.x * 256 + threadIdx.x;   // b*CES
  int b = idx >> 11;
  int es = idx & (CES - 1);
  float m = -1e30f;
#pragma unroll
  for (int sl = 0; sl < 16; sl++) m = fmaxf(m, pmax[(b * 16 + sl) * CES + es]);
  float s = 0.f;
#pragma unroll
  for (int sl = 0; sl < 16; sl++)
    s += psum[(b * 16 + sl) * CES + es] * __expf(pmax[(b * 16 + sl) * CES + es] - m);
  cmax[idx] = m; csum[idx] = s;
}

// ---------------- fused combine softmax (over es) -> bf16 ----------------
__global__ __launch_bounds__(256) void rowcomb_k(const float* __restrict__ lg,
                                                 u16* __restrict__ outB) {
  __shared__ float red[8];
  long row = blockIdx.x;                       // b*CN + n
  const float* p = lg + row * CES + threadIdx.x * 8;
  float4 a = *(const float4*)p;
  float4 b = *(const float4*)(p + 4);
  float v[8] = {a.x, a.y, a.z, a.w, b.x, b.y, b.z, b.w};
  float m = v[0];
#pragma unroll
  for (int c = 1; c < 8; c++) m = fmaxf(m, v[c]);
#pragma unroll
  for (int off = 32; off; off >>= 1) m = fmaxf(m, __shfl_xor(m, off, 64));
  int wv = threadIdx.x >> 6;
  if ((threadIdx.x & 63) == 0) red[wv] = m;
  __syncthreads();
  m = fmaxf(fmaxf(red[0], red[1]), fmaxf(red[2], red[3]));
  float s = 0.f;
#pragma unroll
  for (int c = 0; c < 8; c++) { v[c] = __expf(v[c] - m); s += v[c]; }
#pragma unroll
  for (int off = 32; off; off >>= 1) s += __shfl_xor(s, off, 64);
  if ((threadIdx.x & 63) == 0) red[4 + wv] = s;
  __syncthreads();
  float inv = 1.f / (red[4] + red[5] + red[6] + red[7]);
  u16 o[8];
#pragma unroll
  for (int c = 0; c < 8; c++) o[c] = f2bf(v[c] * inv);
  *(uint4*)(outB + row * CES + threadIdx.x * 8) = *(const uint4*)o;
}

// in [z][R][C] f32 -> out [z][C][R] bf16; expmode: v = exp(v - sub[z*C + col])
__global__ __launch_bounds__(256) void tr_f2b_k(const float* __restrict__ in,
    u16* __restrict__ out, const float* __restrict__ sub, int R, int C, int expmode) {
  __shared__ u16 t[32][33];
  int z = blockIdx.z;
  long ibase = (long)z * R * C;
  int r0 = blockIdx.y * 32, c0 = blockIdx.x * 32;
  int tx = threadIdx.x & 31, ty = threadIdx.x >> 5;
  float cm = expmode ? sub[(long)z * C + c0 + tx] : 0.f;
  for (int rr = ty; rr < 32; rr += 8) {
    float v = in[ibase + (long)(r0 + rr) * C + c0 + tx];
    if (expmode) v = __expf(v - cm);
    t[tx][rr] = f2bf(v);
  }
  __syncthreads();
  for (int cc = ty; cc < 32; cc += 8)
    out[ibase + (long)(c0 + cc) * R + r0 + tx] = t[cc][tx];
}

// ---------------- epilogues ----------------
struct MEpSESplit {  // SE hi/lo planes [b][es][d], es = ei*512+si; m=(b,si), n=(ei,di)
  u16* hi; u16* lo; const float* scale;
  __device__ void store(int z, int m, int n, float v) const {
    v *= scale[0];
    int b = m >> 9, si = m & 511, ei = n >> 10, di = n & 1023;
    long o = ((long)(b * CES + ei * 512 + si)) * CD + di;
    u16 h = f2bf(v);
    hi[o] = h;
    lo[o] = f2bf(v - __uint_as_float((u32)h << 16));
  }
};
struct MEpLogits {   // logits[b][n][es] = v ; z=b, m=token, n=es
  float* lg;
  __device__ void store(int b, int m, int n, float v) const {
    lg[((long)(b * CN + m)) * CES + n] = v;
  }
};
struct MEpSlots {  // slotsB[e][b*512+si][d] = bf16(v / csum[b][es]); z=b, m=es
  u16* sb; const float* __restrict__ csum;
  __device__ void store(int b, int m, int n, float v) const {
    float inv = 1.f / csum[b * CES + m];
    int e = m >> 9, si = m & 511;
    sb[((long)(e * 2048 + b * 512 + si)) * CD + n] = f2bf(v * inv);
  }
};
struct MEpGelu {   // h[e][m][H] = bf16(gelu(v*sc1[e] + b1[e][n])); z=e, m=(b,si)
  // tanh-form GELU: |err vs exact| below bf16 rounding of h (verified r8/r9).
  u16* h; const float* __restrict__ scales; const float* __restrict__ b1;
  __device__ void store(int e, int m, int n, float v) const {
    float xg = v * scales[1 + e] + b1[e * CH + n];
    float t = xg * (0.7978845608f + 0.0356774081f * xg * xg);
    float ex = __expf(2.f * t);
    float th = 1.f - 2.f / (ex + 1.f);          // tanh(t), saturates correctly
    float g = 0.5f * xg * (1.f + th);
    h[((long)(e * 2048 + m)) * CH + n] = f2bf(g);
  }
};
struct MEpYT {     // outbufT[b][d][es] = bf16(v*sc2[e] + b2[e][m]); z=e, m=d, n=(b,si)
  u16* ot; const float* __restrict__ scales; const float* __restrict__ b2;
  __device__ void store(int e, int m, int n, float v) const {
    int b = n >> 9, si = n & 511;
    ot[((long)(b * CD + m)) * CES + e * 512 + si] = f2bf(v * scales[5 + e] + b2[e * CD + m]);
  }
};
struct MEpOut {    // out[b][n][d] = v (combine already has 1/rsum); z=b
  float* o;
  __device__ void store(int b, int m, int n, float v) const {
    o[((long)(b * CN + m)) * CD + n] = v;
  }
};

// ------ bf16 MFMA GEMM, 128xBN, 4 waves, 2-deep db + counted vmcnt (r15-proven) ------
template <int BN, int BK, class EP>
__global__ __launch_bounds__(256) void mgemm_db_k(const u16* __restrict__ A, long Azs, int ldA,
                                                  const u16* __restrict__ B, long Bzs, int ldB,
                                                  EP ep, int K) {
  constexpr int BM = 128;
  constexpr int FI = 4;
  constexpr int FJ = BN / 32;
  constexpr int RPL = 512 / BK;            // rows per 1KB load-group
  constexpr int NGRP = (BM + BN) / RPL;    // 1KB groups per K-step
  constexpr int GPW = NGRP / 4;            // gl2lds instructions per wave per stage
  static_assert(GPW == 4, "vmcnt literals below assume 4 loads per stage");
  __shared__ __align__(16) u16 S[2][(BM + BN) * BK];
  int bx, by, bz;
  xcd_swz(bx, by, bz);
  const int tid = threadIdx.x;
  const int wid = tid >> 6, lane = tid & 63;
  const int m0 = by * BM, n0 = bx * BN;
  const u16* Az = A + (long)bz * Azs;
  const u16* Bz = B + (long)bz * Bzs;
  const int wr = wid >> 1, wc = wid & 1;
  const int lrow = lane / (BK / 8);        // row within load-group
  const int lk   = (lane % (BK / 8)) * 8;  // k offset within row

  auto stage = [&](int buf, int k0) {
#pragma unroll
    for (int g = 0; g < GPW; g++) {
      int grp = g * 4 + wid;
      int row = grp * RPL + lrow;          // A rows [0,BM), then B rows
      const u16* src = (row < BM)
          ? Az + (long)(m0 + row) * ldA + k0 + lk
          : Bz + (long)(n0 + row - BM) * ldB + k0 + lk;
      gl2lds16(src, (char*)S[buf] + grp * 1024);
    }
  };

  f32x4 acc[FI][FJ];
  f32x4 zero = {0.f, 0.f, 0.f, 0.f};
#pragma unroll
  for (int i = 0; i < FI; i++)
#pragma unroll
    for (int j = 0; j < FJ; j++) acc[i][j] = zero;

  stage(0, 0);
  int cur = 0;
  for (int k0 = 0; k0 < K; k0 += BK) {
    if (k0 + BK < K) {
      stage(cur ^ 1, k0 + BK);             // prefetch next tile
      asm volatile("s_waitcnt vmcnt(4)" ::: "memory");   // cur-tile done; next in flight
    } else {
      asm volatile("s_waitcnt vmcnt(0)" ::: "memory");   // final tile: full drain
    }
    __builtin_amdgcn_s_barrier();          // buffer cur complete for all waves
    __builtin_amdgcn_sched_barrier(0);
    const u16* Sc = S[cur];
#pragma unroll
    for (int kk2 = 0; kk2 < BK / 32; kk2++) {
      bf16x8 af[FI], bfr[FJ];
#pragma unroll
      for (int i = 0; i < FI; i++) {
        int arow = wr * 64 + i * 16 + (lane & 15);
        af[i] = *(const bf16x8*)&Sc[arow * BK + kk2 * 32 + (lane >> 4) * 8];
      }
#pragma unroll
      for (int j = 0; j < FJ; j++) {
        int brow = BM + wc * (BN / 2) + j * 16 + (lane & 15);
        bfr[j] = *(const bf16x8*)&Sc[brow * BK + kk2 * 32 + (lane >> 4) * 8];
      }
#pragma unroll
      for (int i = 0; i < FI; i++)
#pragma unroll
        for (int j = 0; j < FJ; j++)
          acc[i][j] = __builtin_amdgcn_mfma_f32_16x16x32_bf16(af[i], bfr[j], acc[i][j], 0, 0, 0);
    }
    __builtin_amdgcn_s_barrier();          // all waves done reading buffer cur
    __builtin_amdgcn_sched_barrier(0);
    cur ^= 1;
  }
#pragma unroll
  for (int i = 0; i < FI; i++) {
    int grow = m0 + wr * 64 + i * 16 + (lane >> 4) * 4;
#pragma unroll
    for (int j = 0; j < FJ; j++) {
      int gcol = n0 + wc * (BN / 2) + j * 16 + (lane & 15);
#pragma unroll
      for (int r = 0; r < 4; r++)
        ep.store(bz, grow + r, gcol, acc[i][j][r]);
    }
  }
}

// ---------------- bf16 MFMA GEMM, 256x128 tile, 8 waves (proven r10/r11, FFN1) -------
template <class EP>
__global__ __launch_bounds__(512) void mgemm_big_k(const u16* __restrict__ A, long Azs, int ldA,
                                                   const u16* __restrict__ B, long Bzs, int ldB,
                                                   EP ep, int K) {
  constexpr int BM = 256, BN = 128, BK = 32;
  __shared__ __align__(16) u16 S[(BM + BN) * BK];   // 24 KiB
  int bx, by, bz;
  xcd_swz(bx, by, bz);
  const int tid = threadIdx.x;
  const int wid = tid >> 6, lane = tid & 63;
  const int m0 = by * BM, n0 = bx * BN;
  const u16* Az = A + (long)bz * Azs;
  const u16* Bz = B + (long)bz * Bzs;
  const int wr = wid >> 1, wc = wid & 1;
  const int lrow = lane >> 2;              // 16 rows per 1KB group
  const int lk   = (lane & 3) * 8;

  f32x4 acc[4][4];
  f32x4 zero = {0.f, 0.f, 0.f, 0.f};
#pragma unroll
  for (int i = 0; i < 4; i++)
#pragma unroll
    for (int j = 0; j < 4; j++) acc[i][j] = zero;

  for (int k0 = 0; k0 < K; k0 += BK) {
#pragma unroll
    for (int g = 0; g < 3; g++) {          // 24 groups / 8 waves
      int grp = g * 8 + wid;
      int row = grp * 16 + lrow;           // A rows [0,256), then B rows
      const u16* src = (row < BM)
          ? Az + (long)(m0 + row) * ldA + k0 + lk
          : Bz + (long)(n0 + row - BM) * ldB + k0 + lk;
      gl2lds16(src, (char*)S + grp * 1024);
    }
    __syncthreads();
    bf16x8 af[4], bfr[4];
#pragma unroll
    for (int i = 0; i < 4; i++) {
      int arow = wr * 64 + i * 16 + (lane & 15);
      af[i] = *(const bf16x8*)&S[arow * BK + (lane >> 4) * 8];
      int brow = BM + wc * 64 + i * 16 + (lane & 15);
      bfr[i] = *(const bf16x8*)&S[brow * BK + (lane >> 4) * 8];
    }
#pragma unroll
    for (int i = 0; i < 4; i++)
#pragma unroll
      for (int j = 0; j < 4; j++)
        acc[i][j] = __builtin_amdgcn_mfma_f32_16x16x32_bf16(af[i], bfr[j], acc[i][j], 0, 0, 0);
    __syncthreads();
  }
#pragma unroll
  for (int i = 0; i < 4; i++) {
    int grow = m0 + wr * 64 + i * 16 + (lane >> 4) * 4;
#pragma unroll
    for (int j = 0; j < 4; j++) {
      int gcol = n0 + wc * 64 + j * 16 + (lane & 15);
#pragma unroll
      for (int r = 0; r < 4; r++)
        ep.store(bz, grow + r, gcol, acc[i][j][r]);
    }
  }
}

// ---- split-bf16 3-term GEMM, 128^2 tile, 4 waves, 2-deep db + counted vmcnt ----
// Same r15-proven barrier/vmcnt skeleton as mgemm_db_k; stage = 8 loads/thread
// over 4 arrays -> vmcnt(8) when next stage in flight. LDS 2x32KB = 64KB
// (blocks/CU stays 2, the measured occupancy). CSTAT scratch reuses the stage
// buffer (dead after the K-loop's final barrier).
template <bool CSTAT, class EP>
__global__ __launch_bounds__(256) void mgemm3_k(const u16* __restrict__ Ah,
                                                const u16* __restrict__ Al, long Azs, int ldA,
                                                const u16* __restrict__ Bh,
                                                const u16* __restrict__ Bl, long Bzs, int ldB,
                                                EP ep, int K,
                                                float* __restrict__ pmax,
                                                float* __restrict__ psum) {
  constexpr int BK = 32;
  __shared__ __align__(16) u16 S[2][16384];   // per buf: Ah|Al|Bh|Bl, 8KB each
  int bx, by, bz;
  xcd_swz(bx, by, bz);
  const int tid = threadIdx.x;
  const int wid = tid >> 6, lane = tid & 63;
  const int m0 = by * 128, n0 = bx * 128;
  const u16* Ahz = Ah + (long)bz * Azs;
  const u16* Alz = Al + (long)bz * Azs;
  const u16* Bhz = Bh + (long)bz * Bzs;
  const u16* Blz = Bl + (long)bz * Bzs;
  const int wr = wid >> 1, wc = wid & 1;
  const int srow = lane >> 2;
  const int sk8  = (lane & 3) * 8;

  auto stage = [&](int buf, int k0) {
    char* base = (char*)S[buf];
#pragma unroll
    for (int i = 0; i < 2; i++) {
      int chunk = i * 4 + wid;
      int r = chunk * 16 + srow;
      long ao = (long)(m0 + r) * ldA + k0 + sk8;
      long bo = (long)(n0 + r) * ldB + k0 + sk8;
      gl2lds16(Ahz + ao, base + chunk * 1024);
      gl2lds16(Alz + ao, base + 8192 + chunk * 1024);
      gl2lds16(Bhz + bo, base + 16384 + chunk * 1024);
      gl2lds16(Blz + bo, base + 24576 + chunk * 1024);
    }
  };

  f32x4 acc[4][4];
  f32x4 zero = {0.f, 0.f, 0.f, 0.f};
#pragma unroll
  for (int i = 0; i < 4; i++)
#pragma unroll
    for (int j = 0; j < 4; j++) acc[i][j] = zero;

  stage(0, 0);
  int cur = 0;
  for (int k0 = 0; k0 < K; k0 += BK) {
    if (k0 + BK < K) {
      stage(cur ^ 1, k0 + BK);             // prefetch next tile
      asm volatile("s_waitcnt vmcnt(8)" ::: "memory");   // cur stage (8 loads) done
    } else {
      asm volatile("s_waitcnt vmcnt(0)" ::: "memory");
    }
    __builtin_amdgcn_s_barrier();
    __builtin_amdgcn_sched_barrier(0);
    const u16* Sb = S[cur];
    bf16x8 ah[4], al[4], bh[4], bl[4];
#pragma unroll
    for (int i = 0; i < 4; i++) {
      int arow = wr * 64 + i * 16 + (lane & 15);
      int aoff = arow * BK + (lane >> 4) * 8;
      ah[i] = *(const bf16x8*)&Sb[aoff];
      al[i] = *(const bf16x8*)&Sb[4096 + aoff];
      int brow = wc * 64 + i * 16 + (lane & 15);
      int boff = brow * BK + (lane >> 4) * 8;
      bh[i] = *(const bf16x8*)&Sb[8192 + boff];
      bl[i] = *(const bf16x8*)&Sb[12288 + boff];
    }
#pragma unroll
    for (int i = 0; i < 4; i++)
#pragma unroll
      for (int j = 0; j < 4; j++) {
        acc[i][j] = __builtin_amdgcn_mfma_f32_16x16x32_bf16(ah[i], bh[j], acc[i][j], 0, 0, 0);
        acc[i][j] = __builtin_amdgcn_mfma_f32_16x16x32_bf16(al[i], bh[j], acc[i][j], 0, 0, 0);
        acc[i][j] = __builtin_amdgcn_mfma_f32_16x16x32_bf16(ah[i], bl[j], acc[i][j], 0, 0, 0);
      }
    __builtin_amdgcn_s_barrier();
    __builtin_amdgcn_sched_barrier(0);
    cur ^= 1;
  }
#pragma unroll
  for (int i = 0; i < 4; i++) {
    int grow = m0 + wr * 64 + i * 16 + (lane >> 4) * 4;
#pragma unroll
    for (int j = 0; j < 4; j++) {
      int gcol = n0 + wc * 64 + j * 16 + (lane & 15);
#pragma unroll
      for (int r = 0; r < 4; r++)
        ep.store(bz, grow + r, gcol, acc[i][j][r]);
    }
  }

  if constexpr (CSTAT) {
    // stage buffers are dead after the K-loop's final barrier; reuse as scratch.
    float* cred = (float*)&S[0][0];        // [2][128]
    float* sred = cred + 256;              // [2][128]
    float cmv[4], lsum[4];
#pragma unroll
    for (int j = 0; j < 4; j++) {
      float m = acc[0][j][0];
#pragma unroll
      for (int i = 0; i < 4; i++)
#pragma unroll
        for (int r = 0; r < 4; r++) m = fmaxf(m, acc[i][j][r]);
      m = fmaxf(m, __shfl_xor(m, 16, 64));
      m = fmaxf(m, __shfl_xor(m, 32, 64));
      cmv[j] = m;                          // col max over this wave's 64 rows
    }
    if (lane < 16) {
#pragma unroll
      for (int j = 0; j < 4; j++) cred[wr * 128 + wc * 64 + j * 16 + lane] = cmv[j];
    }
    __syncthreads();
#pragma unroll
    for (int j = 0; j < 4; j++) {
      int c = wc * 64 + j * 16 + (lane & 15);
      float cm = fmaxf(cred[c], cred[128 + c]);   // block col max (128 rows)
      float s = 0.f;
#pragma unroll
      for (int i = 0; i < 4; i++)
#pragma unroll
        for (int r = 0; r < 4; r++) s += __expf(acc[i][j][r] - cm);
      s += __shfl_xor(s, 16, 64);
      s += __shfl_xor(s, 32, 64);
      cmv[j] = cm; lsum[j] = s;
    }
    if (lane < 16) {
#pragma unroll
      for (int j = 0; j < 4; j++) sred[wr * 128 + wc * 64 + j * 16 + lane] = lsum[j];
    }
    __syncthreads();
    if (wr == 0 && lane < 16) {
      long sb = ((long)bz * 16 + by) * CES + n0;
#pragma unroll
      for (int j = 0; j < 4; j++) {
        int c = wc * 64 + j * 16 + lane;
        pmax[sb + c] = cmv[j];
        psum[sb + c] = sred[c] + sred[128 + c];
      }
    }
  }
}

// ---------------- launch ----------------
extern "C" void kernel_launch(void* const* d_in, const int* in_sizes, int n_in,
                              void* d_out, int out_size, void* d_ws, size_t ws_size,
                              hipStream_t stream) {
  const float* x          = (const float*)d_in[0];
  const float* W_slot     = (const float*)d_in[1];
  const float* u_slot     = (const float*)d_in[2];
  const float* sigma_slot = (const float*)d_in[3];
  const float* W1         = (const float*)d_in[4];
  const float* b1         = (const float*)d_in[5];
  const float* u1         = (const float*)d_in[6];
  const float* sig1       = (const float*)d_in[7];
  const float* W2         = (const float*)d_in[8];
  const float* b2         = (const float*)d_in[9];
  const float* u2         = (const float*)d_in[10];
  const float* sig2       = (const float*)d_in[11];
  float* out = (float*)d_out;

  // ---- workspace overlays (peak ~202 MiB, proven footprint) ----
  char* ws = (char*)d_ws;
  size_t off = 0;
  auto alloc = [&](size_t bytes) -> char* {
    char* p = ws + off;
    off += (bytes + 255) & ~(size_t)255;
    return p;
  };
  float* t1s = (float*)alloc(4096 * 4);
  float* t1a = (float*)alloc(4 * 4096 * 4);
  float* t1b = (float*)alloc(4 * 1024 * 4);
  float* t2s = (float*)alloc(1024 * 4);
  float* t2a = (float*)alloc(4 * 1024 * 4);
  float* t2b = (float*)alloc(4 * 4096 * 4);
  float* scales = (float*)alloc(16 * 4);
  float* pmax   = (float*)alloc((size_t)CB * 16 * CES * 4);
  float* psum   = (float*)alloc((size_t)CB * 16 * CES * 4);
  float* cmax   = (float*)alloc((size_t)CB * CES * 4);
  float* csum   = (float*)alloc((size_t)CB * CES * 4);
  char* regAB   = alloc((size_t)CB * CN * CD * 2 * 2);                // 32 MiB
  char* regBB   = alloc((size_t)CB * CES * CD * 2 * 2);               // 32 MiB
  char* regL    = alloc((size_t)CB * CN * CES * 4);                   // 64 MiB
  char* regS    = alloc((size_t)CE * CB * CS * CD * 2);               // 16 MiB
  u16* W1b      = (u16*)alloc((size_t)CE * CH * CD * 2);              // 32 MiB
  u16* W2b      = (u16*)alloc((size_t)CE * CD * CH * 2);              // 32 MiB

  u16*   xh      = (u16*)regAB;                        // [b][n][d]
  u16*   xl      = (u16*)(regAB + (size_t)CB * CN * CD * 2);
  u16*   dispT   = (u16*)regAB;                        // [b][es][n]
  u16*   combineB= (u16*)regAB;                        // [b][n][es]
  u16*   seh     = (u16*)regBB;                        // [b][es][d]
  u16*   sel     = (u16*)(regBB + (size_t)CB * CES * CD * 2);
  u16*   xT      = (u16*)regBB;                        // [b][d][n]
  float* logits  = (float*)regL;                       // [b][n][es]
  u16*   hbuf    = (u16*)regL;                         // [e][2048][H]
  u16*   xmh     = (u16*)regL;                         // [(b,s)][d] 4 MiB
  u16*   xml     = (u16*)(regL + (size_t)CB * CS * CD * 2);
  u16*   wslh    = (u16*)(regL + (size_t)2 * CB * CS * CD * 2);  // [4096][1024] 8 MiB
  u16*   wsll    = (u16*)(regL + (size_t)2 * CB * CS * CD * 2 + (size_t)CE * CD * CD * 2);
  u16*   slotsB  = (u16*)regS;                         // [e][(b,si)][d]
  u16*   outbufT = (u16*)regS;                         // [b][d][es]

  // zero t2s..t2b in one span (consecutive 256-aligned allocs)
  hipMemsetAsync(t2s, 0, (size_t)((char*)t2b - (char*)t2s) + 4 * 4096 * 4, stream);

  // spectral scales (gemv_cols also emits bf16 weight planes)
  gemv_rows_k<<<dim3(4096 / 4, 1), 256, 0, stream>>>(W_slot, u_slot, t1s, 4096, 1024, 0);
  gemv_rows_k<<<dim3(4096 / 4, 4), 256, 0, stream>>>(W1, u1, t1a, CH, CD, CD);
  gemv_rows_k<<<dim3(1024 / 4, 4), 256, 0, stream>>>(W2, u2, t1b, CD, CH, CH);
  gemv_cols_k<<<dim3(1024 / 256, 4096 / 256, 1), 256, 0, stream>>>(W_slot, t1s, t2s, wslh, wsll, 4096, 1024);
  gemv_cols_k<<<dim3(1024 / 256, 4096 / 256, 4), 256, 0, stream>>>(W1, t1a, t2a, W1b, nullptr, CH, CD);
  gemv_cols_k<<<dim3(4096 / 256, 1024 / 256, 4), 256, 0, stream>>>(W2, t1b, t2b, W2b, nullptr, CD, CH);
  scale_all_k<<<9, 256, 0, stream>>>(t1s, t2s, t1a, t2a, t1b, t2b,
                                     sigma_slot, sig1, sig2, scales);

  // x hi/lo split + token-group-mean hi/lo split (single pass over x)
  xsplit_fused_k<<<(CB * CS * (CD / 8)) / 256, 256, 0, stream>>>(x, xh, xl, xmh, xml);

  // SE = (xm @ W_slot^T) * scale_slot, split-bf16 3-term -> SE hi/lo planes
  mgemm3_k<false><<<dim3(4096 / 128, 2048 / 128, 1), 256, 0, stream>>>(
      xmh, xml, 0L, CD, wslh, wsll, 0L, CD, MEpSESplit{seh, sel, scales}, CD,
      nullptr, nullptr);

  // logits[b] = x_b @ SE_b^T, split-bf16 3-term -> f32, + fused col stats
  mgemm3_k<true><<<dim3(CES / 128, CN / 128, CB), 256, 0, stream>>>(
      xh, xl, (long)CN * CD, CD, seh, sel, (long)CES * CD, CD,
      MEpLogits{logits}, CD, pmax, psum);

  // dispatch softmax stat combine (16 slabs of 128 rows)
  colstat_comb_k<<<(CB * CES) / 256, 256, 0, stream>>>(pmax, psum, cmax, csum);

  // dispT[b][es][n] = bf16(exp(lg - cmax))   (overwrites xh/xl; dead after logits)
  tr_f2b_k<<<dim3(CES / 32, CN / 32, CB), 256, 0, stream>>>(logits, dispT, cmax, CN, CES, 1);
  // xT[b][d][n] = bf16(x^T)                  (overwrites seh; dead after logits)
  tr_f2b_k<<<dim3(CD / 32, CN / 32, CB), 256, 0, stream>>>(x, xT, nullptr, CN, CD, 0);

  // slots: [b] dispT(2048 x K2048) @ xT(1024 x K2048)^T -> slotsB (bf16, /csum)
  mgemm_db_k<128, 32><<<dim3(CD / 128, CES / 128, CB), 256, 0, stream>>>(
      dispT, (long)CES * CN, CN, xT, (long)CD * CN, CN, MEpSlots{slotsB, csum}, CN);

  // combineB[b][n][es] = bf16(softmax over es)   (overwrites dispT; dead)
  rowcomb_k<<<CB * CN, 256, 0, stream>>>(logits, combineB);

  // FFN1: [e] slotsB(2048 x K1024) @ W1b(4096 x K1024)^T -> hbuf (gelu, bf16)
  mgemm_big_k<<<dim3(CH / 128, 2048 / 256, CE), 512, 0, stream>>>(
      slotsB, (long)2048 * CD, CD, W1b, (long)CH * CD, CD, MEpGelu{hbuf, scales, b1}, CD);

  // FFN2 (swapped, writes y^T directly): [e] W2b(1024 x K4096) @ hbuf(2048 x K4096)^T
  mgemm_db_k<128, 32><<<dim3(2048 / 128, CD / 128, CE), 256, 0, stream>>>(
      W2b, (long)CD * CH, CH, hbuf, (long)2048 * CH, CH, MEpYT{outbufT, scales, b2}, CH);

  // final: [b] combineB(2048 x K2048) @ outbufT(1024 x K2048)^T -> out f32
  mgemm_db_k<128, 32><<<dim3(CD / 128, CN / 128, CB), 256, 0, stream>>>(
      combineB, (long)CN * CES, CES, outbufT, (long)CD * CES, CES, MEpOut{out}, CES);

  (void)in_sizes; (void)n_in; (void)out_size; (void)ws_size;
}

// Round 18
// 791.952 us; speedup vs baseline: 1.0797x; 1.0061x over previous
//
#include <hip/hip_runtime.h>
#include <hip/hip_bf16.h>
#include <math.h>

constexpr int CB  = 4;     // batch
constexpr int CN  = 2048;  // tokens
constexpr int CD  = 1024;  // model dim
constexpr int CE  = 4;     // experts
constexpr int CS  = 512;   // slots per expert
constexpr int CH  = 4096;  // expert hidden
constexpr int CES = 2048;  // E*S

typedef unsigned short u16;
typedef unsigned int   u32;
typedef __bf16 bf16x8 __attribute__((ext_vector_type(8)));
typedef float  f32x4  __attribute__((ext_vector_type(4)));

__device__ __forceinline__ u16 f2bf(float x) {
  u32 u = __float_as_uint(x);
  u = (u + 0x7FFF + ((u >> 16) & 1)) >> 16;   // round-to-nearest-even
  return (u16)u;
}

__device__ __forceinline__ void gl2lds16(const void* g, void* l) {
  __builtin_amdgcn_global_load_lds(
      (const __attribute__((address_space(1))) void*)g,
      (__attribute__((address_space(3))) void*)l, 16, 0, 0);
}

// bijective XCD-aware block swizzle (all grids have nwg % 8 == 0)
__device__ __forceinline__ void xcd_swz(int& bx, int& by, int& bz) {
  u32 gx = gridDim.x, gy = gridDim.y;
  u32 w = blockIdx.x + gx * (blockIdx.y + gy * blockIdx.z);
  u32 nwg = gx * gy * gridDim.z;
  u32 q = nwg >> 3;
  u32 wg = (w & 7) * q + (w >> 3);
  bx = wg % gx;
  u32 r = wg / gx;
  by = r % gy;
  bz = r / gy;
}

// ---------------- spectral-norm scale kernels ----------------
// scale = sigma * ||W u|| / ||W^T (W u)||

__global__ __launch_bounds__(256) void gemv_rows_k(const float* __restrict__ W,
    const float* __restrict__ u, float* __restrict__ t1, int M, int K, int ustride) {
  int bi = blockIdx.y;
  int row = blockIdx.x * 4 + (threadIdx.x >> 6);
  int lane = threadIdx.x & 63;
  const float* Wr = W + ((long)bi * M + row) * K;
  const float* ub = u + (long)bi * ustride;
  float s = 0.f;
  for (int k = lane; k < K; k += 64) s += Wr[k] * ub[k];
#pragma unroll
  for (int off = 32; off; off >>= 1) s += __shfl_down(s, off, 64);
  if (lane == 0) t1[bi * M + row] = s;
}

// also emits bf16 conversion of W (and optional lo-plane split)
__global__ __launch_bounds__(256) void gemv_cols_k(const float* __restrict__ W,
    const float* __restrict__ t1, float* __restrict__ t2,
    u16* __restrict__ bh, u16* __restrict__ bl, int M, int K) {
  int bi = blockIdx.z;
  int k = blockIdx.x * 256 + threadIdx.x;
  int m0 = blockIdx.y * 256;
  const float* Wb = W + (long)bi * M * K;
  const float* tb = t1 + bi * M;
  u16* bhb = bh + (long)bi * M * K;
  u16* blb = bl ? bl + (long)bi * M * K : nullptr;
  float s = 0.f;
#pragma unroll 4
  for (int m = 0; m < 256; m++) {
    long idx = (long)(m0 + m) * K + k;
    float w = Wb[idx];
    s += w * tb[m0 + m];
    u16 h = f2bf(w);
    bhb[idx] = h;
    if (blb) blb[idx] = f2bf(w - __uint_as_float((u32)h << 16));
  }
  atomicAdd(&t2[bi * K + k], s);
}

// all 9 spectral scales in one launch: block 0 = W_slot, 1..4 = W1[e], 5..8 = W2[e]
__global__ __launch_bounds__(256) void scale_all_k(
    const float* __restrict__ t1s, const float* __restrict__ t2s,
    const float* __restrict__ t1a, const float* __restrict__ t2a,
    const float* __restrict__ t1b, const float* __restrict__ t2b,
    const float* __restrict__ sigs, const float* __restrict__ sig1,
    const float* __restrict__ sig2, float* __restrict__ scales) {
  int bi = blockIdx.x;
  const float *t1, *t2; float sg; float* o; int M, K;
  if (bi == 0)      { t1 = t1s;                 t2 = t2s;                 sg = sigs[0];     o = scales + 0;      M = 4096; K = 1024; }
  else if (bi < 5)  { int e = bi - 1; t1 = t1a + e * 4096; t2 = t2a + e * 1024; sg = sig1[e]; o = scales + 1 + e; M = 4096; K = 1024; }
  else              { int e = bi - 5; t1 = t1b + e * 1024; t2 = t2b + e * 4096; sg = sig2[e]; o = scales + 5 + e; M = 1024; K = 4096; }
  int tid = threadIdx.x;
  __shared__ float red[256];
  float s1 = 0.f;
  for (int i = tid; i < M; i += 256) { float v = t1[i]; s1 += v * v; }
  red[tid] = s1; __syncthreads();
  for (int w = 128; w; w >>= 1) { if (tid < w) red[tid] += red[tid + w]; __syncthreads(); }
  float n1 = red[0]; __syncthreads();
  float s2 = 0.f;
  for (int i = tid; i < K; i += 256) { float v = t2[i]; s2 += v * v; }
  red[tid] = s2; __syncthreads();
  for (int w = 128; w; w >>= 1) { if (tid < w) red[tid] += red[tid + w]; __syncthreads(); }
  if (tid == 0) o[0] = sg * sqrtf(n1 / red[0]);
}

// ---------------- fused x hi/lo split + token-group-mean hi/lo split ----------------
__global__ __launch_bounds__(256) void xsplit_fused_k(const float* __restrict__ x,
    u16* __restrict__ xh, u16* __restrict__ xl,
    u16* __restrict__ xmh, u16* __restrict__ xml) {
  int idx = blockIdx.x * 256 + threadIdx.x;      // b*S*(D/8) total
  int d8 = idx & (CD / 8 - 1);
  int si = (idx >> 7) & (CS - 1);
  int b  = idx >> 16;
  long rbase = ((long)(b * CN + si * 4)) * CD + d8 * 8;
  float vr[4][8];
#pragma unroll
  for (int r = 0; r < 4; r++) {
    float4 a = *(const float4*)(x + rbase + (long)r * CD);
    float4 c = *(const float4*)(x + rbase + (long)r * CD + 4);
    vr[r][0]=a.x; vr[r][1]=a.y; vr[r][2]=a.z; vr[r][3]=a.w;
    vr[r][4]=c.x; vr[r][5]=c.y; vr[r][6]=c.z; vr[r][7]=c.w;
  }
#pragma unroll
  for (int r = 0; r < 4; r++) {
    u16 oh[8], ol[8];
#pragma unroll
    for (int c = 0; c < 8; c++) {
      u16 h = f2bf(vr[r][c]);
      oh[c] = h;
      ol[c] = f2bf(vr[r][c] - __uint_as_float((u32)h << 16));
    }
    *(uint4*)(xh + rbase + (long)r * CD) = *(const uint4*)oh;
    *(uint4*)(xl + rbase + (long)r * CD) = *(const uint4*)ol;
  }
  long mbase = ((long)(b * CS + si)) * CD + d8 * 8;
  u16 oh[8], ol[8];
#pragma unroll
  for (int c = 0; c < 8; c++) {
    float v = 0.25f * (vr[0][c] + vr[1][c] + vr[2][c] + vr[3][c]);
    u16 h = f2bf(v);
    oh[c] = h;
    ol[c] = f2bf(v - __uint_as_float((u32)h << 16));
  }
  *(uint4*)(xmh + mbase) = *(const uint4*)oh;
  *(uint4*)(xml + mbase) = *(const uint4*)ol;
}

// ---------------- dispatch softmax stat combine (16 slabs of 128 rows) ----------------
__global__ __launch_bounds__(256) void colstat_comb_k(const float* __restrict__ pmax,
    const float* __restrict__ psum, float* __restrict__ cmax, float* __restrict__ csum) {
  int idx = blockIdx.x * 256 + threadIdx.x;   // b*CES
  int b = idx >> 11;
  int es = idx & (CES - 1);
  float m = -1e30f;
#pragma unroll
  for (int sl = 0; sl < 16; sl++) m = fmaxf(m, pmax[(b * 16 + sl) * CES + es]);
  float s = 0.f;
#pragma unroll
  for (int sl = 0; sl < 16; sl++)
    s += psum[(b * 16 + sl) * CES + es] * __expf(pmax[(b * 16 + sl) * CES + es] - m);
  cmax[idx] = m; csum[idx] = s;
}

// ---------------- fused combine softmax (over es) -> bf16 ----------------
__global__ __launch_bounds__(256) void rowcomb_k(const float* __restrict__ lg,
                                                 u16* __restrict__ outB) {
  __shared__ float red[8];
  long row = blockIdx.x;                       // b*CN + n
  const float* p = lg + row * CES + threadIdx.x * 8;
  float4 a = *(const float4*)p;
  float4 b = *(const float4*)(p + 4);
  float v[8] = {a.x, a.y, a.z, a.w, b.x, b.y, b.z, b.w};
  float m = v[0];
#pragma unroll
  for (int c = 1; c < 8; c++) m = fmaxf(m, v[c]);
#pragma unroll
  for (int off = 32; off; off >>= 1) m = fmaxf(m, __shfl_xor(m, off, 64));
  int wv = threadIdx.x >> 6;
  if ((threadIdx.x & 63) == 0) red[wv] = m;
  __syncthreads();
  m = fmaxf(fmaxf(red[0], red[1]), fmaxf(red[2], red[3]));
  float s = 0.f;
#pragma unroll
  for (int c = 0; c < 8; c++) { v[c] = __expf(v[c] - m); s += v[c]; }
#pragma unroll
  for (int off = 32; off; off >>= 1) s += __shfl_xor(s, off, 64);
  if ((threadIdx.x & 63) == 0) red[4 + wv] = s;
  __syncthreads();
  float inv = 1.f / (red[4] + red[5] + red[6] + red[7]);
  u16 o[8];
#pragma unroll
  for (int c = 0; c < 8; c++) o[c] = f2bf(v[c] * inv);
  *(uint4*)(outB + row * CES + threadIdx.x * 8) = *(const uint4*)o;
}

// in [z][R][C] f32 -> out [z][C][R] bf16; expmode: v = exp(v - sub[z*C + col])
__global__ __launch_bounds__(256) void tr_f2b_k(const float* __restrict__ in,
    u16* __restrict__ out, const float* __restrict__ sub, int R, int C, int expmode) {
  __shared__ u16 t[32][33];
  int z = blockIdx.z;
  long ibase = (long)z * R * C;
  int r0 = blockIdx.y * 32, c0 = blockIdx.x * 32;
  int tx = threadIdx.x & 31, ty = threadIdx.x >> 5;
  float cm = expmode ? sub[(long)z * C + c0 + tx] : 0.f;
  for (int rr = ty; rr < 32; rr += 8) {
    float v = in[ibase + (long)(r0 + rr) * C + c0 + tx];
    if (expmode) v = __expf(v - cm);
    t[tx][rr] = f2bf(v);
  }
  __syncthreads();
  for (int cc = ty; cc < 32; cc += 8)
    out[ibase + (long)(c0 + cc) * R + r0 + tx] = t[cc][tx];
}

// ---------------- epilogues ----------------
struct MEpSESplit {  // SE hi/lo planes [b][es][d], es = ei*512+si; m=(b,si), n=(ei,di)
  u16* hi; u16* lo; const float* scale;
  __device__ void store(int z, int m, int n, float v) const {
    v *= scale[0];
    int b = m >> 9, si = m & 511, ei = n >> 10, di = n & 1023;
    long o = ((long)(b * CES + ei * 512 + si)) * CD + di;
    u16 h = f2bf(v);
    hi[o] = h;
    lo[o] = f2bf(v - __uint_as_float((u32)h << 16));
  }
};
struct MEpLogits {   // logits[b][n][es] = v ; z=b, m=token, n=es
  float* lg;
  __device__ void store(int b, int m, int n, float v) const {
    lg[((long)(b * CN + m)) * CES + n] = v;
  }
};
struct MEpSlots {  // slotsB[e][b*512+si][d] = bf16(v / csum[b][es]); z=b, m=es
  u16* sb; const float* __restrict__ csum;
  __device__ void store(int b, int m, int n, float v) const {
    float inv = 1.f / csum[b * CES + m];
    int e = m >> 9, si = m & 511;
    sb[((long)(e * 2048 + b * 512 + si)) * CD + n] = f2bf(v * inv);
  }
};
struct MEpGelu {   // h[e][m][H] = bf16(gelu(v*sc1[e] + b1[e][n])); z=e, m=(b,si)
  // tanh-form GELU: |err vs exact| below bf16 rounding of h (verified r8/r9).
  u16* h; const float* __restrict__ scales; const float* __restrict__ b1;
  __device__ void store(int e, int m, int n, float v) const {
    float xg = v * scales[1 + e] + b1[e * CH + n];
    float t = xg * (0.7978845608f + 0.0356774081f * xg * xg);
    float ex = __expf(2.f * t);
    float th = 1.f - 2.f / (ex + 1.f);          // tanh(t), saturates correctly
    float g = 0.5f * xg * (1.f + th);
    h[((long)(e * 2048 + m)) * CH + n] = f2bf(g);
  }
};
struct MEpYT {     // outbufT[b][d][es] = bf16(v*sc2[e] + b2[e][m]); z=e, m=d, n=(b,si)
  u16* ot; const float* __restrict__ scales; const float* __restrict__ b2;
  __device__ void store(int e, int m, int n, float v) const {
    int b = n >> 9, si = n & 511;
    ot[((long)(b * CD + m)) * CES + e * 512 + si] = f2bf(v * scales[5 + e] + b2[e * CD + m]);
  }
};
struct MEpOut {    // out[b][n][d] = v (combine already has 1/rsum); z=b
  float* o;
  __device__ void store(int b, int m, int n, float v) const {
    o[((long)(b * CN + m)) * CD + n] = v;
  }
};

// ------ bf16 MFMA GEMM, 128xBN, 4 waves, 2-deep db + counted vmcnt (r15-proven) ------
template <int BN, int BK, class EP>
__global__ __launch_bounds__(256) void mgemm_db_k(const u16* __restrict__ A, long Azs, int ldA,
                                                  const u16* __restrict__ B, long Bzs, int ldB,
                                                  EP ep, int K) {
  constexpr int BM = 128;
  constexpr int FI = 4;
  constexpr int FJ = BN / 32;
  constexpr int RPL = 512 / BK;            // rows per 1KB load-group
  constexpr int NGRP = (BM + BN) / RPL;    // 1KB groups per K-step
  constexpr int GPW = NGRP / 4;            // gl2lds instructions per wave per stage
  static_assert(GPW == 4, "vmcnt literals below assume 4 loads per stage");
  __shared__ __align__(16) u16 S[2][(BM + BN) * BK];
  int bx, by, bz;
  xcd_swz(bx, by, bz);
  const int tid = threadIdx.x;
  const int wid = tid >> 6, lane = tid & 63;
  const int m0 = by * BM, n0 = bx * BN;
  const u16* Az = A + (long)bz * Azs;
  const u16* Bz = B + (long)bz * Bzs;
  const int wr = wid >> 1, wc = wid & 1;
  const int lrow = lane / (BK / 8);        // row within load-group
  const int lk   = (lane % (BK / 8)) * 8;  // k offset within row

  auto stage = [&](int buf, int k0) {
#pragma unroll
    for (int g = 0; g < GPW; g++) {
      int grp = g * 4 + wid;
      int row = grp * RPL + lrow;          // A rows [0,BM), then B rows
      const u16* src = (row < BM)
          ? Az + (long)(m0 + row) * ldA + k0 + lk
          : Bz + (long)(n0 + row - BM) * ldB + k0 + lk;
      gl2lds16(src, (char*)S[buf] + grp * 1024);
    }
  };

  f32x4 acc[FI][FJ];
  f32x4 zero = {0.f, 0.f, 0.f, 0.f};
#pragma unroll
  for (int i = 0; i < FI; i++)
#pragma unroll
    for (int j = 0; j < FJ; j++) acc[i][j] = zero;

  stage(0, 0);
  int cur = 0;
  for (int k0 = 0; k0 < K; k0 += BK) {
    if (k0 + BK < K) {
      stage(cur ^ 1, k0 + BK);             // prefetch next tile
      asm volatile("s_waitcnt vmcnt(4)" ::: "memory");   // cur-tile done; next in flight
    } else {
      asm volatile("s_waitcnt vmcnt(0)" ::: "memory");   // final tile: full drain
    }
    __builtin_amdgcn_s_barrier();          // buffer cur complete for all waves
    __builtin_amdgcn_sched_barrier(0);
    const u16* Sc = S[cur];
#pragma unroll
    for (int kk2 = 0; kk2 < BK / 32; kk2++) {
      bf16x8 af[FI], bfr[FJ];
#pragma unroll
      for (int i = 0; i < FI; i++) {
        int arow = wr * 64 + i * 16 + (lane & 15);
        af[i] = *(const bf16x8*)&Sc[arow * BK + kk2 * 32 + (lane >> 4) * 8];
      }
#pragma unroll
      for (int j = 0; j < FJ; j++) {
        int brow = BM + wc * (BN / 2) + j * 16 + (lane & 15);
        bfr[j] = *(const bf16x8*)&Sc[brow * BK + kk2 * 32 + (lane >> 4) * 8];
      }
#pragma unroll
      for (int i = 0; i < FI; i++)
#pragma unroll
        for (int j = 0; j < FJ; j++)
          acc[i][j] = __builtin_amdgcn_mfma_f32_16x16x32_bf16(af[i], bfr[j], acc[i][j], 0, 0, 0);
    }
    __builtin_amdgcn_s_barrier();          // all waves done reading buffer cur
    __builtin_amdgcn_sched_barrier(0);
    cur ^= 1;
  }
#pragma unroll
  for (int i = 0; i < FI; i++) {
    int grow = m0 + wr * 64 + i * 16 + (lane >> 4) * 4;
#pragma unroll
    for (int j = 0; j < FJ; j++) {
      int gcol = n0 + wc * (BN / 2) + j * 16 + (lane & 15);
#pragma unroll
      for (int r = 0; r < 4; r++)
        ep.store(bz, grow + r, gcol, acc[i][j][r]);
    }
  }
}

// ---- bf16 MFMA GEMM, 256x128 tile, 8 waves, 2-deep db + counted vmcnt (FFN1) ----
// Same r15/r17-proven skeleton; GPW=3 loads/thread/stage -> vmcnt(3).
// LDS 2x24KB = 48KB -> 3 blocks/CU (threads cap is 4).
template <class EP>
__global__ __launch_bounds__(512) void mgemm_big_k(const u16* __restrict__ A, long Azs, int ldA,
                                                   const u16* __restrict__ B, long Bzs, int ldB,
                                                   EP ep, int K) {
  constexpr int BM = 256, BN = 128, BK = 32;
  __shared__ __align__(16) u16 S[2][(BM + BN) * BK];   // 2 x 24 KiB
  int bx, by, bz;
  xcd_swz(bx, by, bz);
  const int tid = threadIdx.x;
  const int wid = tid >> 6, lane = tid & 63;
  const int m0 = by * BM, n0 = bx * BN;
  const u16* Az = A + (long)bz * Azs;
  const u16* Bz = B + (long)bz * Bzs;
  const int wr = wid >> 1, wc = wid & 1;
  const int lrow = lane >> 2;              // 16 rows per 1KB group
  const int lk   = (lane & 3) * 8;

  auto stage = [&](int buf, int k0) {
#pragma unroll
    for (int g = 0; g < 3; g++) {          // 24 groups / 8 waves
      int grp = g * 8 + wid;
      int row = grp * 16 + lrow;           // A rows [0,256), then B rows
      const u16* src = (row < BM)
          ? Az + (long)(m0 + row) * ldA + k0 + lk
          : Bz + (long)(n0 + row - BM) * ldB + k0 + lk;
      gl2lds16(src, (char*)S[buf] + grp * 1024);
    }
  };

  f32x4 acc[4][4];
  f32x4 zero = {0.f, 0.f, 0.f, 0.f};
#pragma unroll
  for (int i = 0; i < 4; i++)
#pragma unroll
    for (int j = 0; j < 4; j++) acc[i][j] = zero;

  stage(0, 0);
  int cur = 0;
  for (int k0 = 0; k0 < K; k0 += BK) {
    if (k0 + BK < K) {
      stage(cur ^ 1, k0 + BK);             // prefetch next tile
      asm volatile("s_waitcnt vmcnt(3)" ::: "memory");   // cur stage (3 loads) done
    } else {
      asm volatile("s_waitcnt vmcnt(0)" ::: "memory");
    }
    __builtin_amdgcn_s_barrier();
    __builtin_amdgcn_sched_barrier(0);
    const u16* Sc = S[cur];
    bf16x8 af[4], bfr[4];
#pragma unroll
    for (int i = 0; i < 4; i++) {
      int arow = wr * 64 + i * 16 + (lane & 15);
      af[i] = *(const bf16x8*)&Sc[arow * BK + (lane >> 4) * 8];
      int brow = BM + wc * 64 + i * 16 + (lane & 15);
      bfr[i] = *(const bf16x8*)&Sc[brow * BK + (lane >> 4) * 8];
    }
#pragma unroll
    for (int i = 0; i < 4; i++)
#pragma unroll
      for (int j = 0; j < 4; j++)
        acc[i][j] = __builtin_amdgcn_mfma_f32_16x16x32_bf16(af[i], bfr[j], acc[i][j], 0, 0, 0);
    __builtin_amdgcn_s_barrier();
    __builtin_amdgcn_sched_barrier(0);
    cur ^= 1;
  }
#pragma unroll
  for (int i = 0; i < 4; i++) {
    int grow = m0 + wr * 64 + i * 16 + (lane >> 4) * 4;
#pragma unroll
    for (int j = 0; j < 4; j++) {
      int gcol = n0 + wc * 64 + j * 16 + (lane & 15);
#pragma unroll
      for (int r = 0; r < 4; r++)
        ep.store(bz, grow + r, gcol, acc[i][j][r]);
    }
  }
}

// ---- split-bf16 3-term GEMM, 128^2 tile, 4 waves, 2-deep db + counted vmcnt ----
// (r17-proven.) CSTAT scratch reuses the stage buffer.
template <bool CSTAT, class EP>
__global__ __launch_bounds__(256) void mgemm3_k(const u16* __restrict__ Ah,
                                                const u16* __restrict__ Al, long Azs, int ldA,
                                                const u16* __restrict__ Bh,
                                                const u16* __restrict__ Bl, long Bzs, int ldB,
                                                EP ep, int K,
                                                float* __restrict__ pmax,
                                                float* __restrict__ psum) {
  constexpr int BK = 32;
  __shared__ __align__(16) u16 S[2][16384];   // per buf: Ah|Al|Bh|Bl, 8KB each
  int bx, by, bz;
  xcd_swz(bx, by, bz);
  const int tid = threadIdx.x;
  const int wid = tid >> 6, lane = tid & 63;
  const int m0 = by * 128, n0 = bx * 128;
  const u16* Ahz = Ah + (long)bz * Azs;
  const u16* Alz = Al + (long)bz * Azs;
  const u16* Bhz = Bh + (long)bz * Bzs;
  const u16* Blz = Bl + (long)bz * Bzs;
  const int wr = wid >> 1, wc = wid & 1;
  const int srow = lane >> 2;
  const int sk8  = (lane & 3) * 8;

  auto stage = [&](int buf, int k0) {
    char* base = (char*)S[buf];
#pragma unroll
    for (int i = 0; i < 2; i++) {
      int chunk = i * 4 + wid;
      int r = chunk * 16 + srow;
      long ao = (long)(m0 + r) * ldA + k0 + sk8;
      long bo = (long)(n0 + r) * ldB + k0 + sk8;
      gl2lds16(Ahz + ao, base + chunk * 1024);
      gl2lds16(Alz + ao, base + 8192 + chunk * 1024);
      gl2lds16(Bhz + bo, base + 16384 + chunk * 1024);
      gl2lds16(Blz + bo, base + 24576 + chunk * 1024);
    }
  };

  f32x4 acc[4][4];
  f32x4 zero = {0.f, 0.f, 0.f, 0.f};
#pragma unroll
  for (int i = 0; i < 4; i++)
#pragma unroll
    for (int j = 0; j < 4; j++) acc[i][j] = zero;

  stage(0, 0);
  int cur = 0;
  for (int k0 = 0; k0 < K; k0 += BK) {
    if (k0 + BK < K) {
      stage(cur ^ 1, k0 + BK);             // prefetch next tile
      asm volatile("s_waitcnt vmcnt(8)" ::: "memory");   // cur stage (8 loads) done
    } else {
      asm volatile("s_waitcnt vmcnt(0)" ::: "memory");
    }
    __builtin_amdgcn_s_barrier();
    __builtin_amdgcn_sched_barrier(0);
    const u16* Sb = S[cur];
    bf16x8 ah[4], al[4], bh[4], bl[4];
#pragma unroll
    for (int i = 0; i < 4; i++) {
      int arow = wr * 64 + i * 16 + (lane & 15);
      int aoff = arow * BK + (lane >> 4) * 8;
      ah[i] = *(const bf16x8*)&Sb[aoff];
      al[i] = *(const bf16x8*)&Sb[4096 + aoff];
      int brow = wc * 64 + i * 16 + (lane & 15);
      int boff = brow * BK + (lane >> 4) * 8;
      bh[i] = *(const bf16x8*)&Sb[8192 + boff];
      bl[i] = *(const bf16x8*)&Sb[12288 + boff];
    }
#pragma unroll
    for (int i = 0; i < 4; i++)
#pragma unroll
      for (int j = 0; j < 4; j++) {
        acc[i][j] = __builtin_amdgcn_mfma_f32_16x16x32_bf16(ah[i], bh[j], acc[i][j], 0, 0, 0);
        acc[i][j] = __builtin_amdgcn_mfma_f32_16x16x32_bf16(al[i], bh[j], acc[i][j], 0, 0, 0);
        acc[i][j] = __builtin_amdgcn_mfma_f32_16x16x32_bf16(ah[i], bl[j], acc[i][j], 0, 0, 0);
      }
    __builtin_amdgcn_s_barrier();
    __builtin_amdgcn_sched_barrier(0);
    cur ^= 1;
  }
#pragma unroll
  for (int i = 0; i < 4; i++) {
    int grow = m0 + wr * 64 + i * 16 + (lane >> 4) * 4;
#pragma unroll
    for (int j = 0; j < 4; j++) {
      int gcol = n0 + wc * 64 + j * 16 + (lane & 15);
#pragma unroll
      for (int r = 0; r < 4; r++)
        ep.store(bz, grow + r, gcol, acc[i][j][r]);
    }
  }

  if constexpr (CSTAT) {
    // stage buffers are dead after the K-loop's final barrier; reuse as scratch.
    float* cred = (float*)&S[0][0];        // [2][128]
    float* sred = cred + 256;              // [2][128]
    float cmv[4], lsum[4];
#pragma unroll
    for (int j = 0; j < 4; j++) {
      float m = acc[0][j][0];
#pragma unroll
      for (int i = 0; i < 4; i++)
#pragma unroll
        for (int r = 0; r < 4; r++) m = fmaxf(m, acc[i][j][r]);
      m = fmaxf(m, __shfl_xor(m, 16, 64));
      m = fmaxf(m, __shfl_xor(m, 32, 64));
      cmv[j] = m;                          // col max over this wave's 64 rows
    }
    if (lane < 16) {
#pragma unroll
      for (int j = 0; j < 4; j++) cred[wr * 128 + wc * 64 + j * 16 + lane] = cmv[j];
    }
    __syncthreads();
#pragma unroll
    for (int j = 0; j < 4; j++) {
      int c = wc * 64 + j * 16 + (lane & 15);
      float cm = fmaxf(cred[c], cred[128 + c]);   // block col max (128 rows)
      float s = 0.f;
#pragma unroll
      for (int i = 0; i < 4; i++)
#pragma unroll
        for (int r = 0; r < 4; r++) s += __expf(acc[i][j][r] - cm);
      s += __shfl_xor(s, 16, 64);
      s += __shfl_xor(s, 32, 64);
      cmv[j] = cm; lsum[j] = s;
    }
    if (lane < 16) {
#pragma unroll
      for (int j = 0; j < 4; j++) sred[wr * 128 + wc * 64 + j * 16 + lane] = lsum[j];
    }
    __syncthreads();
    if (wr == 0 && lane < 16) {
      long sb = ((long)bz * 16 + by) * CES + n0;
#pragma unroll
      for (int j = 0; j < 4; j++) {
        int c = wc * 64 + j * 16 + lane;
        pmax[sb + c] = cmv[j];
        psum[sb + c] = sred[c] + sred[128 + c];
      }
    }
  }
}

// ---------------- launch ----------------
extern "C" void kernel_launch(void* const* d_in, const int* in_sizes, int n_in,
                              void* d_out, int out_size, void* d_ws, size_t ws_size,
                              hipStream_t stream) {
  const float* x          = (const float*)d_in[0];
  const float* W_slot     = (const float*)d_in[1];
  const float* u_slot     = (const float*)d_in[2];
  const float* sigma_slot = (const float*)d_in[3];
  const float* W1         = (const float*)d_in[4];
  const float* b1         = (const float*)d_in[5];
  const float* u1         = (const float*)d_in[6];
  const float* sig1       = (const float*)d_in[7];
  const float* W2         = (const float*)d_in[8];
  const float* b2         = (const float*)d_in[9];
  const float* u2         = (const float*)d_in[10];
  const float* sig2       = (const float*)d_in[11];
  float* out = (float*)d_out;

  // ---- workspace overlays (peak ~202 MiB, proven footprint) ----
  char* ws = (char*)d_ws;
  size_t off = 0;
  auto alloc = [&](size_t bytes) -> char* {
    char* p = ws + off;
    off += (bytes + 255) & ~(size_t)255;
    return p;
  };
  float* t1s = (float*)alloc(4096 * 4);
  float* t1a = (float*)alloc(4 * 4096 * 4);
  float* t1b = (float*)alloc(4 * 1024 * 4);
  float* t2s = (float*)alloc(1024 * 4);
  float* t2a = (float*)alloc(4 * 1024 * 4);
  float* t2b = (float*)alloc(4 * 4096 * 4);
  float* scales = (float*)alloc(16 * 4);
  float* pmax   = (float*)alloc((size_t)CB * 16 * CES * 4);
  float* psum   = (float*)alloc((size_t)CB * 16 * CES * 4);
  float* cmax   = (float*)alloc((size_t)CB * CES * 4);
  float* csum   = (float*)alloc((size_t)CB * CES * 4);
  char* regAB   = alloc((size_t)CB * CN * CD * 2 * 2);                // 32 MiB
  char* regBB   = alloc((size_t)CB * CES * CD * 2 * 2);               // 32 MiB
  char* regL    = alloc((size_t)CB * CN * CES * 4);                   // 64 MiB
  char* regS    = alloc((size_t)CE * CB * CS * CD * 2);               // 16 MiB
  u16* W1b      = (u16*)alloc((size_t)CE * CH * CD * 2);              // 32 MiB
  u16* W2b      = (u16*)alloc((size_t)CE * CD * CH * 2);              // 32 MiB

  u16*   xh      = (u16*)regAB;                        // [b][n][d]
  u16*   xl      = (u16*)(regAB + (size_t)CB * CN * CD * 2);
  u16*   dispT   = (u16*)regAB;                        // [b][es][n]
  u16*   combineB= (u16*)regAB;                        // [b][n][es]
  u16*   seh     = (u16*)regBB;                        // [b][es][d]
  u16*   sel     = (u16*)(regBB + (size_t)CB * CES * CD * 2);
  u16*   xT      = (u16*)regBB;                        // [b][d][n]
  float* logits  = (float*)regL;                       // [b][n][es]
  u16*   hbuf    = (u16*)regL;                         // [e][2048][H]
  u16*   xmh     = (u16*)regL;                         // [(b,s)][d] 4 MiB
  u16*   xml     = (u16*)(regL + (size_t)CB * CS * CD * 2);
  u16*   wslh    = (u16*)(regL + (size_t)2 * CB * CS * CD * 2);  // [4096][1024] 8 MiB
  u16*   wsll    = (u16*)(regL + (size_t)2 * CB * CS * CD * 2 + (size_t)CE * CD * CD * 2);
  u16*   slotsB  = (u16*)regS;                         // [e][(b,si)][d]
  u16*   outbufT = (u16*)regS;                         // [b][d][es]

  // zero t2s..t2b in one span (consecutive 256-aligned allocs)
  hipMemsetAsync(t2s, 0, (size_t)((char*)t2b - (char*)t2s) + 4 * 4096 * 4, stream);

  // spectral scales (gemv_cols also emits bf16 weight planes)
  gemv_rows_k<<<dim3(4096 / 4, 1), 256, 0, stream>>>(W_slot, u_slot, t1s, 4096, 1024, 0);
  gemv_rows_k<<<dim3(4096 / 4, 4), 256, 0, stream>>>(W1, u1, t1a, CH, CD, CD);
  gemv_rows_k<<<dim3(1024 / 4, 4), 256, 0, stream>>>(W2, u2, t1b, CD, CH, CH);
  gemv_cols_k<<<dim3(1024 / 256, 4096 / 256, 1), 256, 0, stream>>>(W_slot, t1s, t2s, wslh, wsll, 4096, 1024);
  gemv_cols_k<<<dim3(1024 / 256, 4096 / 256, 4), 256, 0, stream>>>(W1, t1a, t2a, W1b, nullptr, CH, CD);
  gemv_cols_k<<<dim3(4096 / 256, 1024 / 256, 4), 256, 0, stream>>>(W2, t1b, t2b, W2b, nullptr, CD, CH);
  scale_all_k<<<9, 256, 0, stream>>>(t1s, t2s, t1a, t2a, t1b, t2b,
                                     sigma_slot, sig1, sig2, scales);

  // x hi/lo split + token-group-mean hi/lo split (single pass over x)
  xsplit_fused_k<<<(CB * CS * (CD / 8)) / 256, 256, 0, stream>>>(x, xh, xl, xmh, xml);

  // SE = (xm @ W_slot^T) * scale_slot, split-bf16 3-term -> SE hi/lo planes
  mgemm3_k<false><<<dim3(4096 / 128, 2048 / 128, 1), 256, 0, stream>>>(
      xmh, xml, 0L, CD, wslh, wsll, 0L, CD, MEpSESplit{seh, sel, scales}, CD,
      nullptr, nullptr);

  // logits[b] = x_b @ SE_b^T, split-bf16 3-term -> f32, + fused col stats
  mgemm3_k<true><<<dim3(CES / 128, CN / 128, CB), 256, 0, stream>>>(
      xh, xl, (long)CN * CD, CD, seh, sel, (long)CES * CD, CD,
      MEpLogits{logits}, CD, pmax, psum);

  // dispatch softmax stat combine (16 slabs of 128 rows)
  colstat_comb_k<<<(CB * CES) / 256, 256, 0, stream>>>(pmax, psum, cmax, csum);

  // dispT[b][es][n] = bf16(exp(lg - cmax))   (overwrites xh/xl; dead after logits)
  tr_f2b_k<<<dim3(CES / 32, CN / 32, CB), 256, 0, stream>>>(logits, dispT, cmax, CN, CES, 1);
  // xT[b][d][n] = bf16(x^T)                  (overwrites seh; dead after logits)
  tr_f2b_k<<<dim3(CD / 32, CN / 32, CB), 256, 0, stream>>>(x, xT, nullptr, CN, CD, 0);

  // slots: [b] dispT(2048 x K2048) @ xT(1024 x K2048)^T -> slotsB (bf16, /csum)
  mgemm_db_k<128, 32><<<dim3(CD / 128, CES / 128, CB), 256, 0, stream>>>(
      dispT, (long)CES * CN, CN, xT, (long)CD * CN, CN, MEpSlots{slotsB, csum}, CN);

  // combineB[b][n][es] = bf16(softmax over es)   (overwrites dispT; dead)
  rowcomb_k<<<CB * CN, 256, 0, stream>>>(logits, combineB);

  // FFN1: [e] slotsB(2048 x K1024) @ W1b(4096 x K1024)^T -> hbuf (gelu, bf16)
  // (256x128 tile, 1024 blocks, now db + counted vmcnt)
  mgemm_big_k<<<dim3(CH / 128, 2048 / 256, CE), 512, 0, stream>>>(
      slotsB, (long)2048 * CD, CD, W1b, (long)CH * CD, CD, MEpGelu{hbuf, scales, b1}, CD);

  // FFN2 (swapped, writes y^T directly): [e] W2b(1024 x K4096) @ hbuf(2048 x K4096)^T
  mgemm_db_k<128, 32><<<dim3(2048 / 128, CD / 128, CE), 256, 0, stream>>>(
      W2b, (long)CD * CH, CH, hbuf, (long)2048 * CH, CH, MEpYT{outbufT, scales, b2}, CH);

  // final: [b] combineB(2048 x K2048) @ outbufT(1024 x K2048)^T -> out f32
  mgemm_db_k<128, 32><<<dim3(CD / 128, CN / 128, CB), 256, 0, stream>>>(
      combineB, (long)CN * CES, CES, outbufT, (long)CD * CES, CES, MEpOut{out}, CES);

  (void)in_sizes; (void)n_in; (void)out_size; (void)ws_size;
}

// Round 19
// 786.172 us; speedup vs baseline: 1.0876x; 1.0074x over previous
//
#include <hip/hip_runtime.h>
#include <hip/hip_bf16.h>
#include <math.h>

constexpr int CB  = 4;     // batch
constexpr int CN  = 2048;  // tokens
constexpr int CD  = 1024;  // model dim
constexpr int CE  = 4;     // experts
constexpr int CS  = 512;   // slots per expert
constexpr int CH  = 4096;  // expert hidden
constexpr int CES = 2048;  // E*S

typedef unsigned short u16;
typedef unsigned int   u32;
typedef __bf16 bf16x8 __attribute__((ext_vector_type(8)));
typedef float  f32x4  __attribute__((ext_vector_type(4)));

__device__ __forceinline__ u16 f2bf(float x) {
  u32 u = __float_as_uint(x);
  u = (u + 0x7FFF + ((u >> 16) & 1)) >> 16;   // round-to-nearest-even
  return (u16)u;
}

__device__ __forceinline__ void gl2lds16(const void* g, void* l) {
  __builtin_amdgcn_global_load_lds(
      (const __attribute__((address_space(1))) void*)g,
      (__attribute__((address_space(3))) void*)l, 16, 0, 0);
}

// bijective XCD-aware block swizzle (all grids have nwg % 8 == 0)
__device__ __forceinline__ void xcd_swz(int& bx, int& by, int& bz) {
  u32 gx = gridDim.x, gy = gridDim.y;
  u32 w = blockIdx.x + gx * (blockIdx.y + gy * blockIdx.z);
  u32 nwg = gx * gy * gridDim.z;
  u32 q = nwg >> 3;
  u32 wg = (w & 7) * q + (w >> 3);
  bx = wg % gx;
  u32 r = wg / gx;
  by = r % gy;
  bz = r / gy;
}

// LDS bank-conflict swizzle (rule #21: both-sides-or-neither with gl2lds).
// Row = 64B (BK=32 bf16) = 4 chunks of 16B. Involution: chunk ^= (row>>1)&3.
// Staging lane l writes LDS (row=l>>2, chunk=l&3) -> must LOAD global chunk
// (l&3)^((l>>3)&3). Reader of (row, chunk g) reads LDS chunk g^((row>>1)&3).
// Spreads the 16-row fragment read from 8-way conflict to 2-way (free, m136).

// ---------------- spectral-norm scale kernels ----------------
// scale = sigma * ||W u|| / ||W^T (W u)||

__global__ __launch_bounds__(256) void gemv_rows_k(const float* __restrict__ W,
    const float* __restrict__ u, float* __restrict__ t1, int M, int K, int ustride) {
  int bi = blockIdx.y;
  int row = blockIdx.x * 4 + (threadIdx.x >> 6);
  int lane = threadIdx.x & 63;
  const float* Wr = W + ((long)bi * M + row) * K;
  const float* ub = u + (long)bi * ustride;
  float s = 0.f;
  for (int k = lane; k < K; k += 64) s += Wr[k] * ub[k];
#pragma unroll
  for (int off = 32; off; off >>= 1) s += __shfl_down(s, off, 64);
  if (lane == 0) t1[bi * M + row] = s;
}

// also emits bf16 conversion of W (and optional lo-plane split)
__global__ __launch_bounds__(256) void gemv_cols_k(const float* __restrict__ W,
    const float* __restrict__ t1, float* __restrict__ t2,
    u16* __restrict__ bh, u16* __restrict__ bl, int M, int K) {
  int bi = blockIdx.z;
  int k = blockIdx.x * 256 + threadIdx.x;
  int m0 = blockIdx.y * 256;
  const float* Wb = W + (long)bi * M * K;
  const float* tb = t1 + bi * M;
  u16* bhb = bh + (long)bi * M * K;
  u16* blb = bl ? bl + (long)bi * M * K : nullptr;
  float s = 0.f;
#pragma unroll 4
  for (int m = 0; m < 256; m++) {
    long idx = (long)(m0 + m) * K + k;
    float w = Wb[idx];
    s += w * tb[m0 + m];
    u16 h = f2bf(w);
    bhb[idx] = h;
    if (blb) blb[idx] = f2bf(w - __uint_as_float((u32)h << 16));
  }
  atomicAdd(&t2[bi * K + k], s);
}

// all 9 spectral scales in one launch: block 0 = W_slot, 1..4 = W1[e], 5..8 = W2[e]
__global__ __launch_bounds__(256) void scale_all_k(
    const float* __restrict__ t1s, const float* __restrict__ t2s,
    const float* __restrict__ t1a, const float* __restrict__ t2a,
    const float* __restrict__ t1b, const float* __restrict__ t2b,
    const float* __restrict__ sigs, const float* __restrict__ sig1,
    const float* __restrict__ sig2, float* __restrict__ scales) {
  int bi = blockIdx.x;
  const float *t1, *t2; float sg; float* o; int M, K;
  if (bi == 0)      { t1 = t1s;                 t2 = t2s;                 sg = sigs[0];     o = scales + 0;      M = 4096; K = 1024; }
  else if (bi < 5)  { int e = bi - 1; t1 = t1a + e * 4096; t2 = t2a + e * 1024; sg = sig1[e]; o = scales + 1 + e; M = 4096; K = 1024; }
  else              { int e = bi - 5; t1 = t1b + e * 1024; t2 = t2b + e * 4096; sg = sig2[e]; o = scales + 5 + e; M = 1024; K = 4096; }
  int tid = threadIdx.x;
  __shared__ float red[256];
  float s1 = 0.f;
  for (int i = tid; i < M; i += 256) { float v = t1[i]; s1 += v * v; }
  red[tid] = s1; __syncthreads();
  for (int w = 128; w; w >>= 1) { if (tid < w) red[tid] += red[tid + w]; __syncthreads(); }
  float n1 = red[0]; __syncthreads();
  float s2 = 0.f;
  for (int i = tid; i < K; i += 256) { float v = t2[i]; s2 += v * v; }
  red[tid] = s2; __syncthreads();
  for (int w = 128; w; w >>= 1) { if (tid < w) red[tid] += red[tid + w]; __syncthreads(); }
  if (tid == 0) o[0] = sg * sqrtf(n1 / red[0]);
}

// ---------------- fused x hi/lo split + token-group-mean hi/lo split ----------------
__global__ __launch_bounds__(256) void xsplit_fused_k(const float* __restrict__ x,
    u16* __restrict__ xh, u16* __restrict__ xl,
    u16* __restrict__ xmh, u16* __restrict__ xml) {
  int idx = blockIdx.x * 256 + threadIdx.x;      // b*S*(D/8) total
  int d8 = idx & (CD / 8 - 1);
  int si = (idx >> 7) & (CS - 1);
  int b  = idx >> 16;
  long rbase = ((long)(b * CN + si * 4)) * CD + d8 * 8;
  float vr[4][8];
#pragma unroll
  for (int r = 0; r < 4; r++) {
    float4 a = *(const float4*)(x + rbase + (long)r * CD);
    float4 c = *(const float4*)(x + rbase + (long)r * CD + 4);
    vr[r][0]=a.x; vr[r][1]=a.y; vr[r][2]=a.z; vr[r][3]=a.w;
    vr[r][4]=c.x; vr[r][5]=c.y; vr[r][6]=c.z; vr[r][7]=c.w;
  }
#pragma unroll
  for (int r = 0; r < 4; r++) {
    u16 oh[8], ol[8];
#pragma unroll
    for (int c = 0; c < 8; c++) {
      u16 h = f2bf(vr[r][c]);
      oh[c] = h;
      ol[c] = f2bf(vr[r][c] - __uint_as_float((u32)h << 16));
    }
    *(uint4*)(xh + rbase + (long)r * CD) = *(const uint4*)oh;
    *(uint4*)(xl + rbase + (long)r * CD) = *(const uint4*)ol;
  }
  long mbase = ((long)(b * CS + si)) * CD + d8 * 8;
  u16 oh[8], ol[8];
#pragma unroll
  for (int c = 0; c < 8; c++) {
    float v = 0.25f * (vr[0][c] + vr[1][c] + vr[2][c] + vr[3][c]);
    u16 h = f2bf(v);
    oh[c] = h;
    ol[c] = f2bf(v - __uint_as_float((u32)h << 16));
  }
  *(uint4*)(xmh + mbase) = *(const uint4*)oh;
  *(uint4*)(xml + mbase) = *(const uint4*)ol;
}

// ---------------- dispatch softmax stat combine (16 slabs of 128 rows) ----------------
__global__ __launch_bounds__(256) void colstat_comb_k(const float* __restrict__ pmax,
    const float* __restrict__ psum, float* __restrict__ cmax, float* __restrict__ csum) {
  int idx = blockIdx.x * 256 + threadIdx.x;   // b*CES
  int b = idx >> 11;
  int es = idx & (CES - 1);
  float m = -1e30f;
#pragma unroll
  for (int sl = 0; sl < 16; sl++) m = fmaxf(m, pmax[(b * 16 + sl) * CES + es]);
  float s = 0.f;
#pragma unroll
  for (int sl = 0; sl < 16; sl++)
    s += psum[(b * 16 + sl) * CES + es] * __expf(pmax[(b * 16 + sl) * CES + es] - m);
  cmax[idx] = m; csum[idx] = s;
}

// ---------------- fused combine softmax (over es) -> bf16 ----------------
__global__ __launch_bounds__(256) void rowcomb_k(const float* __restrict__ lg,
                                                 u16* __restrict__ outB) {
  __shared__ float red[8];
  long row = blockIdx.x;                       // b*CN + n
  const float* p = lg + row * CES + threadIdx.x * 8;
  float4 a = *(const float4*)p;
  float4 b = *(const float4*)(p + 4);
  float v[8] = {a.x, a.y, a.z, a.w, b.x, b.y, b.z, b.w};
  float m = v[0];
#pragma unroll
  for (int c = 1; c < 8; c++) m = fmaxf(m, v[c]);
#pragma unroll
  for (int off = 32; off; off >>= 1) m = fmaxf(m, __shfl_xor(m, off, 64));
  int wv = threadIdx.x >> 6;
  if ((threadIdx.x & 63) == 0) red[wv] = m;
  __syncthreads();
  m = fmaxf(fmaxf(red[0], red[1]), fmaxf(red[2], red[3]));
  float s = 0.f;
#pragma unroll
  for (int c = 0; c < 8; c++) { v[c] = __expf(v[c] - m); s += v[c]; }
#pragma unroll
  for (int off = 32; off; off >>= 1) s += __shfl_xor(s, off, 64);
  if ((threadIdx.x & 63) == 0) red[4 + wv] = s;
  __syncthreads();
  float inv = 1.f / (red[4] + red[5] + red[6] + red[7]);
  u16 o[8];
#pragma unroll
  for (int c = 0; c < 8; c++) o[c] = f2bf(v[c] * inv);
  *(uint4*)(outB + row * CES + threadIdx.x * 8) = *(const uint4*)o;
}

// in [z][R][C] f32 -> out [z][C][R] bf16; expmode: v = exp(v - sub[z*C + col])
__global__ __launch_bounds__(256) void tr_f2b_k(const float* __restrict__ in,
    u16* __restrict__ out, const float* __restrict__ sub, int R, int C, int expmode) {
  __shared__ u16 t[32][33];
  int z = blockIdx.z;
  long ibase = (long)z * R * C;
  int r0 = blockIdx.y * 32, c0 = blockIdx.x * 32;
  int tx = threadIdx.x & 31, ty = threadIdx.x >> 5;
  float cm = expmode ? sub[(long)z * C + c0 + tx] : 0.f;
  for (int rr = ty; rr < 32; rr += 8) {
    float v = in[ibase + (long)(r0 + rr) * C + c0 + tx];
    if (expmode) v = __expf(v - cm);
    t[tx][rr] = f2bf(v);
  }
  __syncthreads();
  for (int cc = ty; cc < 32; cc += 8)
    out[ibase + (long)(c0 + cc) * R + r0 + tx] = t[cc][tx];
}

// ---------------- epilogues ----------------
struct MEpSESplit {  // SE hi/lo planes [b][es][d], es = ei*512+si; m=(b,si), n=(ei,di)
  u16* hi; u16* lo; const float* scale;
  __device__ void store(int z, int m, int n, float v) const {
    v *= scale[0];
    int b = m >> 9, si = m & 511, ei = n >> 10, di = n & 1023;
    long o = ((long)(b * CES + ei * 512 + si)) * CD + di;
    u16 h = f2bf(v);
    hi[o] = h;
    lo[o] = f2bf(v - __uint_as_float((u32)h << 16));
  }
};
struct MEpLogits {   // logits[b][n][es] = v ; z=b, m=token, n=es
  float* lg;
  __device__ void store(int b, int m, int n, float v) const {
    lg[((long)(b * CN + m)) * CES + n] = v;
  }
};
struct MEpSlots {  // slotsB[e][b*512+si][d] = bf16(v / csum[b][es]); z=b, m=es
  u16* sb; const float* __restrict__ csum;
  __device__ void store(int b, int m, int n, float v) const {
    float inv = 1.f / csum[b * CES + m];
    int e = m >> 9, si = m & 511;
    sb[((long)(e * 2048 + b * 512 + si)) * CD + n] = f2bf(v * inv);
  }
};
struct MEpGelu {   // h[e][m][H] = bf16(gelu(v*sc1[e] + b1[e][n])); z=e, m=(b,si)
  // tanh-form GELU: |err vs exact| below bf16 rounding of h (verified r8/r9).
  u16* h; const float* __restrict__ scales; const float* __restrict__ b1;
  __device__ void store(int e, int m, int n, float v) const {
    float xg = v * scales[1 + e] + b1[e * CH + n];
    float t = xg * (0.7978845608f + 0.0356774081f * xg * xg);
    float ex = __expf(2.f * t);
    float th = 1.f - 2.f / (ex + 1.f);          // tanh(t), saturates correctly
    float g = 0.5f * xg * (1.f + th);
    h[((long)(e * 2048 + m)) * CH + n] = f2bf(g);
  }
};
struct MEpYT {     // outbufT[b][d][es] = bf16(v*sc2[e] + b2[e][m]); z=e, m=d, n=(b,si)
  u16* ot; const float* __restrict__ scales; const float* __restrict__ b2;
  __device__ void store(int e, int m, int n, float v) const {
    int b = n >> 9, si = n & 511;
    ot[((long)(b * CD + m)) * CES + e * 512 + si] = f2bf(v * scales[5 + e] + b2[e * CD + m]);
  }
};
struct MEpOut {    // out[b][n][d] = v (combine already has 1/rsum); z=b
  float* o;
  __device__ void store(int b, int m, int n, float v) const {
    o[((long)(b * CN + m)) * CD + n] = v;
  }
};

// ------ bf16 MFMA GEMM, 128xBN, 4 waves, 2-deep db + counted vmcnt + LDS swizzle ------
template <int BN, int BK, class EP>
__global__ __launch_bounds__(256) void mgemm_db_k(const u16* __restrict__ A, long Azs, int ldA,
                                                  const u16* __restrict__ B, long Bzs, int ldB,
                                                  EP ep, int K) {
  constexpr int BM = 128;
  constexpr int FI = 4;
  constexpr int FJ = BN / 32;
  static_assert(BK == 32, "swizzle + vmcnt literals assume BK=32");
  constexpr int RPL = 16;                  // rows per 1KB load-group
  constexpr int NGRP = (BM + BN) / RPL;    // 1KB groups per K-step
  constexpr int GPW = NGRP / 4;            // gl2lds instructions per wave per stage
  static_assert(GPW == 4, "vmcnt literals below assume 4 loads per stage");
  __shared__ __align__(16) u16 S[2][(BM + BN) * BK];
  int bx, by, bz;
  xcd_swz(bx, by, bz);
  const int tid = threadIdx.x;
  const int wid = tid >> 6, lane = tid & 63;
  const int m0 = by * BM, n0 = bx * BN;
  const u16* Az = A + (long)bz * Azs;
  const u16* Bz = B + (long)bz * Bzs;
  const int wr = wid >> 1, wc = wid & 1;
  const int lrow = lane >> 2;              // row within load-group
  const int lk   = (((lane & 3) ^ ((lane >> 3) & 3)) * 8);  // swizzled source chunk

  auto stage = [&](int buf, int k0) {
#pragma unroll
    for (int g = 0; g < GPW; g++) {
      int grp = g * 4 + wid;
      int row = grp * RPL + lrow;          // A rows [0,BM), then B rows
      const u16* src = (row < BM)
          ? Az + (long)(m0 + row) * ldA + k0 + lk
          : Bz + (long)(n0 + row - BM) * ldB + k0 + lk;
      gl2lds16(src, (char*)S[buf] + grp * 1024);
    }
  };

  f32x4 acc[FI][FJ];
  f32x4 zero = {0.f, 0.f, 0.f, 0.f};
#pragma unroll
  for (int i = 0; i < FI; i++)
#pragma unroll
    for (int j = 0; j < FJ; j++) acc[i][j] = zero;

  stage(0, 0);
  int cur = 0;
  for (int k0 = 0; k0 < K; k0 += BK) {
    if (k0 + BK < K) {
      stage(cur ^ 1, k0 + BK);             // prefetch next tile
      asm volatile("s_waitcnt vmcnt(4)" ::: "memory");   // cur-tile done; next in flight
    } else {
      asm volatile("s_waitcnt vmcnt(0)" ::: "memory");   // final tile: full drain
    }
    __builtin_amdgcn_s_barrier();          // buffer cur complete for all waves
    __builtin_amdgcn_sched_barrier(0);
    const u16* Sc = S[cur];
    {
      bf16x8 af[FI], bfr[FJ];
#pragma unroll
      for (int i = 0; i < FI; i++) {
        int arow = wr * 64 + i * 16 + (lane & 15);
        int ac = ((lane >> 4) ^ ((arow >> 1) & 3)) * 8;
        af[i] = *(const bf16x8*)&Sc[arow * BK + ac];
      }
#pragma unroll
      for (int j = 0; j < FJ; j++) {
        int brow = BM + wc * (BN / 2) + j * 16 + (lane & 15);
        int bc = ((lane >> 4) ^ ((brow >> 1) & 3)) * 8;
        bfr[j] = *(const bf16x8*)&Sc[brow * BK + bc];
      }
#pragma unroll
      for (int i = 0; i < FI; i++)
#pragma unroll
        for (int j = 0; j < FJ; j++)
          acc[i][j] = __builtin_amdgcn_mfma_f32_16x16x32_bf16(af[i], bfr[j], acc[i][j], 0, 0, 0);
    }
    __builtin_amdgcn_s_barrier();          // all waves done reading buffer cur
    __builtin_amdgcn_sched_barrier(0);
    cur ^= 1;
  }
#pragma unroll
  for (int i = 0; i < FI; i++) {
    int grow = m0 + wr * 64 + i * 16 + (lane >> 4) * 4;
#pragma unroll
    for (int j = 0; j < FJ; j++) {
      int gcol = n0 + wc * (BN / 2) + j * 16 + (lane & 15);
#pragma unroll
      for (int r = 0; r < 4; r++)
        ep.store(bz, grow + r, gcol, acc[i][j][r]);
    }
  }
}

// ---- bf16 MFMA GEMM, 256x128 tile, 8 waves, 2-deep db + counted vmcnt + swizzle ----
template <class EP>
__global__ __launch_bounds__(512) void mgemm_big_k(const u16* __restrict__ A, long Azs, int ldA,
                                                   const u16* __restrict__ B, long Bzs, int ldB,
                                                   EP ep, int K) {
  constexpr int BM = 256, BN = 128, BK = 32;
  __shared__ __align__(16) u16 S[2][(BM + BN) * BK];   // 2 x 24 KiB
  int bx, by, bz;
  xcd_swz(bx, by, bz);
  const int tid = threadIdx.x;
  const int wid = tid >> 6, lane = tid & 63;
  const int m0 = by * BM, n0 = bx * BN;
  const u16* Az = A + (long)bz * Azs;
  const u16* Bz = B + (long)bz * Bzs;
  const int wr = wid >> 1, wc = wid & 1;
  const int lrow = lane >> 2;              // 16 rows per 1KB group
  const int lk   = (((lane & 3) ^ ((lane >> 3) & 3)) * 8);  // swizzled source chunk

  auto stage = [&](int buf, int k0) {
#pragma unroll
    for (int g = 0; g < 3; g++) {          // 24 groups / 8 waves
      int grp = g * 8 + wid;
      int row = grp * 16 + lrow;           // A rows [0,256), then B rows
      const u16* src = (row < BM)
          ? Az + (long)(m0 + row) * ldA + k0 + lk
          : Bz + (long)(n0 + row - BM) * ldB + k0 + lk;
      gl2lds16(src, (char*)S[buf] + grp * 1024);
    }
  };

  f32x4 acc[4][4];
  f32x4 zero = {0.f, 0.f, 0.f, 0.f};
#pragma unroll
  for (int i = 0; i < 4; i++)
#pragma unroll
    for (int j = 0; j < 4; j++) acc[i][j] = zero;

  stage(0, 0);
  int cur = 0;
  for (int k0 = 0; k0 < K; k0 += BK) {
    if (k0 + BK < K) {
      stage(cur ^ 1, k0 + BK);             // prefetch next tile
      asm volatile("s_waitcnt vmcnt(3)" ::: "memory");   // cur stage (3 loads) done
    } else {
      asm volatile("s_waitcnt vmcnt(0)" ::: "memory");
    }
    __builtin_amdgcn_s_barrier();
    __builtin_amdgcn_sched_barrier(0);
    const u16* Sc = S[cur];
    bf16x8 af[4], bfr[4];
#pragma unroll
    for (int i = 0; i < 4; i++) {
      int arow = wr * 64 + i * 16 + (lane & 15);
      int ac = ((lane >> 4) ^ ((arow >> 1) & 3)) * 8;
      af[i] = *(const bf16x8*)&Sc[arow * BK + ac];
      int brow = BM + wc * 64 + i * 16 + (lane & 15);
      int bc = ((lane >> 4) ^ ((brow >> 1) & 3)) * 8;
      bfr[i] = *(const bf16x8*)&Sc[brow * BK + bc];
    }
#pragma unroll
    for (int i = 0; i < 4; i++)
#pragma unroll
      for (int j = 0; j < 4; j++)
        acc[i][j] = __builtin_amdgcn_mfma_f32_16x16x32_bf16(af[i], bfr[j], acc[i][j], 0, 0, 0);
    __builtin_amdgcn_s_barrier();
    __builtin_amdgcn_sched_barrier(0);
    cur ^= 1;
  }
#pragma unroll
  for (int i = 0; i < 4; i++) {
    int grow = m0 + wr * 64 + i * 16 + (lane >> 4) * 4;
#pragma unroll
    for (int j = 0; j < 4; j++) {
      int gcol = n0 + wc * 64 + j * 16 + (lane & 15);
#pragma unroll
      for (int r = 0; r < 4; r++)
        ep.store(bz, grow + r, gcol, acc[i][j][r]);
    }
  }
}

// ---- split-bf16 3-term GEMM, 128^2 tile, 4 waves, 2-deep db + vmcnt + swizzle ----
template <bool CSTAT, class EP>
__global__ __launch_bounds__(256) void mgemm3_k(const u16* __restrict__ Ah,
                                                const u16* __restrict__ Al, long Azs, int ldA,
                                                const u16* __restrict__ Bh,
                                                const u16* __restrict__ Bl, long Bzs, int ldB,
                                                EP ep, int K,
                                                float* __restrict__ pmax,
                                                float* __restrict__ psum) {
  constexpr int BK = 32;
  __shared__ __align__(16) u16 S[2][16384];   // per buf: Ah|Al|Bh|Bl, 8KB each
  int bx, by, bz;
  xcd_swz(bx, by, bz);
  const int tid = threadIdx.x;
  const int wid = tid >> 6, lane = tid & 63;
  const int m0 = by * 128, n0 = bx * 128;
  const u16* Ahz = Ah + (long)bz * Azs;
  const u16* Alz = Al + (long)bz * Azs;
  const u16* Bhz = Bh + (long)bz * Bzs;
  const u16* Blz = Bl + (long)bz * Bzs;
  const int wr = wid >> 1, wc = wid & 1;
  const int srow = lane >> 2;
  const int sk8  = (((lane & 3) ^ ((lane >> 3) & 3)) * 8);  // swizzled source chunk

  auto stage = [&](int buf, int k0) {
    char* base = (char*)S[buf];
#pragma unroll
    for (int i = 0; i < 2; i++) {
      int chunk = i * 4 + wid;
      int r = chunk * 16 + srow;
      long ao = (long)(m0 + r) * ldA + k0 + sk8;
      long bo = (long)(n0 + r) * ldB + k0 + sk8;
      gl2lds16(Ahz + ao, base + chunk * 1024);
      gl2lds16(Alz + ao, base + 8192 + chunk * 1024);
      gl2lds16(Bhz + bo, base + 16384 + chunk * 1024);
      gl2lds16(Blz + bo, base + 24576 + chunk * 1024);
    }
  };

  f32x4 acc[4][4];
  f32x4 zero = {0.f, 0.f, 0.f, 0.f};
#pragma unroll
  for (int i = 0; i < 4; i++)
#pragma unroll
    for (int j = 0; j < 4; j++) acc[i][j] = zero;

  stage(0, 0);
  int cur = 0;
  for (int k0 = 0; k0 < K; k0 += BK) {
    if (k0 + BK < K) {
      stage(cur ^ 1, k0 + BK);             // prefetch next tile
      asm volatile("s_waitcnt vmcnt(8)" ::: "memory");   // cur stage (8 loads) done
    } else {
      asm volatile("s_waitcnt vmcnt(0)" ::: "memory");
    }
    __builtin_amdgcn_s_barrier();
    __builtin_amdgcn_sched_barrier(0);
    const u16* Sb = S[cur];
    bf16x8 ah[4], al[4], bh[4], bl[4];
#pragma unroll
    for (int i = 0; i < 4; i++) {
      int arow = wr * 64 + i * 16 + (lane & 15);
      int ac = ((lane >> 4) ^ ((arow >> 1) & 3)) * 8;
      int aoff = arow * BK + ac;
      ah[i] = *(const bf16x8*)&Sb[aoff];
      al[i] = *(const bf16x8*)&Sb[4096 + aoff];
      int brow = wc * 64 + i * 16 + (lane & 15);
      int bc = ((lane >> 4) ^ ((brow >> 1) & 3)) * 8;
      int boff = brow * BK + bc;
      bh[i] = *(const bf16x8*)&Sb[8192 + boff];
      bl[i] = *(const bf16x8*)&Sb[12288 + boff];
    }
#pragma unroll
    for (int i = 0; i < 4; i++)
#pragma unroll
      for (int j = 0; j < 4; j++) {
        acc[i][j] = __builtin_amdgcn_mfma_f32_16x16x32_bf16(ah[i], bh[j], acc[i][j], 0, 0, 0);
        acc[i][j] = __builtin_amdgcn_mfma_f32_16x16x32_bf16(al[i], bh[j], acc[i][j], 0, 0, 0);
        acc[i][j] = __builtin_amdgcn_mfma_f32_16x16x32_bf16(ah[i], bl[j], acc[i][j], 0, 0, 0);
      }
    __builtin_amdgcn_s_barrier();
    __builtin_amdgcn_sched_barrier(0);
    cur ^= 1;
  }
#pragma unroll
  for (int i = 0; i < 4; i++) {
    int grow = m0 + wr * 64 + i * 16 + (lane >> 4) * 4;
#pragma unroll
    for (int j = 0; j < 4; j++) {
      int gcol = n0 + wc * 64 + j * 16 + (lane & 15);
#pragma unroll
      for (int r = 0; r < 4; r++)
        ep.store(bz, grow + r, gcol, acc[i][j][r]);
    }
  }

  if constexpr (CSTAT) {
    // stage buffers are dead after the K-loop's final barrier; reuse as scratch.
    float* cred = (float*)&S[0][0];        // [2][128]
    float* sred = cred + 256;              // [2][128]
    float cmv[4], lsum[4];
#pragma unroll
    for (int j = 0; j < 4; j++) {
      float m = acc[0][j][0];
#pragma unroll
      for (int i = 0; i < 4; i++)
#pragma unroll
        for (int r = 0; r < 4; r++) m = fmaxf(m, acc[i][j][r]);
      m = fmaxf(m, __shfl_xor(m, 16, 64));
      m = fmaxf(m, __shfl_xor(m, 32, 64));
      cmv[j] = m;                          // col max over this wave's 64 rows
    }
    if (lane < 16) {
#pragma unroll
      for (int j = 0; j < 4; j++) cred[wr * 128 + wc * 64 + j * 16 + lane] = cmv[j];
    }
    __syncthreads();
#pragma unroll
    for (int j = 0; j < 4; j++) {
      int c = wc * 64 + j * 16 + (lane & 15);
      float cm = fmaxf(cred[c], cred[128 + c]);   // block col max (128 rows)
      float s = 0.f;
#pragma unroll
      for (int i = 0; i < 4; i++)
#pragma unroll
        for (int r = 0; r < 4; r++) s += __expf(acc[i][j][r] - cm);
      s += __shfl_xor(s, 16, 64);
      s += __shfl_xor(s, 32, 64);
      cmv[j] = cm; lsum[j] = s;
    }
    if (lane < 16) {
#pragma unroll
      for (int j = 0; j < 4; j++) sred[wr * 128 + wc * 64 + j * 16 + lane] = lsum[j];
    }
    __syncthreads();
    if (wr == 0 && lane < 16) {
      long sb = ((long)bz * 16 + by) * CES + n0;
#pragma unroll
      for (int j = 0; j < 4; j++) {
        int c = wc * 64 + j * 16 + lane;
        pmax[sb + c] = cmv[j];
        psum[sb + c] = sred[c] + sred[128 + c];
      }
    }
  }
}

// ---------------- launch ----------------
extern "C" void kernel_launch(void* const* d_in, const int* in_sizes, int n_in,
                              void* d_out, int out_size, void* d_ws, size_t ws_size,
                              hipStream_t stream) {
  const float* x          = (const float*)d_in[0];
  const float* W_slot     = (const float*)d_in[1];
  const float* u_slot     = (const float*)d_in[2];
  const float* sigma_slot = (const float*)d_in[3];
  const float* W1         = (const float*)d_in[4];
  const float* b1         = (const float*)d_in[5];
  const float* u1         = (const float*)d_in[6];
  const float* sig1       = (const float*)d_in[7];
  const float* W2         = (const float*)d_in[8];
  const float* b2         = (const float*)d_in[9];
  const float* u2         = (const float*)d_in[10];
  const float* sig2       = (const float*)d_in[11];
  float* out = (float*)d_out;

  // ---- workspace overlays (peak ~202 MiB, proven footprint) ----
  char* ws = (char*)d_ws;
  size_t off = 0;
  auto alloc = [&](size_t bytes) -> char* {
    char* p = ws + off;
    off += (bytes + 255) & ~(size_t)255;
    return p;
  };
  float* t1s = (float*)alloc(4096 * 4);
  float* t1a = (float*)alloc(4 * 4096 * 4);
  float* t1b = (float*)alloc(4 * 1024 * 4);
  float* t2s = (float*)alloc(1024 * 4);
  float* t2a = (float*)alloc(4 * 1024 * 4);
  float* t2b = (float*)alloc(4 * 4096 * 4);
  float* scales = (float*)alloc(16 * 4);
  float* pmax   = (float*)alloc((size_t)CB * 16 * CES * 4);
  float* psum   = (float*)alloc((size_t)CB * 16 * CES * 4);
  float* cmax   = (float*)alloc((size_t)CB * CES * 4);
  float* csum   = (float*)alloc((size_t)CB * CES * 4);
  char* regAB   = alloc((size_t)CB * CN * CD * 2 * 2);                // 32 MiB
  char* regBB   = alloc((size_t)CB * CES * CD * 2 * 2);               // 32 MiB
  char* regL    = alloc((size_t)CB * CN * CES * 4);                   // 64 MiB
  char* regS    = alloc((size_t)CE * CB * CS * CD * 2);               // 16 MiB
  u16* W1b      = (u16*)alloc((size_t)CE * CH * CD * 2);              // 32 MiB
  u16* W2b      = (u16*)alloc((size_t)CE * CD * CH * 2);              // 32 MiB

  u16*   xh      = (u16*)regAB;                        // [b][n][d]
  u16*   xl      = (u16*)(regAB + (size_t)CB * CN * CD * 2);
  u16*   dispT   = (u16*)regAB;                        // [b][es][n]
  u16*   combineB= (u16*)regAB;                        // [b][n][es]
  u16*   seh     = (u16*)regBB;                        // [b][es][d]
  u16*   sel     = (u16*)(regBB + (size_t)CB * CES * CD * 2);
  u16*   xT      = (u16*)regBB;                        // [b][d][n]
  float* logits  = (float*)regL;                       // [b][n][es]
  u16*   hbuf    = (u16*)regL;                         // [e][2048][H]
  u16*   xmh     = (u16*)regL;                         // [(b,s)][d] 4 MiB
  u16*   xml     = (u16*)(regL + (size_t)CB * CS * CD * 2);
  u16*   wslh    = (u16*)(regL + (size_t)2 * CB * CS * CD * 2);  // [4096][1024] 8 MiB
  u16*   wsll    = (u16*)(regL + (size_t)2 * CB * CS * CD * 2 + (size_t)CE * CD * CD * 2);
  u16*   slotsB  = (u16*)regS;                         // [e][(b,si)][d]
  u16*   outbufT = (u16*)regS;                         // [b][d][es]

  // zero t2s..t2b in one span (consecutive 256-aligned allocs)
  hipMemsetAsync(t2s, 0, (size_t)((char*)t2b - (char*)t2s) + 4 * 4096 * 4, stream);

  // spectral scales (gemv_cols also emits bf16 weight planes)
  gemv_rows_k<<<dim3(4096 / 4, 1), 256, 0, stream>>>(W_slot, u_slot, t1s, 4096, 1024, 0);
  gemv_rows_k<<<dim3(4096 / 4, 4), 256, 0, stream>>>(W1, u1, t1a, CH, CD, CD);
  gemv_rows_k<<<dim3(1024 / 4, 4), 256, 0, stream>>>(W2, u2, t1b, CD, CH, CH);
  gemv_cols_k<<<dim3(1024 / 256, 4096 / 256, 1), 256, 0, stream>>>(W_slot, t1s, t2s, wslh, wsll, 4096, 1024);
  gemv_cols_k<<<dim3(1024 / 256, 4096 / 256, 4), 256, 0, stream>>>(W1, t1a, t2a, W1b, nullptr, CH, CD);
  gemv_cols_k<<<dim3(4096 / 256, 1024 / 256, 4), 256, 0, stream>>>(W2, t1b, t2b, W2b, nullptr, CD, CH);
  scale_all_k<<<9, 256, 0, stream>>>(t1s, t2s, t1a, t2a, t1b, t2b,
                                     sigma_slot, sig1, sig2, scales);

  // x hi/lo split + token-group-mean hi/lo split (single pass over x)
  xsplit_fused_k<<<(CB * CS * (CD / 8)) / 256, 256, 0, stream>>>(x, xh, xl, xmh, xml);

  // SE = (xm @ W_slot^T) * scale_slot, split-bf16 3-term -> SE hi/lo planes
  mgemm3_k<false><<<dim3(4096 / 128, 2048 / 128, 1), 256, 0, stream>>>(
      xmh, xml, 0L, CD, wslh, wsll, 0L, CD, MEpSESplit{seh, sel, scales}, CD,
      nullptr, nullptr);

  // logits[b] = x_b @ SE_b^T, split-bf16 3-term -> f32, + fused col stats
  mgemm3_k<true><<<dim3(CES / 128, CN / 128, CB), 256, 0, stream>>>(
      xh, xl, (long)CN * CD, CD, seh, sel, (long)CES * CD, CD,
      MEpLogits{logits}, CD, pmax, psum);

  // dispatch softmax stat combine (16 slabs of 128 rows)
  colstat_comb_k<<<(CB * CES) / 256, 256, 0, stream>>>(pmax, psum, cmax, csum);

  // dispT[b][es][n] = bf16(exp(lg - cmax))   (overwrites xh/xl; dead after logits)
  tr_f2b_k<<<dim3(CES / 32, CN / 32, CB), 256, 0, stream>>>(logits, dispT, cmax, CN, CES, 1);
  // xT[b][d][n] = bf16(x^T)                  (overwrites seh; dead after logits)
  tr_f2b_k<<<dim3(CD / 32, CN / 32, CB), 256, 0, stream>>>(x, xT, nullptr, CN, CD, 0);

  // slots: [b] dispT(2048 x K2048) @ xT(1024 x K2048)^T -> slotsB (bf16, /csum)
  mgemm_db_k<128, 32><<<dim3(CD / 128, CES / 128, CB), 256, 0, stream>>>(
      dispT, (long)CES * CN, CN, xT, (long)CD * CN, CN, MEpSlots{slotsB, csum}, CN);

  // combineB[b][n][es] = bf16(softmax over es)   (overwrites dispT; dead)
  rowcomb_k<<<CB * CN, 256, 0, stream>>>(logits, combineB);

  // FFN1: [e] slotsB(2048 x K1024) @ W1b(4096 x K1024)^T -> hbuf (gelu, bf16)
  mgemm_big_k<<<dim3(CH / 128, 2048 / 256, CE), 512, 0, stream>>>(
      slotsB, (long)2048 * CD, CD, W1b, (long)CH * CD, CD, MEpGelu{hbuf, scales, b1}, CD);

  // FFN2 (swapped, writes y^T directly): [e] W2b(1024 x K4096) @ hbuf(2048 x K4096)^T
  mgemm_db_k<128, 32><<<dim3(2048 / 128, CD / 128, CE), 256, 0, stream>>>(
      W2b, (long)CD * CH, CH, hbuf, (long)2048 * CH, CH, MEpYT{outbufT, scales, b2}, CH);

  // final: [b] combineB(2048 x K2048) @ outbufT(1024 x K2048)^T -> out f32
  mgemm_db_k<128, 32><<<dim3(CD / 128, CN / 128, CB), 256, 0, stream>>>(
      combineB, (long)CN * CES, CES, outbufT, (long)CD * CES, CES, MEpOut{out}, CES);

  (void)in_sizes; (void)n_in; (void)out_size; (void)ws_size;
}

// Round 20
// 784.759 us; speedup vs baseline: 1.0896x; 1.0018x over previous
//
#include <hip/hip_runtime.h>
#include <hip/hip_bf16.h>
#include <math.h>

constexpr int CB  = 4;     // batch
constexpr int CN  = 2048;  // tokens
constexpr int CD  = 1024;  // model dim
constexpr int CE  = 4;     // experts
constexpr int CS  = 512;   // slots per expert
constexpr int CH  = 4096;  // expert hidden
constexpr int CES = 2048;  // E*S

typedef unsigned short u16;
typedef unsigned int   u32;
typedef __bf16 bf16x8 __attribute__((ext_vector_type(8)));
typedef float  f32x4  __attribute__((ext_vector_type(4)));

__device__ __forceinline__ u16 f2bf(float x) {
  u32 u = __float_as_uint(x);
  u = (u + 0x7FFF + ((u >> 16) & 1)) >> 16;   // round-to-nearest-even
  return (u16)u;
}

__device__ __forceinline__ void gl2lds16(const void* g, void* l) {
  __builtin_amdgcn_global_load_lds(
      (const __attribute__((address_space(1))) void*)g,
      (__attribute__((address_space(3))) void*)l, 16, 0, 0);
}

// bijective XCD-aware block swizzle (all grids have nwg % 8 == 0)
__device__ __forceinline__ void xcd_swz(int& bx, int& by, int& bz) {
  u32 gx = gridDim.x, gy = gridDim.y;
  u32 w = blockIdx.x + gx * (blockIdx.y + gy * blockIdx.z);
  u32 nwg = gx * gy * gridDim.z;
  u32 q = nwg >> 3;
  u32 wg = (w & 7) * q + (w >> 3);
  bx = wg % gx;
  u32 r = wg / gx;
  by = r % gy;
  bz = r / gy;
}

// LDS bank-conflict swizzle (rule #21: both-sides-or-neither with gl2lds).
// Row = 64B (BK=32 bf16) = 4 chunks of 16B. Involution: chunk ^= (row>>1)&3.
// Staging lane l writes LDS (row=l>>2, chunk=l&3) -> must LOAD global chunk
// (l&3)^((l>>3)&3). Reader of (row, chunk g) reads LDS chunk g^((row>>1)&3).

// ---------------- spectral-norm scale kernels ----------------
// scale = sigma * ||W u|| / ||W^T (W u)||

__global__ __launch_bounds__(256) void gemv_rows_k(const float* __restrict__ W,
    const float* __restrict__ u, float* __restrict__ t1, int M, int K, int ustride) {
  int bi = blockIdx.y;
  int row = blockIdx.x * 4 + (threadIdx.x >> 6);
  int lane = threadIdx.x & 63;
  const float* Wr = W + ((long)bi * M + row) * K;
  const float* ub = u + (long)bi * ustride;
  float s = 0.f;
  for (int k = lane; k < K; k += 64) s += Wr[k] * ub[k];
#pragma unroll
  for (int off = 32; off; off >>= 1) s += __shfl_down(s, off, 64);
  if (lane == 0) t1[bi * M + row] = s;
}

// also emits bf16 conversion of W (and optional lo-plane split)
__global__ __launch_bounds__(256) void gemv_cols_k(const float* __restrict__ W,
    const float* __restrict__ t1, float* __restrict__ t2,
    u16* __restrict__ bh, u16* __restrict__ bl, int M, int K) {
  int bi = blockIdx.z;
  int k = blockIdx.x * 256 + threadIdx.x;
  int m0 = blockIdx.y * 256;
  const float* Wb = W + (long)bi * M * K;
  const float* tb = t1 + bi * M;
  u16* bhb = bh + (long)bi * M * K;
  u16* blb = bl ? bl + (long)bi * M * K : nullptr;
  float s = 0.f;
#pragma unroll 4
  for (int m = 0; m < 256; m++) {
    long idx = (long)(m0 + m) * K + k;
    float w = Wb[idx];
    s += w * tb[m0 + m];
    u16 h = f2bf(w);
    bhb[idx] = h;
    if (blb) blb[idx] = f2bf(w - __uint_as_float((u32)h << 16));
  }
  atomicAdd(&t2[bi * K + k], s);
}

// all 9 spectral scales in one launch: block 0 = W_slot, 1..4 = W1[e], 5..8 = W2[e]
__global__ __launch_bounds__(256) void scale_all_k(
    const float* __restrict__ t1s, const float* __restrict__ t2s,
    const float* __restrict__ t1a, const float* __restrict__ t2a,
    const float* __restrict__ t1b, const float* __restrict__ t2b,
    const float* __restrict__ sigs, const float* __restrict__ sig1,
    const float* __restrict__ sig2, float* __restrict__ scales) {
  int bi = blockIdx.x;
  const float *t1, *t2; float sg; float* o; int M, K;
  if (bi == 0)      { t1 = t1s;                 t2 = t2s;                 sg = sigs[0];     o = scales + 0;      M = 4096; K = 1024; }
  else if (bi < 5)  { int e = bi - 1; t1 = t1a + e * 4096; t2 = t2a + e * 1024; sg = sig1[e]; o = scales + 1 + e; M = 4096; K = 1024; }
  else              { int e = bi - 5; t1 = t1b + e * 1024; t2 = t2b + e * 4096; sg = sig2[e]; o = scales + 5 + e; M = 1024; K = 4096; }
  int tid = threadIdx.x;
  __shared__ float red[256];
  float s1 = 0.f;
  for (int i = tid; i < M; i += 256) { float v = t1[i]; s1 += v * v; }
  red[tid] = s1; __syncthreads();
  for (int w = 128; w; w >>= 1) { if (tid < w) red[tid] += red[tid + w]; __syncthreads(); }
  float n1 = red[0]; __syncthreads();
  float s2 = 0.f;
  for (int i = tid; i < K; i += 256) { float v = t2[i]; s2 += v * v; }
  red[tid] = s2; __syncthreads();
  for (int w = 128; w; w >>= 1) { if (tid < w) red[tid] += red[tid + w]; __syncthreads(); }
  if (tid == 0) o[0] = sg * sqrtf(n1 / red[0]);
}

// ---------------- fused x hi/lo split + token-group-mean hi/lo split ----------------
__global__ __launch_bounds__(256) void xsplit_fused_k(const float* __restrict__ x,
    u16* __restrict__ xh, u16* __restrict__ xl,
    u16* __restrict__ xmh, u16* __restrict__ xml) {
  int idx = blockIdx.x * 256 + threadIdx.x;      // b*S*(D/8) total
  int d8 = idx & (CD / 8 - 1);
  int si = (idx >> 7) & (CS - 1);
  int b  = idx >> 16;
  long rbase = ((long)(b * CN + si * 4)) * CD + d8 * 8;
  float vr[4][8];
#pragma unroll
  for (int r = 0; r < 4; r++) {
    float4 a = *(const float4*)(x + rbase + (long)r * CD);
    float4 c = *(const float4*)(x + rbase + (long)r * CD + 4);
    vr[r][0]=a.x; vr[r][1]=a.y; vr[r][2]=a.z; vr[r][3]=a.w;
    vr[r][4]=c.x; vr[r][5]=c.y; vr[r][6]=c.z; vr[r][7]=c.w;
  }
#pragma unroll
  for (int r = 0; r < 4; r++) {
    u16 oh[8], ol[8];
#pragma unroll
    for (int c = 0; c < 8; c++) {
      u16 h = f2bf(vr[r][c]);
      oh[c] = h;
      ol[c] = f2bf(vr[r][c] - __uint_as_float((u32)h << 16));
    }
    *(uint4*)(xh + rbase + (long)r * CD) = *(const uint4*)oh;
    *(uint4*)(xl + rbase + (long)r * CD) = *(const uint4*)ol;
  }
  long mbase = ((long)(b * CS + si)) * CD + d8 * 8;
  u16 oh[8], ol[8];
#pragma unroll
  for (int c = 0; c < 8; c++) {
    float v = 0.25f * (vr[0][c] + vr[1][c] + vr[2][c] + vr[3][c]);
    u16 h = f2bf(v);
    oh[c] = h;
    ol[c] = f2bf(v - __uint_as_float((u32)h << 16));
  }
  *(uint4*)(xmh + mbase) = *(const uint4*)oh;
  *(uint4*)(xml + mbase) = *(const uint4*)ol;
}

// ---------------- dispatch softmax stat combine (16 slabs of 128 rows) ----------------
__global__ __launch_bounds__(256) void colstat_comb_k(const float* __restrict__ pmax,
    const float* __restrict__ psum, float* __restrict__ cmax, float* __restrict__ csum) {
  int idx = blockIdx.x * 256 + threadIdx.x;   // b*CES
  int b = idx >> 11;
  int es = idx & (CES - 1);
  float m = -1e30f;
#pragma unroll
  for (int sl = 0; sl < 16; sl++) m = fmaxf(m, pmax[(b * 16 + sl) * CES + es]);
  float s = 0.f;
#pragma unroll
  for (int sl = 0; sl < 16; sl++)
    s += psum[(b * 16 + sl) * CES + es] * __expf(pmax[(b * 16 + sl) * CES + es] - m);
  cmax[idx] = m; csum[idx] = s;
}

// ---------------- fused combine softmax (over es) -> bf16 ----------------
__global__ __launch_bounds__(256) void rowcomb_k(const float* __restrict__ lg,
                                                 u16* __restrict__ outB) {
  __shared__ float red[8];
  long row = blockIdx.x;                       // b*CN + n
  const float* p = lg + row * CES + threadIdx.x * 8;
  float4 a = *(const float4*)p;
  float4 b = *(const float4*)(p + 4);
  float v[8] = {a.x, a.y, a.z, a.w, b.x, b.y, b.z, b.w};
  float m = v[0];
#pragma unroll
  for (int c = 1; c < 8; c++) m = fmaxf(m, v[c]);
#pragma unroll
  for (int off = 32; off; off >>= 1) m = fmaxf(m, __shfl_xor(m, off, 64));
  int wv = threadIdx.x >> 6;
  if ((threadIdx.x & 63) == 0) red[wv] = m;
  __syncthreads();
  m = fmaxf(fmaxf(red[0], red[1]), fmaxf(red[2], red[3]));
  float s = 0.f;
#pragma unroll
  for (int c = 0; c < 8; c++) { v[c] = __expf(v[c] - m); s += v[c]; }
#pragma unroll
  for (int off = 32; off; off >>= 1) s += __shfl_xor(s, off, 64);
  if ((threadIdx.x & 63) == 0) red[4 + wv] = s;
  __syncthreads();
  float inv = 1.f / (red[4] + red[5] + red[6] + red[7]);
  u16 o[8];
#pragma unroll
  for (int c = 0; c < 8; c++) o[c] = f2bf(v[c] * inv);
  *(uint4*)(outB + row * CES + threadIdx.x * 8) = *(const uint4*)o;
}

// in [z][R][C] f32 -> out [z][C][R] bf16; expmode: v = exp(v - sub[z*C + col])
__global__ __launch_bounds__(256) void tr_f2b_k(const float* __restrict__ in,
    u16* __restrict__ out, const float* __restrict__ sub, int R, int C, int expmode) {
  __shared__ u16 t[32][33];
  int z = blockIdx.z;
  long ibase = (long)z * R * C;
  int r0 = blockIdx.y * 32, c0 = blockIdx.x * 32;
  int tx = threadIdx.x & 31, ty = threadIdx.x >> 5;
  float cm = expmode ? sub[(long)z * C + c0 + tx] : 0.f;
  for (int rr = ty; rr < 32; rr += 8) {
    float v = in[ibase + (long)(r0 + rr) * C + c0 + tx];
    if (expmode) v = __expf(v - cm);
    t[tx][rr] = f2bf(v);
  }
  __syncthreads();
  for (int cc = ty; cc < 32; cc += 8)
    out[ibase + (long)(c0 + cc) * R + r0 + tx] = t[cc][tx];
}

// ---------------- epilogues ----------------
struct MEpSESplit {  // SE hi/lo planes [b][es][d], es = ei*512+si; m=(b,si), n=(ei,di)
  u16* hi; u16* lo; const float* scale;
  __device__ void store(int z, int m, int n, float v) const {
    v *= scale[0];
    int b = m >> 9, si = m & 511, ei = n >> 10, di = n & 1023;
    long o = ((long)(b * CES + ei * 512 + si)) * CD + di;
    u16 h = f2bf(v);
    hi[o] = h;
    lo[o] = f2bf(v - __uint_as_float((u32)h << 16));
  }
};
struct MEpLogits {   // logits[b][n][es] = v ; z=b, m=token, n=es
  float* lg;
  __device__ void store(int b, int m, int n, float v) const {
    lg[((long)(b * CN + m)) * CES + n] = v;
  }
};
struct MEpSlots {  // slotsB[e][b*512+si][d] = bf16(v / csum[b][es]); z=b, m=es
  u16* sb; const float* __restrict__ csum;
  __device__ void store(int b, int m, int n, float v) const {
    float inv = 1.f / csum[b * CES + m];
    int e = m >> 9, si = m & 511;
    sb[((long)(e * 2048 + b * 512 + si)) * CD + n] = f2bf(v * inv);
  }
};
struct MEpGelu {   // h[e][m][H] = bf16(gelu(v*sc1[e] + b1[e][n])); z=e, m=(b,si)
  // tanh-form GELU: |err vs exact| below bf16 rounding of h (verified r8/r9).
  u16* h; const float* __restrict__ scales; const float* __restrict__ b1;
  __device__ void store(int e, int m, int n, float v) const {
    float xg = v * scales[1 + e] + b1[e * CH + n];
    float t = xg * (0.7978845608f + 0.0356774081f * xg * xg);
    float ex = __expf(2.f * t);
    float th = 1.f - 2.f / (ex + 1.f);          // tanh(t), saturates correctly
    float g = 0.5f * xg * (1.f + th);
    h[((long)(e * 2048 + m)) * CH + n] = f2bf(g);
  }
};
struct MEpYT {     // outbufT[b][d][es] = bf16(v*sc2[e] + b2[e][m]); z=e, m=d, n=(b,si)
  u16* ot; const float* __restrict__ scales; const float* __restrict__ b2;
  __device__ void store(int e, int m, int n, float v) const {
    int b = n >> 9, si = n & 511;
    ot[((long)(b * CD + m)) * CES + e * 512 + si] = f2bf(v * scales[5 + e] + b2[e * CD + m]);
  }
};
struct MEpOut {    // out[b][n][d] = v (combine already has 1/rsum); z=b
  float* o;
  __device__ void store(int b, int m, int n, float v) const {
    o[((long)(b * CN + m)) * CD + n] = v;
  }
};

// -- bf16 MFMA GEMM, 128xBN, 4 waves, 4-buffer ring, ONE barrier/K-step + vmcnt --
// Ring safety: read buf = t&3; stage targets (t+2)&3; skewed-issue (t+3)&3 —
// never the read buffer (single barrier bounds skew to <1 iter). Buf reuse at
// t+4 protected by barrier(t+2). vmcnt(8) = 2 stages in flight (FIFO => stage t
// done). LDS 4x16KB = 64KB (2 blocks/CU, grid-capped anyway).
template <int BN, int BK, class EP>
__global__ __launch_bounds__(256) void mgemm_db_k(const u16* __restrict__ A, long Azs, int ldA,
                                                  const u16* __restrict__ B, long Bzs, int ldB,
                                                  EP ep, int K) {
  constexpr int BM = 128;
  constexpr int FI = 4;
  constexpr int FJ = BN / 32;
  static_assert(BK == 32, "swizzle + vmcnt literals assume BK=32");
  constexpr int RPL = 16;                  // rows per 1KB load-group
  constexpr int NGRP = (BM + BN) / RPL;    // 1KB groups per K-step
  constexpr int GPW = NGRP / 4;            // gl2lds instructions per wave per stage
  static_assert(GPW == 4, "vmcnt literals below assume 4 loads per stage");
  __shared__ __align__(16) u16 S[4][(BM + BN) * BK];
  int bx, by, bz;
  xcd_swz(bx, by, bz);
  const int tid = threadIdx.x;
  const int wid = tid >> 6, lane = tid & 63;
  const int m0 = by * BM, n0 = bx * BN;
  const u16* Az = A + (long)bz * Azs;
  const u16* Bz = B + (long)bz * Bzs;
  const int wr = wid >> 1, wc = wid & 1;
  const int lrow = lane >> 2;              // row within load-group
  const int lk   = (((lane & 3) ^ ((lane >> 3) & 3)) * 8);  // swizzled source chunk

  auto stage = [&](int buf, int k0) {
#pragma unroll
    for (int g = 0; g < GPW; g++) {
      int grp = g * 4 + wid;
      int row = grp * RPL + lrow;          // A rows [0,BM), then B rows
      const u16* src = (row < BM)
          ? Az + (long)(m0 + row) * ldA + k0 + lk
          : Bz + (long)(n0 + row - BM) * ldB + k0 + lk;
      gl2lds16(src, (char*)S[buf] + grp * 1024);
    }
  };

  f32x4 acc[FI][FJ];
  f32x4 zero = {0.f, 0.f, 0.f, 0.f};
#pragma unroll
  for (int i = 0; i < FI; i++)
#pragma unroll
    for (int j = 0; j < FJ; j++) acc[i][j] = zero;

  const int nt = K / BK;
  stage(0, 0);
  if (nt > 1) stage(1, BK);
  int it = 0;
  for (int k0 = 0; k0 < K; k0 += BK, ++it) {
    if (it + 2 < nt) {
      stage((it + 2) & 3, k0 + 2 * BK);    // prefetch tile t+2
      asm volatile("s_waitcnt vmcnt(8)" ::: "memory");   // stage t done; t+1,t+2 in flight
    } else if (it + 1 < nt) {
      asm volatile("s_waitcnt vmcnt(4)" ::: "memory");   // stage t done; t+1 in flight
    } else {
      asm volatile("s_waitcnt vmcnt(0)" ::: "memory");   // final tile: full drain
    }
    __builtin_amdgcn_s_barrier();          // buffer t complete for all waves
    __builtin_amdgcn_sched_barrier(0);
    const u16* Sc = S[it & 3];
    {
      bf16x8 af[FI], bfr[FJ];
#pragma unroll
      for (int i = 0; i < FI; i++) {
        int arow = wr * 64 + i * 16 + (lane & 15);
        int ac = ((lane >> 4) ^ ((arow >> 1) & 3)) * 8;
        af[i] = *(const bf16x8*)&Sc[arow * BK + ac];
      }
#pragma unroll
      for (int j = 0; j < FJ; j++) {
        int brow = BM + wc * (BN / 2) + j * 16 + (lane & 15);
        int bc = ((lane >> 4) ^ ((brow >> 1) & 3)) * 8;
        bfr[j] = *(const bf16x8*)&Sc[brow * BK + bc];
      }
#pragma unroll
      for (int i = 0; i < FI; i++)
#pragma unroll
        for (int j = 0; j < FJ; j++)
          acc[i][j] = __builtin_amdgcn_mfma_f32_16x16x32_bf16(af[i], bfr[j], acc[i][j], 0, 0, 0);
    }
    __builtin_amdgcn_sched_barrier(0);     // keep next iter's stage after compute
  }
#pragma unroll
  for (int i = 0; i < FI; i++) {
    int grow = m0 + wr * 64 + i * 16 + (lane >> 4) * 4;
#pragma unroll
    for (int j = 0; j < FJ; j++) {
      int gcol = n0 + wc * (BN / 2) + j * 16 + (lane & 15);
#pragma unroll
      for (int r = 0; r < 4; r++)
        ep.store(bz, grow + r, gcol, acc[i][j][r]);
    }
  }
}

// ---- bf16 MFMA GEMM, 256x128 tile, 8 waves, 2-deep db + counted vmcnt + swizzle ----
template <class EP>
__global__ __launch_bounds__(512) void mgemm_big_k(const u16* __restrict__ A, long Azs, int ldA,
                                                   const u16* __restrict__ B, long Bzs, int ldB,
                                                   EP ep, int K) {
  constexpr int BM = 256, BN = 128, BK = 32;
  __shared__ __align__(16) u16 S[2][(BM + BN) * BK];   // 2 x 24 KiB
  int bx, by, bz;
  xcd_swz(bx, by, bz);
  const int tid = threadIdx.x;
  const int wid = tid >> 6, lane = tid & 63;
  const int m0 = by * BM, n0 = bx * BN;
  const u16* Az = A + (long)bz * Azs;
  const u16* Bz = B + (long)bz * Bzs;
  const int wr = wid >> 1, wc = wid & 1;
  const int lrow = lane >> 2;              // 16 rows per 1KB group
  const int lk   = (((lane & 3) ^ ((lane >> 3) & 3)) * 8);  // swizzled source chunk

  auto stage = [&](int buf, int k0) {
#pragma unroll
    for (int g = 0; g < 3; g++) {          // 24 groups / 8 waves
      int grp = g * 8 + wid;
      int row = grp * 16 + lrow;           // A rows [0,256), then B rows
      const u16* src = (row < BM)
          ? Az + (long)(m0 + row) * ldA + k0 + lk
          : Bz + (long)(n0 + row - BM) * ldB + k0 + lk;
      gl2lds16(src, (char*)S[buf] + grp * 1024);
    }
  };

  f32x4 acc[4][4];
  f32x4 zero = {0.f, 0.f, 0.f, 0.f};
#pragma unroll
  for (int i = 0; i < 4; i++)
#pragma unroll
    for (int j = 0; j < 4; j++) acc[i][j] = zero;

  stage(0, 0);
  int cur = 0;
  for (int k0 = 0; k0 < K; k0 += BK) {
    if (k0 + BK < K) {
      stage(cur ^ 1, k0 + BK);             // prefetch next tile
      asm volatile("s_waitcnt vmcnt(3)" ::: "memory");   // cur stage (3 loads) done
    } else {
      asm volatile("s_waitcnt vmcnt(0)" ::: "memory");
    }
    __builtin_amdgcn_s_barrier();
    __builtin_amdgcn_sched_barrier(0);
    const u16* Sc = S[cur];
    bf16x8 af[4], bfr[4];
#pragma unroll
    for (int i = 0; i < 4; i++) {
      int arow = wr * 64 + i * 16 + (lane & 15);
      int ac = ((lane >> 4) ^ ((arow >> 1) & 3)) * 8;
      af[i] = *(const bf16x8*)&Sc[arow * BK + ac];
      int brow = BM + wc * 64 + i * 16 + (lane & 15);
      int bc = ((lane >> 4) ^ ((brow >> 1) & 3)) * 8;
      bfr[i] = *(const bf16x8*)&Sc[brow * BK + bc];
    }
#pragma unroll
    for (int i = 0; i < 4; i++)
#pragma unroll
      for (int j = 0; j < 4; j++)
        acc[i][j] = __builtin_amdgcn_mfma_f32_16x16x32_bf16(af[i], bfr[j], acc[i][j], 0, 0, 0);
    __builtin_amdgcn_s_barrier();
    __builtin_amdgcn_sched_barrier(0);
    cur ^= 1;
  }
#pragma unroll
  for (int i = 0; i < 4; i++) {
    int grow = m0 + wr * 64 + i * 16 + (lane >> 4) * 4;
#pragma unroll
    for (int j = 0; j < 4; j++) {
      int gcol = n0 + wc * 64 + j * 16 + (lane & 15);
#pragma unroll
      for (int r = 0; r < 4; r++)
        ep.store(bz, grow + r, gcol, acc[i][j][r]);
    }
  }
}

// ---- split-bf16 3-term GEMM, 128^2 tile, 4 waves, 2-deep db + vmcnt + swizzle ----
template <bool CSTAT, class EP>
__global__ __launch_bounds__(256) void mgemm3_k(const u16* __restrict__ Ah,
                                                const u16* __restrict__ Al, long Azs, int ldA,
                                                const u16* __restrict__ Bh,
                                                const u16* __restrict__ Bl, long Bzs, int ldB,
                                                EP ep, int K,
                                                float* __restrict__ pmax,
                                                float* __restrict__ psum) {
  constexpr int BK = 32;
  __shared__ __align__(16) u16 S[2][16384];   // per buf: Ah|Al|Bh|Bl, 8KB each
  int bx, by, bz;
  xcd_swz(bx, by, bz);
  const int tid = threadIdx.x;
  const int wid = tid >> 6, lane = tid & 63;
  const int m0 = by * 128, n0 = bx * 128;
  const u16* Ahz = Ah + (long)bz * Azs;
  const u16* Alz = Al + (long)bz * Azs;
  const u16* Bhz = Bh + (long)bz * Bzs;
  const u16* Blz = Bl + (long)bz * Bzs;
  const int wr = wid >> 1, wc = wid & 1;
  const int srow = lane >> 2;
  const int sk8  = (((lane & 3) ^ ((lane >> 3) & 3)) * 8);  // swizzled source chunk

  auto stage = [&](int buf, int k0) {
    char* base = (char*)S[buf];
#pragma unroll
    for (int i = 0; i < 2; i++) {
      int chunk = i * 4 + wid;
      int r = chunk * 16 + srow;
      long ao = (long)(m0 + r) * ldA + k0 + sk8;
      long bo = (long)(n0 + r) * ldB + k0 + sk8;
      gl2lds16(Ahz + ao, base + chunk * 1024);
      gl2lds16(Alz + ao, base + 8192 + chunk * 1024);
      gl2lds16(Bhz + bo, base + 16384 + chunk * 1024);
      gl2lds16(Blz + bo, base + 24576 + chunk * 1024);
    }
  };

  f32x4 acc[4][4];
  f32x4 zero = {0.f, 0.f, 0.f, 0.f};
#pragma unroll
  for (int i = 0; i < 4; i++)
#pragma unroll
    for (int j = 0; j < 4; j++) acc[i][j] = zero;

  stage(0, 0);
  int cur = 0;
  for (int k0 = 0; k0 < K; k0 += BK) {
    if (k0 + BK < K) {
      stage(cur ^ 1, k0 + BK);             // prefetch next tile
      asm volatile("s_waitcnt vmcnt(8)" ::: "memory");   // cur stage (8 loads) done
    } else {
      asm volatile("s_waitcnt vmcnt(0)" ::: "memory");
    }
    __builtin_amdgcn_s_barrier();
    __builtin_amdgcn_sched_barrier(0);
    const u16* Sb = S[cur];
    bf16x8 ah[4], al[4], bh[4], bl[4];
#pragma unroll
    for (int i = 0; i < 4; i++) {
      int arow = wr * 64 + i * 16 + (lane & 15);
      int ac = ((lane >> 4) ^ ((arow >> 1) & 3)) * 8;
      int aoff = arow * BK + ac;
      ah[i] = *(const bf16x8*)&Sb[aoff];
      al[i] = *(const bf16x8*)&Sb[4096 + aoff];
      int brow = wc * 64 + i * 16 + (lane & 15);
      int bc = ((lane >> 4) ^ ((brow >> 1) & 3)) * 8;
      int boff = brow * BK + bc;
      bh[i] = *(const bf16x8*)&Sb[8192 + boff];
      bl[i] = *(const bf16x8*)&Sb[12288 + boff];
    }
#pragma unroll
    for (int i = 0; i < 4; i++)
#pragma unroll
      for (int j = 0; j < 4; j++) {
        acc[i][j] = __builtin_amdgcn_mfma_f32_16x16x32_bf16(ah[i], bh[j], acc[i][j], 0, 0, 0);
        acc[i][j] = __builtin_amdgcn_mfma_f32_16x16x32_bf16(al[i], bh[j], acc[i][j], 0, 0, 0);
        acc[i][j] = __builtin_amdgcn_mfma_f32_16x16x32_bf16(ah[i], bl[j], acc[i][j], 0, 0, 0);
      }
    __builtin_amdgcn_s_barrier();
    __builtin_amdgcn_sched_barrier(0);
    cur ^= 1;
  }
#pragma unroll
  for (int i = 0; i < 4; i++) {
    int grow = m0 + wr * 64 + i * 16 + (lane >> 4) * 4;
#pragma unroll
    for (int j = 0; j < 4; j++) {
      int gcol = n0 + wc * 64 + j * 16 + (lane & 15);
#pragma unroll
      for (int r = 0; r < 4; r++)
        ep.store(bz, grow + r, gcol, acc[i][j][r]);
    }
  }

  if constexpr (CSTAT) {
    // stage buffers are dead after the K-loop's final barrier; reuse as scratch.
    float* cred = (float*)&S[0][0];        // [2][128]
    float* sred = cred + 256;              // [2][128]
    float cmv[4], lsum[4];
#pragma unroll
    for (int j = 0; j < 4; j++) {
      float m = acc[0][j][0];
#pragma unroll
      for (int i = 0; i < 4; i++)
#pragma unroll
        for (int r = 0; r < 4; r++) m = fmaxf(m, acc[i][j][r]);
      m = fmaxf(m, __shfl_xor(m, 16, 64));
      m = fmaxf(m, __shfl_xor(m, 32, 64));
      cmv[j] = m;                          // col max over this wave's 64 rows
    }
    if (lane < 16) {
#pragma unroll
      for (int j = 0; j < 4; j++) cred[wr * 128 + wc * 64 + j * 16 + lane] = cmv[j];
    }
    __syncthreads();
#pragma unroll
    for (int j = 0; j < 4; j++) {
      int c = wc * 64 + j * 16 + (lane & 15);
      float cm = fmaxf(cred[c], cred[128 + c]);   // block col max (128 rows)
      float s = 0.f;
#pragma unroll
      for (int i = 0; i < 4; i++)
#pragma unroll
        for (int r = 0; r < 4; r++) s += __expf(acc[i][j][r] - cm);
      s += __shfl_xor(s, 16, 64);
      s += __shfl_xor(s, 32, 64);
      cmv[j] = cm; lsum[j] = s;
    }
    if (lane < 16) {
#pragma unroll
      for (int j = 0; j < 4; j++) sred[wr * 128 + wc * 64 + j * 16 + lane] = lsum[j];
    }
    __syncthreads();
    if (wr == 0 && lane < 16) {
      long sb = ((long)bz * 16 + by) * CES + n0;
#pragma unroll
      for (int j = 0; j < 4; j++) {
        int c = wc * 64 + j * 16 + lane;
        pmax[sb + c] = cmv[j];
        psum[sb + c] = sred[c] + sred[128 + c];
      }
    }
  }
}

// ---------------- launch ----------------
extern "C" void kernel_launch(void* const* d_in, const int* in_sizes, int n_in,
                              void* d_out, int out_size, void* d_ws, size_t ws_size,
                              hipStream_t stream) {
  const float* x          = (const float*)d_in[0];
  const float* W_slot     = (const float*)d_in[1];
  const float* u_slot     = (const float*)d_in[2];
  const float* sigma_slot = (const float*)d_in[3];
  const float* W1         = (const float*)d_in[4];
  const float* b1         = (const float*)d_in[5];
  const float* u1         = (const float*)d_in[6];
  const float* sig1       = (const float*)d_in[7];
  const float* W2         = (const float*)d_in[8];
  const float* b2         = (const float*)d_in[9];
  const float* u2         = (const float*)d_in[10];
  const float* sig2       = (const float*)d_in[11];
  float* out = (float*)d_out;

  // ---- workspace overlays (peak ~202 MiB, proven footprint) ----
  char* ws = (char*)d_ws;
  size_t off = 0;
  auto alloc = [&](size_t bytes) -> char* {
    char* p = ws + off;
    off += (bytes + 255) & ~(size_t)255;
    return p;
  };
  float* t1s = (float*)alloc(4096 * 4);
  float* t1a = (float*)alloc(4 * 4096 * 4);
  float* t1b = (float*)alloc(4 * 1024 * 4);
  float* t2s = (float*)alloc(1024 * 4);
  float* t2a = (float*)alloc(4 * 1024 * 4);
  float* t2b = (float*)alloc(4 * 4096 * 4);
  float* scales = (float*)alloc(16 * 4);
  float* pmax   = (float*)alloc((size_t)CB * 16 * CES * 4);
  float* psum   = (float*)alloc((size_t)CB * 16 * CES * 4);
  float* cmax   = (float*)alloc((size_t)CB * CES * 4);
  float* csum   = (float*)alloc((size_t)CB * CES * 4);
  char* regAB   = alloc((size_t)CB * CN * CD * 2 * 2);                // 32 MiB
  char* regBB   = alloc((size_t)CB * CES * CD * 2 * 2);               // 32 MiB
  char* regL    = alloc((size_t)CB * CN * CES * 4);                   // 64 MiB
  char* regS    = alloc((size_t)CE * CB * CS * CD * 2);               // 16 MiB
  u16* W1b      = (u16*)alloc((size_t)CE * CH * CD * 2);              // 32 MiB
  u16* W2b      = (u16*)alloc((size_t)CE * CD * CH * 2);              // 32 MiB

  u16*   xh      = (u16*)regAB;                        // [b][n][d]
  u16*   xl      = (u16*)(regAB + (size_t)CB * CN * CD * 2);
  u16*   dispT   = (u16*)regAB;                        // [b][es][n]
  u16*   combineB= (u16*)regAB;                        // [b][n][es]
  u16*   seh     = (u16*)regBB;                        // [b][es][d]
  u16*   sel     = (u16*)(regBB + (size_t)CB * CES * CD * 2);
  u16*   xT      = (u16*)regBB;                        // [b][d][n]
  float* logits  = (float*)regL;                       // [b][n][es]
  u16*   hbuf    = (u16*)regL;                         // [e][2048][H]
  u16*   xmh     = (u16*)regL;                         // [(b,s)][d] 4 MiB
  u16*   xml     = (u16*)(regL + (size_t)CB * CS * CD * 2);
  u16*   wslh    = (u16*)(regL + (size_t)2 * CB * CS * CD * 2);  // [4096][1024] 8 MiB
  u16*   wsll    = (u16*)(regL + (size_t)2 * CB * CS * CD * 2 + (size_t)CE * CD * CD * 2);
  u16*   slotsB  = (u16*)regS;                         // [e][(b,si)][d]
  u16*   outbufT = (u16*)regS;                         // [b][d][es]

  // zero t2s..t2b in one span (consecutive 256-aligned allocs)
  hipMemsetAsync(t2s, 0, (size_t)((char*)t2b - (char*)t2s) + 4 * 4096 * 4, stream);

  // spectral scales (gemv_cols also emits bf16 weight planes)
  gemv_rows_k<<<dim3(4096 / 4, 1), 256, 0, stream>>>(W_slot, u_slot, t1s, 4096, 1024, 0);
  gemv_rows_k<<<dim3(4096 / 4, 4), 256, 0, stream>>>(W1, u1, t1a, CH, CD, CD);
  gemv_rows_k<<<dim3(1024 / 4, 4), 256, 0, stream>>>(W2, u2, t1b, CD, CH, CH);
  gemv_cols_k<<<dim3(1024 / 256, 4096 / 256, 1), 256, 0, stream>>>(W_slot, t1s, t2s, wslh, wsll, 4096, 1024);
  gemv_cols_k<<<dim3(1024 / 256, 4096 / 256, 4), 256, 0, stream>>>(W1, t1a, t2a, W1b, nullptr, CH, CD);
  gemv_cols_k<<<dim3(4096 / 256, 1024 / 256, 4), 256, 0, stream>>>(W2, t1b, t2b, W2b, nullptr, CD, CH);
  scale_all_k<<<9, 256, 0, stream>>>(t1s, t2s, t1a, t2a, t1b, t2b,
                                     sigma_slot, sig1, sig2, scales);

  // x hi/lo split + token-group-mean hi/lo split (single pass over x)
  xsplit_fused_k<<<(CB * CS * (CD / 8)) / 256, 256, 0, stream>>>(x, xh, xl, xmh, xml);

  // SE = (xm @ W_slot^T) * scale_slot, split-bf16 3-term -> SE hi/lo planes
  mgemm3_k<false><<<dim3(4096 / 128, 2048 / 128, 1), 256, 0, stream>>>(
      xmh, xml, 0L, CD, wslh, wsll, 0L, CD, MEpSESplit{seh, sel, scales}, CD,
      nullptr, nullptr);

  // logits[b] = x_b @ SE_b^T, split-bf16 3-term -> f32, + fused col stats
  mgemm3_k<true><<<dim3(CES / 128, CN / 128, CB), 256, 0, stream>>>(
      xh, xl, (long)CN * CD, CD, seh, sel, (long)CES * CD, CD,
      MEpLogits{logits}, CD, pmax, psum);

  // dispatch softmax stat combine (16 slabs of 128 rows)
  colstat_comb_k<<<(CB * CES) / 256, 256, 0, stream>>>(pmax, psum, cmax, csum);

  // dispT[b][es][n] = bf16(exp(lg - cmax))   (overwrites xh/xl; dead after logits)
  tr_f2b_k<<<dim3(CES / 32, CN / 32, CB), 256, 0, stream>>>(logits, dispT, cmax, CN, CES, 1);
  // xT[b][d][n] = bf16(x^T)                  (overwrites seh; dead after logits)
  tr_f2b_k<<<dim3(CD / 32, CN / 32, CB), 256, 0, stream>>>(x, xT, nullptr, CN, CD, 0);

  // slots: [b] dispT(2048 x K2048) @ xT(1024 x K2048)^T -> slotsB (bf16, /csum)
  mgemm_db_k<128, 32><<<dim3(CD / 128, CES / 128, CB), 256, 0, stream>>>(
      dispT, (long)CES * CN, CN, xT, (long)CD * CN, CN, MEpSlots{slotsB, csum}, CN);

  // combineB[b][n][es] = bf16(softmax over es)   (overwrites dispT; dead)
  rowcomb_k<<<CB * CN, 256, 0, stream>>>(logits, combineB);

  // FFN1: [e] slotsB(2048 x K1024) @ W1b(4096 x K1024)^T -> hbuf (gelu, bf16)
  mgemm_big_k<<<dim3(CH / 128, 2048 / 256, CE), 512, 0, stream>>>(
      slotsB, (long)2048 * CD, CD, W1b, (long)CH * CD, CD, MEpGelu{hbuf, scales, b1}, CD);

  // FFN2 (swapped, writes y^T directly): [e] W2b(1024 x K4096) @ hbuf(2048 x K4096)^T
  mgemm_db_k<128, 32><<<dim3(2048 / 128, CD / 128, CE), 256, 0, stream>>>(
      W2b, (long)CD * CH, CH, hbuf, (long)2048 * CH, CH, MEpYT{outbufT, scales, b2}, CH);

  // final: [b] combineB(2048 x K2048) @ outbufT(1024 x K2048)^T -> out f32
  mgemm_db_k<128, 32><<<dim3(CD / 128, CN / 128, CB), 256, 0, stream>>>(
      combineB, (long)CN * CES, CES, outbufT, (long)CD * CES, CES, MEpOut{out}, CES);

  (void)in_sizes; (void)n_in; (void)out_size; (void)ws_size;
}

// Round 21
// 782.904 us; speedup vs baseline: 1.0922x; 1.0024x over previous
//
#include <hip/hip_runtime.h>
#include <hip/hip_bf16.h>
#include <math.h>

constexpr int CB  = 4;     // batch
constexpr int CN  = 2048;  // tokens
constexpr int CD  = 1024;  // model dim
constexpr int CE  = 4;     // experts
constexpr int CS  = 512;   // slots per expert
constexpr int CH  = 4096;  // expert hidden
constexpr int CES = 2048;  // E*S

typedef unsigned short u16;
typedef unsigned int   u32;
typedef __bf16 bf16x8 __attribute__((ext_vector_type(8)));
typedef float  f32x4  __attribute__((ext_vector_type(4)));

__device__ __forceinline__ u16 f2bf(float x) {
  u32 u = __float_as_uint(x);
  u = (u + 0x7FFF + ((u >> 16) & 1)) >> 16;   // round-to-nearest-even
  return (u16)u;
}

__device__ __forceinline__ void gl2lds16(const void* g, void* l) {
  __builtin_amdgcn_global_load_lds(
      (const __attribute__((address_space(1))) void*)g,
      (__attribute__((address_space(3))) void*)l, 16, 0, 0);
}

// bijective XCD-aware block swizzle (all grids have nwg % 8 == 0)
__device__ __forceinline__ void xcd_swz(int& bx, int& by, int& bz) {
  u32 gx = gridDim.x, gy = gridDim.y;
  u32 w = blockIdx.x + gx * (blockIdx.y + gy * blockIdx.z);
  u32 nwg = gx * gy * gridDim.z;
  u32 q = nwg >> 3;
  u32 wg = (w & 7) * q + (w >> 3);
  bx = wg % gx;
  u32 r = wg / gx;
  by = r % gy;
  bz = r / gy;
}

// LDS bank-conflict swizzle (rule #21: both-sides-or-neither with gl2lds).
// Row = 64B (BK=32 bf16) = 4 chunks of 16B. Involution: chunk ^= (row>>1)&3.
// Staging lane l writes LDS (row=l>>2, chunk=l&3) -> must LOAD global chunk
// (l&3)^((l>>3)&3). Reader of (row, chunk g) reads LDS chunk g^((row>>1)&3).

// ---------------- spectral-norm scale kernels ----------------
// scale = sigma * ||W u|| / ||W^T (W u)||

__global__ __launch_bounds__(256) void gemv_rows_k(const float* __restrict__ W,
    const float* __restrict__ u, float* __restrict__ t1, int M, int K, int ustride) {
  int bi = blockIdx.y;
  int row = blockIdx.x * 4 + (threadIdx.x >> 6);
  int lane = threadIdx.x & 63;
  const float* Wr = W + ((long)bi * M + row) * K;
  const float* ub = u + (long)bi * ustride;
  float s = 0.f;
  for (int k = lane; k < K; k += 64) s += Wr[k] * ub[k];
#pragma unroll
  for (int off = 32; off; off >>= 1) s += __shfl_down(s, off, 64);
  if (lane == 0) t1[bi * M + row] = s;
}

// also emits bf16 conversion of W (and optional lo-plane split)
__global__ __launch_bounds__(256) void gemv_cols_k(const float* __restrict__ W,
    const float* __restrict__ t1, float* __restrict__ t2,
    u16* __restrict__ bh, u16* __restrict__ bl, int M, int K) {
  int bi = blockIdx.z;
  int k = blockIdx.x * 256 + threadIdx.x;
  int m0 = blockIdx.y * 256;
  const float* Wb = W + (long)bi * M * K;
  const float* tb = t1 + bi * M;
  u16* bhb = bh + (long)bi * M * K;
  u16* blb = bl ? bl + (long)bi * M * K : nullptr;
  float s = 0.f;
#pragma unroll 4
  for (int m = 0; m < 256; m++) {
    long idx = (long)(m0 + m) * K + k;
    float w = Wb[idx];
    s += w * tb[m0 + m];
    u16 h = f2bf(w);
    bhb[idx] = h;
    if (blb) blb[idx] = f2bf(w - __uint_as_float((u32)h << 16));
  }
  atomicAdd(&t2[bi * K + k], s);
}

// all 9 spectral scales in one launch: block 0 = W_slot, 1..4 = W1[e], 5..8 = W2[e]
__global__ __launch_bounds__(256) void scale_all_k(
    const float* __restrict__ t1s, const float* __restrict__ t2s,
    const float* __restrict__ t1a, const float* __restrict__ t2a,
    const float* __restrict__ t1b, const float* __restrict__ t2b,
    const float* __restrict__ sigs, const float* __restrict__ sig1,
    const float* __restrict__ sig2, float* __restrict__ scales) {
  int bi = blockIdx.x;
  const float *t1, *t2; float sg; float* o; int M, K;
  if (bi == 0)      { t1 = t1s;                 t2 = t2s;                 sg = sigs[0];     o = scales + 0;      M = 4096; K = 1024; }
  else if (bi < 5)  { int e = bi - 1; t1 = t1a + e * 4096; t2 = t2a + e * 1024; sg = sig1[e]; o = scales + 1 + e; M = 4096; K = 1024; }
  else              { int e = bi - 5; t1 = t1b + e * 1024; t2 = t2b + e * 4096; sg = sig2[e]; o = scales + 5 + e; M = 1024; K = 4096; }
  int tid = threadIdx.x;
  __shared__ float red[256];
  float s1 = 0.f;
  for (int i = tid; i < M; i += 256) { float v = t1[i]; s1 += v * v; }
  red[tid] = s1; __syncthreads();
  for (int w = 128; w; w >>= 1) { if (tid < w) red[tid] += red[tid + w]; __syncthreads(); }
  float n1 = red[0]; __syncthreads();
  float s2 = 0.f;
  for (int i = tid; i < K; i += 256) { float v = t2[i]; s2 += v * v; }
  red[tid] = s2; __syncthreads();
  for (int w = 128; w; w >>= 1) { if (tid < w) red[tid] += red[tid + w]; __syncthreads(); }
  if (tid == 0) o[0] = sg * sqrtf(n1 / red[0]);
}

// ---------------- fused x hi/lo split + token-group-mean hi/lo split ----------------
__global__ __launch_bounds__(256) void xsplit_fused_k(const float* __restrict__ x,
    u16* __restrict__ xh, u16* __restrict__ xl,
    u16* __restrict__ xmh, u16* __restrict__ xml) {
  int idx = blockIdx.x * 256 + threadIdx.x;      // b*S*(D/8) total
  int d8 = idx & (CD / 8 - 1);
  int si = (idx >> 7) & (CS - 1);
  int b  = idx >> 16;
  long rbase = ((long)(b * CN + si * 4)) * CD + d8 * 8;
  float vr[4][8];
#pragma unroll
  for (int r = 0; r < 4; r++) {
    float4 a = *(const float4*)(x + rbase + (long)r * CD);
    float4 c = *(const float4*)(x + rbase + (long)r * CD + 4);
    vr[r][0]=a.x; vr[r][1]=a.y; vr[r][2]=a.z; vr[r][3]=a.w;
    vr[r][4]=c.x; vr[r][5]=c.y; vr[r][6]=c.z; vr[r][7]=c.w;
  }
#pragma unroll
  for (int r = 0; r < 4; r++) {
    u16 oh[8], ol[8];
#pragma unroll
    for (int c = 0; c < 8; c++) {
      u16 h = f2bf(vr[r][c]);
      oh[c] = h;
      ol[c] = f2bf(vr[r][c] - __uint_as_float((u32)h << 16));
    }
    *(uint4*)(xh + rbase + (long)r * CD) = *(const uint4*)oh;
    *(uint4*)(xl + rbase + (long)r * CD) = *(const uint4*)ol;
  }
  long mbase = ((long)(b * CS + si)) * CD + d8 * 8;
  u16 oh[8], ol[8];
#pragma unroll
  for (int c = 0; c < 8; c++) {
    float v = 0.25f * (vr[0][c] + vr[1][c] + vr[2][c] + vr[3][c]);
    u16 h = f2bf(v);
    oh[c] = h;
    ol[c] = f2bf(v - __uint_as_float((u32)h << 16));
  }
  *(uint4*)(xmh + mbase) = *(const uint4*)oh;
  *(uint4*)(xml + mbase) = *(const uint4*)ol;
}

// ---------------- dispatch softmax stat combine (16 slabs of 128 rows) ----------------
__global__ __launch_bounds__(256) void colstat_comb_k(const float* __restrict__ pmax,
    const float* __restrict__ psum, float* __restrict__ cmax, float* __restrict__ csum) {
  int idx = blockIdx.x * 256 + threadIdx.x;   // b*CES
  int b = idx >> 11;
  int es = idx & (CES - 1);
  float m = -1e30f;
#pragma unroll
  for (int sl = 0; sl < 16; sl++) m = fmaxf(m, pmax[(b * 16 + sl) * CES + es]);
  float s = 0.f;
#pragma unroll
  for (int sl = 0; sl < 16; sl++)
    s += psum[(b * 16 + sl) * CES + es] * __expf(pmax[(b * 16 + sl) * CES + es] - m);
  cmax[idx] = m; csum[idx] = s;
}

// ---------------- fused combine softmax (over es) -> bf16 ----------------
__global__ __launch_bounds__(256) void rowcomb_k(const float* __restrict__ lg,
                                                 u16* __restrict__ outB) {
  __shared__ float red[8];
  long row = blockIdx.x;                       // b*CN + n
  const float* p = lg + row * CES + threadIdx.x * 8;
  float4 a = *(const float4*)p;
  float4 b = *(const float4*)(p + 4);
  float v[8] = {a.x, a.y, a.z, a.w, b.x, b.y, b.z, b.w};
  float m = v[0];
#pragma unroll
  for (int c = 1; c < 8; c++) m = fmaxf(m, v[c]);
#pragma unroll
  for (int off = 32; off; off >>= 1) m = fmaxf(m, __shfl_xor(m, off, 64));
  int wv = threadIdx.x >> 6;
  if ((threadIdx.x & 63) == 0) red[wv] = m;
  __syncthreads();
  m = fmaxf(fmaxf(red[0], red[1]), fmaxf(red[2], red[3]));
  float s = 0.f;
#pragma unroll
  for (int c = 0; c < 8; c++) { v[c] = __expf(v[c] - m); s += v[c]; }
#pragma unroll
  for (int off = 32; off; off >>= 1) s += __shfl_xor(s, off, 64);
  if ((threadIdx.x & 63) == 0) red[4 + wv] = s;
  __syncthreads();
  float inv = 1.f / (red[4] + red[5] + red[6] + red[7]);
  u16 o[8];
#pragma unroll
  for (int c = 0; c < 8; c++) o[c] = f2bf(v[c] * inv);
  *(uint4*)(outB + row * CES + threadIdx.x * 8) = *(const uint4*)o;
}

// in [z][R][C] f32 -> out [z][C][R] bf16; expmode: v = exp(v - sub[z*C + col])
__global__ __launch_bounds__(256) void tr_f2b_k(const float* __restrict__ in,
    u16* __restrict__ out, const float* __restrict__ sub, int R, int C, int expmode) {
  __shared__ u16 t[32][33];
  int z = blockIdx.z;
  long ibase = (long)z * R * C;
  int r0 = blockIdx.y * 32, c0 = blockIdx.x * 32;
  int tx = threadIdx.x & 31, ty = threadIdx.x >> 5;
  float cm = expmode ? sub[(long)z * C + c0 + tx] : 0.f;
  for (int rr = ty; rr < 32; rr += 8) {
    float v = in[ibase + (long)(r0 + rr) * C + c0 + tx];
    if (expmode) v = __expf(v - cm);
    t[tx][rr] = f2bf(v);
  }
  __syncthreads();
  for (int cc = ty; cc < 32; cc += 8)
    out[ibase + (long)(c0 + cc) * R + r0 + tx] = t[cc][tx];
}

// ---------------- epilogues ----------------
struct MEpSESplit {  // SE hi/lo planes [b][es][d], es = ei*512+si; m=(b,si), n=(ei,di)
  u16* hi; u16* lo; const float* scale;
  __device__ void store(int z, int m, int n, float v) const {
    v *= scale[0];
    int b = m >> 9, si = m & 511, ei = n >> 10, di = n & 1023;
    long o = ((long)(b * CES + ei * 512 + si)) * CD + di;
    u16 h = f2bf(v);
    hi[o] = h;
    lo[o] = f2bf(v - __uint_as_float((u32)h << 16));
  }
};
struct MEpLogits {   // logits[b][n][es] = v ; z=b, m=token, n=es
  float* lg;
  __device__ void store(int b, int m, int n, float v) const {
    lg[((long)(b * CN + m)) * CES + n] = v;
  }
};
struct MEpSlots {  // slotsB[e][b*512+si][d] = bf16(v / csum[b][es]); z=b, m=es
  u16* sb; const float* __restrict__ csum;
  __device__ void store(int b, int m, int n, float v) const {
    float inv = 1.f / csum[b * CES + m];
    int e = m >> 9, si = m & 511;
    sb[((long)(e * 2048 + b * 512 + si)) * CD + n] = f2bf(v * inv);
  }
};
struct MEpGelu {   // h[e][m][H] = bf16(gelu(v*sc1[e] + b1[e][n])); z=e, m=(b,si)
  // tanh-form GELU: |err vs exact| below bf16 rounding of h (verified r8/r9).
  u16* h; const float* __restrict__ scales; const float* __restrict__ b1;
  __device__ void store(int e, int m, int n, float v) const {
    float xg = v * scales[1 + e] + b1[e * CH + n];
    float t = xg * (0.7978845608f + 0.0356774081f * xg * xg);
    float ex = __expf(2.f * t);
    float th = 1.f - 2.f / (ex + 1.f);          // tanh(t), saturates correctly
    float g = 0.5f * xg * (1.f + th);
    h[((long)(e * 2048 + m)) * CH + n] = f2bf(g);
  }
};
struct MEpYT {     // outbufT[b][d][es] = bf16(v*sc2[e] + b2[e][m]); z=e, m=d, n=(b,si)
  u16* ot; const float* __restrict__ scales; const float* __restrict__ b2;
  __device__ void store(int e, int m, int n, float v) const {
    int b = n >> 9, si = n & 511;
    ot[((long)(b * CD + m)) * CES + e * 512 + si] = f2bf(v * scales[5 + e] + b2[e * CD + m]);
  }
};
struct MEpOut {    // out[b][n][d] = v (combine already has 1/rsum); z=b
  float* o;
  __device__ void store(int b, int m, int n, float v) const {
    o[((long)(b * CN + m)) * CD + n] = v;
  }
};

// -- bf16 MFMA GEMM, 128xBN, 4 waves, 4-buffer ring, ONE barrier/K-step + vmcnt --
// + T5: setprio(1) around the MFMA cluster (role-diverse waves: stage-issuers
// vs MFMA-runners; scheduler prefers MFMA waves).
template <int BN, int BK, class EP>
__global__ __launch_bounds__(256) void mgemm_db_k(const u16* __restrict__ A, long Azs, int ldA,
                                                  const u16* __restrict__ B, long Bzs, int ldB,
                                                  EP ep, int K) {
  constexpr int BM = 128;
  constexpr int FI = 4;
  constexpr int FJ = BN / 32;
  static_assert(BK == 32, "swizzle + vmcnt literals assume BK=32");
  constexpr int RPL = 16;                  // rows per 1KB load-group
  constexpr int NGRP = (BM + BN) / RPL;    // 1KB groups per K-step
  constexpr int GPW = NGRP / 4;            // gl2lds instructions per wave per stage
  static_assert(GPW == 4, "vmcnt literals below assume 4 loads per stage");
  __shared__ __align__(16) u16 S[4][(BM + BN) * BK];
  int bx, by, bz;
  xcd_swz(bx, by, bz);
  const int tid = threadIdx.x;
  const int wid = tid >> 6, lane = tid & 63;
  const int m0 = by * BM, n0 = bx * BN;
  const u16* Az = A + (long)bz * Azs;
  const u16* Bz = B + (long)bz * Bzs;
  const int wr = wid >> 1, wc = wid & 1;
  const int lrow = lane >> 2;              // row within load-group
  const int lk   = (((lane & 3) ^ ((lane >> 3) & 3)) * 8);  // swizzled source chunk

  auto stage = [&](int buf, int k0) {
#pragma unroll
    for (int g = 0; g < GPW; g++) {
      int grp = g * 4 + wid;
      int row = grp * RPL + lrow;          // A rows [0,BM), then B rows
      const u16* src = (row < BM)
          ? Az + (long)(m0 + row) * ldA + k0 + lk
          : Bz + (long)(n0 + row - BM) * ldB + k0 + lk;
      gl2lds16(src, (char*)S[buf] + grp * 1024);
    }
  };

  f32x4 acc[FI][FJ];
  f32x4 zero = {0.f, 0.f, 0.f, 0.f};
#pragma unroll
  for (int i = 0; i < FI; i++)
#pragma unroll
    for (int j = 0; j < FJ; j++) acc[i][j] = zero;

  const int nt = K / BK;
  stage(0, 0);
  if (nt > 1) stage(1, BK);
  int it = 0;
  for (int k0 = 0; k0 < K; k0 += BK, ++it) {
    if (it + 2 < nt) {
      stage((it + 2) & 3, k0 + 2 * BK);    // prefetch tile t+2
      asm volatile("s_waitcnt vmcnt(8)" ::: "memory");   // stage t done; t+1,t+2 in flight
    } else if (it + 1 < nt) {
      asm volatile("s_waitcnt vmcnt(4)" ::: "memory");   // stage t done; t+1 in flight
    } else {
      asm volatile("s_waitcnt vmcnt(0)" ::: "memory");   // final tile: full drain
    }
    __builtin_amdgcn_s_barrier();          // buffer t complete for all waves
    __builtin_amdgcn_sched_barrier(0);
    const u16* Sc = S[it & 3];
    {
      bf16x8 af[FI], bfr[FJ];
#pragma unroll
      for (int i = 0; i < FI; i++) {
        int arow = wr * 64 + i * 16 + (lane & 15);
        int ac = ((lane >> 4) ^ ((arow >> 1) & 3)) * 8;
        af[i] = *(const bf16x8*)&Sc[arow * BK + ac];
      }
#pragma unroll
      for (int j = 0; j < FJ; j++) {
        int brow = BM + wc * (BN / 2) + j * 16 + (lane & 15);
        int bc = ((lane >> 4) ^ ((brow >> 1) & 3)) * 8;
        bfr[j] = *(const bf16x8*)&Sc[brow * BK + bc];
      }
      __builtin_amdgcn_s_setprio(1);
#pragma unroll
      for (int i = 0; i < FI; i++)
#pragma unroll
        for (int j = 0; j < FJ; j++)
          acc[i][j] = __builtin_amdgcn_mfma_f32_16x16x32_bf16(af[i], bfr[j], acc[i][j], 0, 0, 0);
      __builtin_amdgcn_s_setprio(0);
    }
    __builtin_amdgcn_sched_barrier(0);     // keep next iter's stage after compute
  }
#pragma unroll
  for (int i = 0; i < FI; i++) {
    int grow = m0 + wr * 64 + i * 16 + (lane >> 4) * 4;
#pragma unroll
    for (int j = 0; j < FJ; j++) {
      int gcol = n0 + wc * (BN / 2) + j * 16 + (lane & 15);
#pragma unroll
      for (int r = 0; r < 4; r++)
        ep.store(bz, grow + r, gcol, acc[i][j][r]);
    }
  }
}

// ---- bf16 MFMA GEMM, 256x128 tile, 8 waves, 2-deep db + counted vmcnt + swizzle ----
template <class EP>
__global__ __launch_bounds__(512) void mgemm_big_k(const u16* __restrict__ A, long Azs, int ldA,
                                                   const u16* __restrict__ B, long Bzs, int ldB,
                                                   EP ep, int K) {
  constexpr int BM = 256, BN = 128, BK = 32;
  __shared__ __align__(16) u16 S[2][(BM + BN) * BK];   // 2 x 24 KiB
  int bx, by, bz;
  xcd_swz(bx, by, bz);
  const int tid = threadIdx.x;
  const int wid = tid >> 6, lane = tid & 63;
  const int m0 = by * BM, n0 = bx * BN;
  const u16* Az = A + (long)bz * Azs;
  const u16* Bz = B + (long)bz * Bzs;
  const int wr = wid >> 1, wc = wid & 1;
  const int lrow = lane >> 2;              // 16 rows per 1KB group
  const int lk   = (((lane & 3) ^ ((lane >> 3) & 3)) * 8);  // swizzled source chunk

  auto stage = [&](int buf, int k0) {
#pragma unroll
    for (int g = 0; g < 3; g++) {          // 24 groups / 8 waves
      int grp = g * 8 + wid;
      int row = grp * 16 + lrow;           // A rows [0,256), then B rows
      const u16* src = (row < BM)
          ? Az + (long)(m0 + row) * ldA + k0 + lk
          : Bz + (long)(n0 + row - BM) * ldB + k0 + lk;
      gl2lds16(src, (char*)S[buf] + grp * 1024);
    }
  };

  f32x4 acc[4][4];
  f32x4 zero = {0.f, 0.f, 0.f, 0.f};
#pragma unroll
  for (int i = 0; i < 4; i++)
#pragma unroll
    for (int j = 0; j < 4; j++) acc[i][j] = zero;

  stage(0, 0);
  int cur = 0;
  for (int k0 = 0; k0 < K; k0 += BK) {
    if (k0 + BK < K) {
      stage(cur ^ 1, k0 + BK);             // prefetch next tile
      asm volatile("s_waitcnt vmcnt(3)" ::: "memory");   // cur stage (3 loads) done
    } else {
      asm volatile("s_waitcnt vmcnt(0)" ::: "memory");
    }
    __builtin_amdgcn_s_barrier();
    __builtin_amdgcn_sched_barrier(0);
    const u16* Sc = S[cur];
    bf16x8 af[4], bfr[4];
#pragma unroll
    for (int i = 0; i < 4; i++) {
      int arow = wr * 64 + i * 16 + (lane & 15);
      int ac = ((lane >> 4) ^ ((arow >> 1) & 3)) * 8;
      af[i] = *(const bf16x8*)&Sc[arow * BK + ac];
      int brow = BM + wc * 64 + i * 16 + (lane & 15);
      int bc = ((lane >> 4) ^ ((brow >> 1) & 3)) * 8;
      bfr[i] = *(const bf16x8*)&Sc[brow * BK + bc];
    }
    __builtin_amdgcn_s_setprio(1);
#pragma unroll
    for (int i = 0; i < 4; i++)
#pragma unroll
      for (int j = 0; j < 4; j++)
        acc[i][j] = __builtin_amdgcn_mfma_f32_16x16x32_bf16(af[i], bfr[j], acc[i][j], 0, 0, 0);
    __builtin_amdgcn_s_setprio(0);
    __builtin_amdgcn_s_barrier();
    __builtin_amdgcn_sched_barrier(0);
    cur ^= 1;
  }
#pragma unroll
  for (int i = 0; i < 4; i++) {
    int grow = m0 + wr * 64 + i * 16 + (lane >> 4) * 4;
#pragma unroll
    for (int j = 0; j < 4; j++) {
      int gcol = n0 + wc * 64 + j * 16 + (lane & 15);
#pragma unroll
      for (int r = 0; r < 4; r++)
        ep.store(bz, grow + r, gcol, acc[i][j][r]);
    }
  }
}

// ---- split-bf16 3-term GEMM, 128^2 tile, 4 waves, 2-deep db + vmcnt + swizzle ----
template <bool CSTAT, class EP>
__global__ __launch_bounds__(256) void mgemm3_k(const u16* __restrict__ Ah,
                                                const u16* __restrict__ Al, long Azs, int ldA,
                                                const u16* __restrict__ Bh,
                                                const u16* __restrict__ Bl, long Bzs, int ldB,
                                                EP ep, int K,
                                                float* __restrict__ pmax,
                                                float* __restrict__ psum) {
  constexpr int BK = 32;
  __shared__ __align__(16) u16 S[2][16384];   // per buf: Ah|Al|Bh|Bl, 8KB each
  int bx, by, bz;
  xcd_swz(bx, by, bz);
  const int tid = threadIdx.x;
  const int wid = tid >> 6, lane = tid & 63;
  const int m0 = by * 128, n0 = bx * 128;
  const u16* Ahz = Ah + (long)bz * Azs;
  const u16* Alz = Al + (long)bz * Azs;
  const u16* Bhz = Bh + (long)bz * Bzs;
  const u16* Blz = Bl + (long)bz * Bzs;
  const int wr = wid >> 1, wc = wid & 1;
  const int srow = lane >> 2;
  const int sk8  = (((lane & 3) ^ ((lane >> 3) & 3)) * 8);  // swizzled source chunk

  auto stage = [&](int buf, int k0) {
    char* base = (char*)S[buf];
#pragma unroll
    for (int i = 0; i < 2; i++) {
      int chunk = i * 4 + wid;
      int r = chunk * 16 + srow;
      long ao = (long)(m0 + r) * ldA + k0 + sk8;
      long bo = (long)(n0 + r) * ldB + k0 + sk8;
      gl2lds16(Ahz + ao, base + chunk * 1024);
      gl2lds16(Alz + ao, base + 8192 + chunk * 1024);
      gl2lds16(Bhz + bo, base + 16384 + chunk * 1024);
      gl2lds16(Blz + bo, base + 24576 + chunk * 1024);
    }
  };

  f32x4 acc[4][4];
  f32x4 zero = {0.f, 0.f, 0.f, 0.f};
#pragma unroll
  for (int i = 0; i < 4; i++)
#pragma unroll
    for (int j = 0; j < 4; j++) acc[i][j] = zero;

  stage(0, 0);
  int cur = 0;
  for (int k0 = 0; k0 < K; k0 += BK) {
    if (k0 + BK < K) {
      stage(cur ^ 1, k0 + BK);             // prefetch next tile
      asm volatile("s_waitcnt vmcnt(8)" ::: "memory");   // cur stage (8 loads) done
    } else {
      asm volatile("s_waitcnt vmcnt(0)" ::: "memory");
    }
    __builtin_amdgcn_s_barrier();
    __builtin_amdgcn_sched_barrier(0);
    const u16* Sb = S[cur];
    bf16x8 ah[4], al[4], bh[4], bl[4];
#pragma unroll
    for (int i = 0; i < 4; i++) {
      int arow = wr * 64 + i * 16 + (lane & 15);
      int ac = ((lane >> 4) ^ ((arow >> 1) & 3)) * 8;
      int aoff = arow * BK + ac;
      ah[i] = *(const bf16x8*)&Sb[aoff];
      al[i] = *(const bf16x8*)&Sb[4096 + aoff];
      int brow = wc * 64 + i * 16 + (lane & 15);
      int bc = ((lane >> 4) ^ ((brow >> 1) & 3)) * 8;
      int boff = brow * BK + bc;
      bh[i] = *(const bf16x8*)&Sb[8192 + boff];
      bl[i] = *(const bf16x8*)&Sb[12288 + boff];
    }
    __builtin_amdgcn_s_setprio(1);
#pragma unroll
    for (int i = 0; i < 4; i++)
#pragma unroll
      for (int j = 0; j < 4; j++) {
        acc[i][j] = __builtin_amdgcn_mfma_f32_16x16x32_bf16(ah[i], bh[j], acc[i][j], 0, 0, 0);
        acc[i][j] = __builtin_amdgcn_mfma_f32_16x16x32_bf16(al[i], bh[j], acc[i][j], 0, 0, 0);
        acc[i][j] = __builtin_amdgcn_mfma_f32_16x16x32_bf16(ah[i], bl[j], acc[i][j], 0, 0, 0);
      }
    __builtin_amdgcn_s_setprio(0);
    __builtin_amdgcn_s_barrier();
    __builtin_amdgcn_sched_barrier(0);
    cur ^= 1;
  }
#pragma unroll
  for (int i = 0; i < 4; i++) {
    int grow = m0 + wr * 64 + i * 16 + (lane >> 4) * 4;
#pragma unroll
    for (int j = 0; j < 4; j++) {
      int gcol = n0 + wc * 64 + j * 16 + (lane & 15);
#pragma unroll
      for (int r = 0; r < 4; r++)
        ep.store(bz, grow + r, gcol, acc[i][j][r]);
    }
  }

  if constexpr (CSTAT) {
    // stage buffers are dead after the K-loop's final barrier; reuse as scratch.
    float* cred = (float*)&S[0][0];        // [2][128]
    float* sred = cred + 256;              // [2][128]
    float cmv[4], lsum[4];
#pragma unroll
    for (int j = 0; j < 4; j++) {
      float m = acc[0][j][0];
#pragma unroll
      for (int i = 0; i < 4; i++)
#pragma unroll
        for (int r = 0; r < 4; r++) m = fmaxf(m, acc[i][j][r]);
      m = fmaxf(m, __shfl_xor(m, 16, 64));
      m = fmaxf(m, __shfl_xor(m, 32, 64));
      cmv[j] = m;                          // col max over this wave's 64 rows
    }
    if (lane < 16) {
#pragma unroll
      for (int j = 0; j < 4; j++) cred[wr * 128 + wc * 64 + j * 16 + lane] = cmv[j];
    }
    __syncthreads();
#pragma unroll
    for (int j = 0; j < 4; j++) {
      int c = wc * 64 + j * 16 + (lane & 15);
      float cm = fmaxf(cred[c], cred[128 + c]);   // block col max (128 rows)
      float s = 0.f;
#pragma unroll
      for (int i = 0; i < 4; i++)
#pragma unroll
        for (int r = 0; r < 4; r++) s += __expf(acc[i][j][r] - cm);
      s += __shfl_xor(s, 16, 64);
      s += __shfl_xor(s, 32, 64);
      cmv[j] = cm; lsum[j] = s;
    }
    if (lane < 16) {
#pragma unroll
      for (int j = 0; j < 4; j++) sred[wr * 128 + wc * 64 + j * 16 + lane] = lsum[j];
    }
    __syncthreads();
    if (wr == 0 && lane < 16) {
      long sb = ((long)bz * 16 + by) * CES + n0;
#pragma unroll
      for (int j = 0; j < 4; j++) {
        int c = wc * 64 + j * 16 + lane;
        pmax[sb + c] = cmv[j];
        psum[sb + c] = sred[c] + sred[128 + c];
      }
    }
  }
}

// ---------------- launch ----------------
extern "C" void kernel_launch(void* const* d_in, const int* in_sizes, int n_in,
                              void* d_out, int out_size, void* d_ws, size_t ws_size,
                              hipStream_t stream) {
  const float* x          = (const float*)d_in[0];
  const float* W_slot     = (const float*)d_in[1];
  const float* u_slot     = (const float*)d_in[2];
  const float* sigma_slot = (const float*)d_in[3];
  const float* W1         = (const float*)d_in[4];
  const float* b1         = (const float*)d_in[5];
  const float* u1         = (const float*)d_in[6];
  const float* sig1       = (const float*)d_in[7];
  const float* W2         = (const float*)d_in[8];
  const float* b2         = (const float*)d_in[9];
  const float* u2         = (const float*)d_in[10];
  const float* sig2       = (const float*)d_in[11];
  float* out = (float*)d_out;

  // ---- workspace overlays (peak ~202 MiB, proven footprint) ----
  char* ws = (char*)d_ws;
  size_t off = 0;
  auto alloc = [&](size_t bytes) -> char* {
    char* p = ws + off;
    off += (bytes + 255) & ~(size_t)255;
    return p;
  };
  float* t1s = (float*)alloc(4096 * 4);
  float* t1a = (float*)alloc(4 * 4096 * 4);
  float* t1b = (float*)alloc(4 * 1024 * 4);
  float* t2s = (float*)alloc(1024 * 4);
  float* t2a = (float*)alloc(4 * 1024 * 4);
  float* t2b = (float*)alloc(4 * 4096 * 4);
  float* scales = (float*)alloc(16 * 4);
  float* pmax   = (float*)alloc((size_t)CB * 16 * CES * 4);
  float* psum   = (float*)alloc((size_t)CB * 16 * CES * 4);
  float* cmax   = (float*)alloc((size_t)CB * CES * 4);
  float* csum   = (float*)alloc((size_t)CB * CES * 4);
  char* regAB   = alloc((size_t)CB * CN * CD * 2 * 2);                // 32 MiB
  char* regBB   = alloc((size_t)CB * CES * CD * 2 * 2);               // 32 MiB
  char* regL    = alloc((size_t)CB * CN * CES * 4);                   // 64 MiB
  char* regS    = alloc((size_t)CE * CB * CS * CD * 2);               // 16 MiB
  u16* W1b      = (u16*)alloc((size_t)CE * CH * CD * 2);              // 32 MiB
  u16* W2b      = (u16*)alloc((size_t)CE * CD * CH * 2);              // 32 MiB

  u16*   xh      = (u16*)regAB;                        // [b][n][d]
  u16*   xl      = (u16*)(regAB + (size_t)CB * CN * CD * 2);
  u16*   dispT   = (u16*)regAB;                        // [b][es][n]
  u16*   combineB= (u16*)regAB;                        // [b][n][es]
  u16*   seh     = (u16*)regBB;                        // [b][es][d]
  u16*   sel     = (u16*)(regBB + (size_t)CB * CES * CD * 2);
  u16*   xT      = (u16*)regBB;                        // [b][d][n]
  float* logits  = (float*)regL;                       // [b][n][es]
  u16*   hbuf    = (u16*)regL;                         // [e][2048][H]
  u16*   xmh     = (u16*)regL;                         // [(b,s)][d] 4 MiB
  u16*   xml     = (u16*)(regL + (size_t)CB * CS * CD * 2);
  u16*   wslh    = (u16*)(regL + (size_t)2 * CB * CS * CD * 2);  // [4096][1024] 8 MiB
  u16*   wsll    = (u16*)(regL + (size_t)2 * CB * CS * CD * 2 + (size_t)CE * CD * CD * 2);
  u16*   slotsB  = (u16*)regS;                         // [e][(b,si)][d]
  u16*   outbufT = (u16*)regS;                         // [b][d][es]

  // zero t2s..t2b in one span (consecutive 256-aligned allocs)
  hipMemsetAsync(t2s, 0, (size_t)((char*)t2b - (char*)t2s) + 4 * 4096 * 4, stream);

  // spectral scales (gemv_cols also emits bf16 weight planes)
  gemv_rows_k<<<dim3(4096 / 4, 1), 256, 0, stream>>>(W_slot, u_slot, t1s, 4096, 1024, 0);
  gemv_rows_k<<<dim3(4096 / 4, 4), 256, 0, stream>>>(W1, u1, t1a, CH, CD, CD);
  gemv_rows_k<<<dim3(1024 / 4, 4), 256, 0, stream>>>(W2, u2, t1b, CD, CH, CH);
  gemv_cols_k<<<dim3(1024 / 256, 4096 / 256, 1), 256, 0, stream>>>(W_slot, t1s, t2s, wslh, wsll, 4096, 1024);
  gemv_cols_k<<<dim3(1024 / 256, 4096 / 256, 4), 256, 0, stream>>>(W1, t1a, t2a, W1b, nullptr, CH, CD);
  gemv_cols_k<<<dim3(4096 / 256, 1024 / 256, 4), 256, 0, stream>>>(W2, t1b, t2b, W2b, nullptr, CD, CH);
  scale_all_k<<<9, 256, 0, stream>>>(t1s, t2s, t1a, t2a, t1b, t2b,
                                     sigma_slot, sig1, sig2, scales);

  // x hi/lo split + token-group-mean hi/lo split (single pass over x)
  xsplit_fused_k<<<(CB * CS * (CD / 8)) / 256, 256, 0, stream>>>(x, xh, xl, xmh, xml);

  // SE = (xm @ W_slot^T) * scale_slot, split-bf16 3-term -> SE hi/lo planes
  mgemm3_k<false><<<dim3(4096 / 128, 2048 / 128, 1), 256, 0, stream>>>(
      xmh, xml, 0L, CD, wslh, wsll, 0L, CD, MEpSESplit{seh, sel, scales}, CD,
      nullptr, nullptr);

  // logits[b] = x_b @ SE_b^T, split-bf16 3-term -> f32, + fused col stats
  mgemm3_k<true><<<dim3(CES / 128, CN / 128, CB), 256, 0, stream>>>(
      xh, xl, (long)CN * CD, CD, seh, sel, (long)CES * CD, CD,
      MEpLogits{logits}, CD, pmax, psum);

  // dispatch softmax stat combine (16 slabs of 128 rows)
  colstat_comb_k<<<(CB * CES) / 256, 256, 0, stream>>>(pmax, psum, cmax, csum);

  // dispT[b][es][n] = bf16(exp(lg - cmax))   (overwrites xh/xl; dead after logits)
  tr_f2b_k<<<dim3(CES / 32, CN / 32, CB), 256, 0, stream>>>(logits, dispT, cmax, CN, CES, 1);
  // xT[b][d][n] = bf16(x^T)                  (overwrites seh; dead after logits)
  tr_f2b_k<<<dim3(CD / 32, CN / 32, CB), 256, 0, stream>>>(x, xT, nullptr, CN, CD, 0);

  // slots: [b] dispT(2048 x K2048) @ xT(1024 x K2048)^T -> slotsB (bf16, /csum)
  mgemm_db_k<128, 32><<<dim3(CD / 128, CES / 128, CB), 256, 0, stream>>>(
      dispT, (long)CES * CN, CN, xT, (long)CD * CN, CN, MEpSlots{slotsB, csum}, CN);

  // combineB[b][n][es] = bf16(softmax over es)   (overwrites dispT; dead)
  rowcomb_k<<<CB * CN, 256, 0, stream>>>(logits, combineB);

  // FFN1: [e] slotsB(2048 x K1024) @ W1b(4096 x K1024)^T -> hbuf (gelu, bf16)
  mgemm_big_k<<<dim3(CH / 128, 2048 / 256, CE), 512, 0, stream>>>(
      slotsB, (long)2048 * CD, CD, W1b, (long)CH * CD, CD, MEpGelu{hbuf, scales, b1}, CD);

  // FFN2 (swapped, writes y^T directly): [e] W2b(1024 x K4096) @ hbuf(2048 x K4096)^T
  mgemm_db_k<128, 32><<<dim3(2048 / 128, CD / 128, CE), 256, 0, stream>>>(
      W2b, (long)CD * CH, CH, hbuf, (long)2048 * CH, CH, MEpYT{outbufT, scales, b2}, CH);

  // final: [b] combineB(2048 x K2048) @ outbufT(1024 x K2048)^T -> out f32
  mgemm_db_k<128, 32><<<dim3(CD / 128, CN / 128, CB), 256, 0, stream>>>(
      combineB, (long)CN * CES, CES, outbufT, (long)CD * CES, CES, MEpOut{out}, CES);

  (void)in_sizes; (void)n_in; (void)out_size; (void)ws_size;
}